// Round 1
// baseline (9723.138 us; speedup 1.0000x reference)
//
#include <hip/hip_runtime.h>
#include <math.h>

// ---------------- problem constants ----------------
// B=32, K=7, Z=64, C=3, H=W=64, G=70, ITERS=3
#define SCALE_ 0.125f

// workspace layout (float offsets)
#define WS_BUFA 0u            // 8388608 floats: enc ping / k / decoder ping
#define WS_BUFB 8388608u      // 8388608 floats: enc pong / decoder pong
#define WS_BUFC 16777216u     // 8388608 floats: v / dc4 output (224*4*4096=3670016)
#define WS_ATTN 25165824u     // 32*7*4096 = 917504
#define WS_PART 26083328u     // 32*16*7*64 = 229376
#define WS_Q    26312704u     // 224*64 = 14336
#define WS_SLOT 26327040u     // 224*64 = 14336
#define WS_ROW  26341376u     // 224

__device__ __forceinline__ float wave_sum(float v) {
#pragma unroll
    for (int m = 32; m >= 1; m >>= 1) v += __shfl_xor(v, m, 64);
    return v;
}

// ---------------- generic direct conv ----------------
// one block = 16x16 output tile of one image; per-thread: one pixel, all COUT channels.
template<int CIN, int COUT, int KS, int PAD>
__global__ __launch_bounds__(256) void conv_direct(
    const float* __restrict__ in, const float* __restrict__ wts,
    const float* __restrict__ bias, float* __restrict__ out,
    int Hin, int Win, int Hout, int Wout, int tilesX, int tilesY, int do_relu)
{
    constexpr int TS = 16;
    constexpr int TH = TS + KS - 1;
    __shared__ float tile[TH][TH + 1];
    const int tpb = tilesX * tilesY;
    const int n  = blockIdx.x / tpb;
    const int t  = blockIdx.x % tpb;
    const int ty0 = (t / tilesX) * TS;
    const int tx0 = (t % tilesX) * TS;
    const int tid = threadIdx.x;
    const int lx = tid & 15, ly = tid >> 4;

    float acc[COUT];
#pragma unroll
    for (int c = 0; c < COUT; ++c) acc[c] = 0.f;

    const float* inb = in + (size_t)n * CIN * Hin * Win;
    for (int ci = 0; ci < CIN; ++ci) {
        const float* inc = inb + (size_t)ci * Hin * Win;
        for (int idx = tid; idx < TH * TH; idx += 256) {
            int r = idx / TH, c = idx % TH;
            int gy = ty0 + r - PAD, gx = tx0 + c - PAD;
            float vv = 0.f;
            if (gy >= 0 && gy < Hin && gx >= 0 && gx < Win) vv = inc[gy * Win + gx];
            tile[r][c] = vv;
        }
        __syncthreads();
        float val[KS * KS];
#pragma unroll
        for (int ky = 0; ky < KS; ++ky)
#pragma unroll
            for (int kx = 0; kx < KS; ++kx)
                val[ky * KS + kx] = tile[ly + ky][lx + kx];
#pragma unroll
        for (int co = 0; co < COUT; ++co) {
            const float* wc = wts + ((size_t)co * CIN + ci) * (KS * KS);
            float a = acc[co];
#pragma unroll
            for (int tt = 0; tt < KS * KS; ++tt)
                a = fmaf(val[tt], wc[tt], a);
            acc[co] = a;
        }
        __syncthreads();
    }
    const int oy = ty0 + ly, ox = tx0 + lx;
    if (oy < Hout && ox < Wout) {
        float* ob = out + (size_t)n * COUT * Hout * Wout + oy * Wout + ox;
#pragma unroll
        for (int co = 0; co < COUT; ++co) {
            float vv = acc[co] + bias[co];
            if (do_relu) vv = fmaxf(vv, 0.f);
            ob[(size_t)co * Hout * Wout] = vv;
        }
    }
}

// ---------------- decoder conv1: input computed on the fly ----------------
// in[n,ci,gy,gx] = slots[n,ci] + (1-gy/69)*dpw[0,ci] + (gy/69)*dpw[1,ci]
//                + (gx/69)*dpw[2,ci] + (1-gx/69)*dpw[3,ci] + dpb[ci]
__global__ __launch_bounds__(256) void conv_dec1(
    const float* __restrict__ slots, const float* __restrict__ dpw,
    const float* __restrict__ dpb, const float* __restrict__ wts,
    const float* __restrict__ bias, float* __restrict__ out)
{
    constexpr int TS = 16, KS = 5, PAD = 1, TH = 20;
    constexpr int CIN = 64, COUT = 32;
    constexpr int Hin = 70, Win = 70, Hout = 68, Wout = 68;
    __shared__ float tile[TH][TH + 1];
    const int n = blockIdx.x / 25;
    const int t = blockIdx.x % 25;
    const int ty0 = (t / 5) * TS;
    const int tx0 = (t % 5) * TS;
    const int tid = threadIdx.x;
    const int lx = tid & 15, ly = tid >> 4;

    float acc[COUT];
#pragma unroll
    for (int c = 0; c < COUT; ++c) acc[c] = 0.f;

    for (int ci = 0; ci < CIN; ++ci) {
        const float sv = slots[n * 64 + ci];
        const float w0 = dpw[ci], w1 = dpw[64 + ci], w2 = dpw[128 + ci], w3 = dpw[192 + ci];
        const float bb = dpb[ci];
        for (int idx = tid; idx < TH * TH; idx += 256) {
            int r = idx / TH, c = idx % TH;
            int gy = ty0 + r - PAD, gx = tx0 + c - PAD;
            float vv = 0.f;
            if (gy >= 0 && gy < Hin && gx >= 0 && gx < Win) {
                float fy = gy * (1.f / 69.f), fx = gx * (1.f / 69.f);
                vv = sv + (1.f - fy) * w0 + fy * w1 + fx * w2 + (1.f - fx) * w3 + bb;
            }
            tile[r][c] = vv;
        }
        __syncthreads();
        float val[KS * KS];
#pragma unroll
        for (int ky = 0; ky < KS; ++ky)
#pragma unroll
            for (int kx = 0; kx < KS; ++kx)
                val[ky * KS + kx] = tile[ly + ky][lx + kx];
#pragma unroll
        for (int co = 0; co < COUT; ++co) {
            const float* wc = wts + ((size_t)co * CIN + ci) * (KS * KS);
            float a = acc[co];
#pragma unroll
            for (int tt = 0; tt < KS * KS; ++tt)
                a = fmaf(val[tt], wc[tt], a);
            acc[co] = a;
        }
        __syncthreads();
    }
    const int oy = ty0 + ly, ox = tx0 + lx;
    if (oy < Hout && ox < Wout) {
        float* ob = out + (size_t)n * COUT * Hout * Wout + oy * Wout + ox;
#pragma unroll
        for (int co = 0; co < COUT; ++co) {
            float vv = fmaxf(acc[co] + bias[co], 0.f);
            ob[(size_t)co * Hout * Wout] = vv;
        }
    }
}

// ---------------- encoder tail: +pe, LN, fc1-relu-fc2, k/v ----------------
// one block per (b, y) row; wave per pixel group, lane = channel.
__global__ __launch_bounds__(256) void encoder_feat(
    const float* __restrict__ h4,   // [32][64][64][64] NCHW (conv4 out, relu'd)
    const float* __restrict__ epw, const float* __restrict__ epb,
    const float* __restrict__ ln1g, const float* __restrict__ ln1b,
    const float* __restrict__ fc1w, const float* __restrict__ fc1b,
    const float* __restrict__ fc2w, const float* __restrict__ fc2b,
    const float* __restrict__ kw, const float* __restrict__ vw,
    float* __restrict__ kout, float* __restrict__ vout)
{
    __shared__ float tile[64][65];
    const int b = blockIdx.x >> 6;
    const int y = blockIdx.x & 63;
    const int tid = threadIdx.x;
    const float* hb = h4 + (size_t)b * 64 * 4096 + y * 64;
#pragma unroll
    for (int rep = 0; rep < 16; ++rep) {
        int c = rep * 4 + (tid >> 6);
        int x = tid & 63;
        tile[x][c] = hb[(size_t)c * 4096 + x];
    }
    __syncthreads();
    const int lane = tid & 63, wv = tid >> 6;
    const float fy = y * (1.f / 63.f);
    const float pe_a = (1.f - fy) * epw[lane] + fy * epw[64 + lane] + epb[lane];
    const float pe_c = epw[128 + lane];
    const float pe_d = epw[192 + lane];
    for (int px = wv; px < 64; px += 4) {
        const float fx = px * (1.f / 63.f);
        float f = tile[px][lane] + pe_a + fx * pe_c + (1.f - fx) * pe_d;
        // layernorm over 64 channels
        float m = wave_sum(f) * (1.f / 64.f);
        float d = f - m;
        float var = wave_sum(d * d) * (1.f / 64.f);
        float fl = d * rsqrtf(var + 1e-5f) * ln1g[lane] + ln1b[lane];
        // fc1 + relu
        float a1 = fc1b[lane];
        for (int c = 0; c < 64; ++c) a1 = fmaf(__shfl(fl, c, 64), fc1w[c * 64 + lane], a1);
        a1 = fmaxf(a1, 0.f);
        // fc2
        float a2 = fc2b[lane];
        for (int c = 0; c < 64; ++c) a2 = fmaf(__shfl(a1, c, 64), fc2w[c * 64 + lane], a2);
        // k, v
        float kk = 0.f, vv = 0.f;
        for (int c = 0; c < 64; ++c) {
            float s = __shfl(a2, c, 64);
            kk = fmaf(s, kw[c * 64 + lane], kk);
            vv = fmaf(s, vw[c * 64 + lane], vv);
        }
        size_t o = (((size_t)b * 4096) + y * 64 + px) * 64 + lane;
        kout[o] = kk;
        vout[o] = vv;
    }
}

// ---------------- slot init ----------------
__global__ __launch_bounds__(256) void slot_init(
    const float* __restrict__ noise, const float* __restrict__ init_slots,
    float* __restrict__ slots)
{
    int i = blockIdx.x * 256 + threadIdx.x;
    if (i < 224 * 64) {
        int z = i & 63;
        float loc = init_slots[z];
        float sp = init_slots[64 + z];
        float spl = log1pf(expf(sp));
        slots[i] = loc + spl * noise[i];
    }
}

// ---------------- q = LN(slots)@q_w * scale; also zero rowsum ----------------
__global__ __launch_bounds__(256) void compute_q(
    const float* __restrict__ slots, const float* __restrict__ lnsg,
    const float* __restrict__ lnsb, const float* __restrict__ qw,
    float* __restrict__ qout, float* __restrict__ rowsum)
{
    const int tid = threadIdx.x;
    if (blockIdx.x == 0 && tid < 224) rowsum[tid] = 0.f;
    const int lane = tid & 63, wv = tid >> 6;
    const int n = blockIdx.x * 4 + wv;
    if (n < 224) {
        float s = slots[n * 64 + lane];
        float m = wave_sum(s) * (1.f / 64.f);
        float d = s - m;
        float var = wave_sum(d * d) * (1.f / 64.f);
        float x = d * rsqrtf(var + 1e-5f) * lnsg[lane] + lnsb[lane];
        float q = 0.f;
        for (int c = 0; c < 64; ++c) q = fmaf(__shfl(x, c, 64), qw[c * 64 + lane], q);
        qout[n * 64 + lane] = q * SCALE_;
    }
}

// ---------------- attention pass 1: dots, softmax over slots, rowsums ----------------
__global__ __launch_bounds__(256) void attn_pass1(
    const float* __restrict__ kbuf, const float* __restrict__ qbuf,
    float* __restrict__ attn, float* __restrict__ rowsum)
{
    __shared__ float qs[7][64];
    __shared__ float red[7][4];
    const int b = blockIdx.x >> 4;
    const int jb = (blockIdx.x & 15) * 256;
    const int tid = threadIdx.x;
    if (tid < 7 * 64) qs[tid / 64][tid % 64] = qbuf[b * 7 * 64 + tid];
    __syncthreads();
    const int j = jb + tid;
    float kr[64];
    const float* kp = kbuf + (((size_t)b * 4096) + j) * 64;
#pragma unroll
    for (int d4 = 0; d4 < 16; ++d4) {
        float4 kv = ((const float4*)kp)[d4];
        kr[d4 * 4 + 0] = kv.x; kr[d4 * 4 + 1] = kv.y;
        kr[d4 * 4 + 2] = kv.z; kr[d4 * 4 + 3] = kv.w;
    }
    float dots[7];
#pragma unroll
    for (int i = 0; i < 7; ++i) {
        float a = 0.f;
#pragma unroll
        for (int d = 0; d < 64; ++d) a = fmaf(kr[d], qs[i][d], a);
        dots[i] = a;
    }
    float mx = dots[0];
#pragma unroll
    for (int i = 1; i < 7; ++i) mx = fmaxf(mx, dots[i]);
    float sum = 0.f;
#pragma unroll
    for (int i = 0; i < 7; ++i) { dots[i] = expf(dots[i] - mx); sum += dots[i]; }
    const float inv = 1.f / sum;
#pragma unroll
    for (int i = 0; i < 7; ++i) {
        float a = dots[i] * inv + 1e-8f;
        dots[i] = a;
        attn[(((size_t)b * 7) + i) * 4096 + j] = a;
    }
    const int lane = tid & 63, wv = tid >> 6;
#pragma unroll
    for (int i = 0; i < 7; ++i) {
        float s = wave_sum(dots[i]);
        if (lane == 0) red[i][wv] = s;
    }
    __syncthreads();
    if (tid < 7) {
        float s = red[tid][0] + red[tid][1] + red[tid][2] + red[tid][3];
        atomicAdd(&rowsum[b * 7 + tid], s);
    }
}

// ---------------- attention pass 2: partial attn^T @ v ----------------
__global__ __launch_bounds__(256) void attn_pass2(
    const float* __restrict__ vbuf, const float* __restrict__ attn,
    float* __restrict__ part)   // [32][16][7][64]
{
    const int b = blockIdx.x >> 4;
    const int js = blockIdx.x & 15;
    const int tid = threadIdx.x;
    const int d = tid & 63, jc = tid >> 6;
    float acc[7];
#pragma unroll
    for (int i = 0; i < 7; ++i) acc[i] = 0.f;
    const int j0 = js * 256;
    for (int j = j0 + jc; j < j0 + 256; j += 4) {
        float av = vbuf[(((size_t)b * 4096) + j) * 64 + d];
#pragma unroll
        for (int i = 0; i < 7; ++i)
            acc[i] = fmaf(attn[(((size_t)b * 7) + i) * 4096 + j], av, acc[i]);
    }
    __shared__ float red[4][7][64];
#pragma unroll
    for (int i = 0; i < 7; ++i) red[jc][i][d] = acc[i];
    __syncthreads();
    if (tid < 7 * 64) {
        int i = tid / 64, dd = tid % 64;
        float s = red[0][i][dd] + red[1][i][dd] + red[2][i][dd] + red[3][i][dd];
        part[((((size_t)b * 16) + js) * 7 + i) * 64 + dd] = s;
    }
}

// ---------------- GRU + residual MLP, one wave per slot row ----------------
__global__ __launch_bounds__(64) void gru_mlp(
    float* __restrict__ slots, const float* __restrict__ part,
    const float* __restrict__ rowsum,
    const float* __restrict__ wih, const float* __restrict__ whh,
    const float* __restrict__ bih, const float* __restrict__ bhh,
    const float* __restrict__ lnfg, const float* __restrict__ lnfb,
    const float* __restrict__ m1w, const float* __restrict__ m1b,
    const float* __restrict__ m2w, const float* __restrict__ m2b)
{
    const int n = blockIdx.x;           // 0..223
    const int b = n / 7, i = n % 7;
    const int l = threadIdx.x;
    float upd = 0.f;
    for (int js = 0; js < 16; ++js)
        upd += part[((((size_t)b * 16) + js) * 7 + i) * 64 + l];
    upd /= rowsum[n];
    const float prev = slots[n * 64 + l];
    float gi0 = bih[l], gi1 = bih[64 + l], gi2 = bih[128 + l];
    float gh0 = bhh[l], gh1 = bhh[64 + l], gh2 = bhh[128 + l];
    for (int c = 0; c < 64; ++c) {
        float u = __shfl(upd, c, 64), p = __shfl(prev, c, 64);
        gi0 = fmaf(u, wih[l * 64 + c], gi0);
        gi1 = fmaf(u, wih[(64 + l) * 64 + c], gi1);
        gi2 = fmaf(u, wih[(128 + l) * 64 + c], gi2);
        gh0 = fmaf(p, whh[l * 64 + c], gh0);
        gh1 = fmaf(p, whh[(64 + l) * 64 + c], gh1);
        gh2 = fmaf(p, whh[(128 + l) * 64 + c], gh2);
    }
    float r  = 1.f / (1.f + expf(-(gi0 + gh0)));
    float zg = 1.f / (1.f + expf(-(gi1 + gh1)));
    float nn = tanhf(gi2 + r * gh2);
    float s = (1.f - zg) * nn + zg * prev;
    // residual MLP with layernorm
    float m = wave_sum(s) * (1.f / 64.f);
    float d = s - m;
    float var = wave_sum(d * d) * (1.f / 64.f);
    float x = d * rsqrtf(var + 1e-5f) * lnfg[l] + lnfb[l];
    float h0 = m1b[l], h1 = m1b[64 + l];
    for (int c = 0; c < 64; ++c) {
        float xv = __shfl(x, c, 64);
        h0 = fmaf(xv, m1w[c * 128 + l], h0);
        h1 = fmaf(xv, m1w[c * 128 + 64 + l], h1);
    }
    h0 = fmaxf(h0, 0.f); h1 = fmaxf(h1, 0.f);
    float o = m2b[l];
    for (int c = 0; c < 64; ++c) {
        o = fmaf(__shfl(h0, c, 64), m2w[c * 64 + l], o);
        o = fmaf(__shfl(h1, c, 64), m2w[(64 + c) * 64 + l], o);
    }
    slots[n * 64 + l] = s + o;
}

// ---------------- finalize: sigmoid, log_softmax over K, recon, mse ----------------
__global__ __launch_bounds__(256) void finalize_k(
    const float* __restrict__ dc4out,   // [224][4][4096]
    const float* __restrict__ inputs,   // [32][3][4096]
    float* __restrict__ out)
{
    const int tid = threadIdx.x;
    const int gp = blockIdx.x * 256 + tid;   // 0..131071
    const int b = gp >> 12, p = gp & 4095;
    float logit[7];
#pragma unroll
    for (int k = 0; k < 7; ++k)
        logit[k] = dc4out[(((size_t)(b * 7 + k)) * 4 + 3) * 4096 + p];
    float mx = logit[0];
#pragma unroll
    for (int k = 1; k < 7; ++k) mx = fmaxf(mx, logit[k]);
    float s = 0.f;
#pragma unroll
    for (int k = 0; k < 7; ++k) s += expf(logit[k] - mx);
    const float lse = mx + logf(s);
    float recon0 = 0.f, recon1 = 0.f, recon2 = 0.f;
    float* xl = out + 1;
    float* ml = out + 2752513;
#pragma unroll
    for (int k = 0; k < 7; ++k) {
        float lp = logit[k] - lse;
        ml[((size_t)(b * 7 + k)) * 4096 + p] = lp;
        float w = expf(lp);
        float x0 = 1.f / (1.f + expf(-dc4out[(((size_t)(b * 7 + k)) * 4 + 0) * 4096 + p]));
        float x1 = 1.f / (1.f + expf(-dc4out[(((size_t)(b * 7 + k)) * 4 + 1) * 4096 + p]));
        float x2 = 1.f / (1.f + expf(-dc4out[(((size_t)(b * 7 + k)) * 4 + 2) * 4096 + p]));
        xl[(((size_t)(b * 7 + k)) * 3 + 0) * 4096 + p] = x0;
        xl[(((size_t)(b * 7 + k)) * 3 + 1) * 4096 + p] = x1;
        xl[(((size_t)(b * 7 + k)) * 3 + 2) * 4096 + p] = x2;
        recon0 = fmaf(x0, w, recon0);
        recon1 = fmaf(x1, w, recon1);
        recon2 = fmaf(x2, w, recon2);
    }
    float err = 0.f;
    {
        float xo = (inputs[((size_t)b * 3 + 0) * 4096 + p] + 1.f) * 0.5f;
        float dd = xo - recon0; err += dd * dd;
        xo = (inputs[((size_t)b * 3 + 1) * 4096 + p] + 1.f) * 0.5f;
        dd = xo - recon1; err += dd * dd;
        xo = (inputs[((size_t)b * 3 + 2) * 4096 + p] + 1.f) * 0.5f;
        dd = xo - recon2; err += dd * dd;
    }
    float wsum = wave_sum(err);
    __shared__ float red[4];
    const int lane = tid & 63, wv = tid >> 6;
    if (lane == 0) red[wv] = wsum;
    __syncthreads();
    if (tid == 0) atomicAdd(out, (red[0] + red[1] + red[2] + red[3]) * (1.f / 32.f));
}

__global__ void zero_mse(float* out) { if (threadIdx.x == 0) out[0] = 0.f; }

__global__ __launch_bounds__(256) void copy_slots(const float* __restrict__ slots,
                                                  float* __restrict__ out)
{
    int i = blockIdx.x * 256 + threadIdx.x;
    if (i < 14336) out[3670017 + i] = slots[i];
}

// ---------------- launch ----------------
extern "C" void kernel_launch(void* const* d_in, const int* in_sizes, int n_in,
                              void* d_out, int out_size, void* d_ws, size_t ws_size,
                              hipStream_t stream) {
    (void)in_sizes; (void)n_in; (void)out_size; (void)ws_size;
    const float* inputs = (const float*)d_in[0];
    const float* noise  = (const float*)d_in[1];
    const float* epw  = (const float*)d_in[2];
    const float* epb  = (const float*)d_in[3];
    const float* ec1w = (const float*)d_in[4];
    const float* ec1b = (const float*)d_in[5];
    const float* ec2w = (const float*)d_in[6];
    const float* ec2b = (const float*)d_in[7];
    const float* ec3w = (const float*)d_in[8];
    const float* ec3b = (const float*)d_in[9];
    const float* ec4w = (const float*)d_in[10];
    const float* ec4b = (const float*)d_in[11];
    const float* ln1g = (const float*)d_in[12];
    const float* ln1b = (const float*)d_in[13];
    const float* fc1w = (const float*)d_in[14];
    const float* fc1b = (const float*)d_in[15];
    const float* fc2w = (const float*)d_in[16];
    const float* fc2b = (const float*)d_in[17];
    const float* lnsg = (const float*)d_in[18];
    const float* lnsb = (const float*)d_in[19];
    const float* lnfg = (const float*)d_in[20];
    const float* lnfb = (const float*)d_in[21];
    const float* qw   = (const float*)d_in[22];
    const float* kw   = (const float*)d_in[23];
    const float* vw   = (const float*)d_in[24];
    const float* m1w  = (const float*)d_in[25];
    const float* m1b  = (const float*)d_in[26];
    const float* m2w  = (const float*)d_in[27];
    const float* m2b  = (const float*)d_in[28];
    const float* wih  = (const float*)d_in[29];
    const float* whh  = (const float*)d_in[30];
    const float* bih  = (const float*)d_in[31];
    const float* bhh  = (const float*)d_in[32];
    const float* init_slots = (const float*)d_in[33];
    const float* dpw  = (const float*)d_in[34];
    const float* dpb  = (const float*)d_in[35];
    const float* dc1w = (const float*)d_in[36];
    const float* dc1b = (const float*)d_in[37];
    const float* dc2w = (const float*)d_in[38];
    const float* dc2b = (const float*)d_in[39];
    const float* dc3w = (const float*)d_in[40];
    const float* dc3b = (const float*)d_in[41];
    const float* dc4w = (const float*)d_in[42];
    const float* dc4b = (const float*)d_in[43];

    float* ws    = (float*)d_ws;
    float* bufA  = ws + WS_BUFA;
    float* bufB  = ws + WS_BUFB;
    float* bufC  = ws + WS_BUFC;
    float* attn  = ws + WS_ATTN;
    float* part  = ws + WS_PART;
    float* qbuf  = ws + WS_Q;
    float* slots = ws + WS_SLOT;
    float* rowsum = ws + WS_ROW;
    float* out = (float*)d_out;

    // ---- encoder ----
    conv_direct<3, 64, 5, 2><<<512, 256, 0, stream>>>(inputs, ec1w, ec1b, bufA, 64, 64, 64, 64, 4, 4, 1);
    conv_direct<64, 64, 5, 2><<<512, 256, 0, stream>>>(bufA, ec2w, ec2b, bufB, 64, 64, 64, 64, 4, 4, 1);
    conv_direct<64, 64, 5, 2><<<512, 256, 0, stream>>>(bufB, ec3w, ec3b, bufA, 64, 64, 64, 64, 4, 4, 1);
    conv_direct<64, 64, 5, 2><<<512, 256, 0, stream>>>(bufA, ec4w, ec4b, bufB, 64, 64, 64, 64, 4, 4, 1);
    encoder_feat<<<2048, 256, 0, stream>>>(bufB, epw, epb, ln1g, ln1b, fc1w, fc1b,
                                           fc2w, fc2b, kw, vw, bufA, bufC);
    slot_init<<<56, 256, 0, stream>>>(noise, init_slots, slots);

    // ---- 3 slot-attention iterations ----
    for (int it = 0; it < 3; ++it) {
        compute_q<<<56, 256, 0, stream>>>(slots, lnsg, lnsb, qw, qbuf, rowsum);
        attn_pass1<<<512, 256, 0, stream>>>(bufA, qbuf, attn, rowsum);
        attn_pass2<<<512, 256, 0, stream>>>(bufC, attn, part);
        gru_mlp<<<224, 64, 0, stream>>>(slots, part, rowsum, wih, whh, bih, bhh,
                                        lnfg, lnfb, m1w, m1b, m2w, m2b);
    }

    // ---- decoder, 4 chunks of 56 images ----
    for (int ch = 0; ch < 4; ++ch) {
        const float* sl = slots + (size_t)ch * 56 * 64;
        float* d4o = bufC + (size_t)ch * 56 * 4 * 4096;
        conv_dec1<<<1400, 256, 0, stream>>>(sl, dpw, dpb, dc1w, dc1b, bufA);
        conv_direct<32, 32, 5, 1><<<1400, 256, 0, stream>>>(bufA, dc2w, dc2b, bufB, 68, 68, 66, 66, 5, 5, 1);
        conv_direct<32, 32, 5, 1><<<896, 256, 0, stream>>>(bufB, dc3w, dc3b, bufA, 66, 66, 64, 64, 4, 4, 1);
        conv_direct<32, 4, 3, 1><<<896, 256, 0, stream>>>(bufA, dc4w, dc4b, d4o, 64, 64, 64, 64, 4, 4, 0);
    }

    // ---- outputs ----
    zero_mse<<<1, 64, 0, stream>>>(out);
    finalize_k<<<512, 256, 0, stream>>>(bufC, inputs, out);
    copy_slots<<<56, 256, 0, stream>>>(slots, out);
}

// Round 2
// 1365.042 us; speedup vs baseline: 7.1230x; 7.1230x over previous
//
#include <hip/hip_runtime.h>
#include <math.h>

typedef short bf16x8 __attribute__((ext_vector_type(8)));
typedef float f32x4 __attribute__((ext_vector_type(4)));

// workspace layout (float offsets)
#define WS_B0   0u           // 4194304 floats = 8388608 bf16 : enc ping / dec ping
#define WS_B1   4194304u     // 4194304 floats : enc pong / dec pong
#define WS_K    8388608u     // 8388608 floats : k  (fp32)
#define WS_V    16777216u    // 8388608 floats : v (fp32); decode: dc4out fp32 at +0, packed wts at +4194304
#define WS_ATTN 25165824u    // 917504
#define WS_PART 26083328u    // 229376
#define WS_Q    26312704u    // 14336
#define WS_SLOT 26327040u    // 14336
#define WS_ROW  26341376u    // 224
#define SCALE_ 0.125f

__device__ __forceinline__ float wave_sum(float v) {
#pragma unroll
    for (int m = 32; m >= 1; m >>= 1) v += __shfl_xor(v, m, 64);
    return v;
}
__device__ __forceinline__ unsigned short f2bf(float f) {
    unsigned u = __float_as_uint(f);
    u = u + 0x7fffu + ((u >> 16) & 1u);
    return (unsigned short)(u >> 16);
}
__device__ __forceinline__ float bf2f(unsigned short h) {
    return __uint_as_float(((unsigned)h) << 16);
}

// ---------------- weight packing into B-fragment order ----------------
// wp[t*8+j] for t=(ch*NT+nt)*64+lane: B[k=cic*32+(lane>>4)*8+j][co=nt*16+(lane&15)]
// at tap (ky,kx); ch = tap*CPT+cic. Zeros for co >= COUT_STORE.
__global__ __launch_bounds__(256) void pack_weights(
    const float* __restrict__ w, unsigned short* __restrict__ wp,
    int CIN, int COUT_STORE, int KS, int NT, int total)
{
    int t = blockIdx.x * 256 + threadIdx.x;
    if (t >= total) return;
    int lane = t & 63;
    int nt = (t >> 6) % NT;
    int ch = t / (64 * NT);
    int CPT = CIN / 32;
    int cic = ch % CPT;
    int tap = ch / CPT;
    int ky = tap / KS, kx = tap % KS;
    int co = nt * 16 + (lane & 15);
    int k0 = cic * 32 + (lane >> 4) * 8;
    unsigned short v[8];
#pragma unroll
    for (int j = 0; j < 8; ++j) {
        int ci = k0 + j;
        float f = (co < COUT_STORE) ? w[((size_t)(co * CIN + ci) * KS + ky) * KS + kx] : 0.f;
        v[j] = f2bf(f);
    }
    *(uint4*)(wp + (size_t)t * 8) = *(uint4*)v;
}

// ---------------- MFMA implicit-GEMM conv ----------------
// in: NHWC bf16. out: NHWC (bf16 or fp32), NSTORE channels stored.
// LDS tile swizzle: channels of pixel column c rotated by c*8 (bank-uniform b128 reads).
template<int CIN, int COUT, int KS, int PAD, int NSTORE, int RELU, int OUTF32>
__global__ __launch_bounds__(256) void conv_mfma(
    const unsigned short* __restrict__ in, const unsigned short* __restrict__ wpack,
    const float* __restrict__ bias, void* __restrict__ outv,
    int Hin, int Win, int Hout, int Wout, int tilesX, int tilesY)
{
    constexpr int TS = 16, TH = TS + KS - 1;
    constexpr int NT = COUT / 16;
    constexpr int CPT = CIN / 32;
    constexpr int G8 = CIN / 8;
    __shared__ __align__(16) unsigned short tile[TH][TH][CIN];
    const int tpb = tilesX * tilesY;
    const int n = blockIdx.x / tpb;
    const int t = blockIdx.x % tpb;
    const int ty0 = (t / tilesX) * TS, tx0 = (t % tilesX) * TS;
    const int tid = threadIdx.x;

    // stage input tile (zero-padded), swizzled
    const unsigned short* inb = in + (size_t)n * Hin * Win * CIN;
    for (int idx = tid; idx < TH * TH * G8; idx += 256) {
        int g = idx % G8;
        int c = (idx / G8) % TH;
        int r = idx / (G8 * TH);
        int iy = ty0 - PAD + r, ix = tx0 - PAD + c;
        uint4 vv = make_uint4(0, 0, 0, 0);
        if (iy >= 0 && iy < Hin && ix >= 0 && ix < Win)
            vv = *(const uint4*)(inb + ((size_t)iy * Win + ix) * CIN + g * 8);
        int slot = (g * 8 + c * 8) % CIN;
        *(uint4*)&tile[r][c][slot] = vv;
    }
    __syncthreads();

    const int wv = tid >> 6, lane = tid & 63;
    const int q = lane >> 4, m = lane & 15;
    f32x4 acc[4][NT];
#pragma unroll
    for (int mt = 0; mt < 4; ++mt)
#pragma unroll
        for (int nt = 0; nt < NT; ++nt) acc[mt][nt] = (f32x4){0.f, 0.f, 0.f, 0.f};

    for (int tap = 0; tap < KS * KS; ++tap) {
        const int ky = tap / KS, kx = tap % KS;
        const int cbase = m + kx;
#pragma unroll
        for (int cic = 0; cic < CPT; ++cic) {
            const int ch = tap * CPT + cic;
            bf16x8 bfr[NT];
#pragma unroll
            for (int nt = 0; nt < NT; ++nt)
                bfr[nt] = *(const bf16x8*)(wpack + ((size_t)(ch * NT + nt) * 64 + lane) * 8);
            const int slot = (cic * 32 + q * 8 + cbase * 8) % CIN;
#pragma unroll
            for (int mt = 0; mt < 4; ++mt) {
                const int orow = wv * 4 + mt;
                bf16x8 afr = *(const bf16x8*)&tile[orow + ky][cbase][slot];
#pragma unroll
                for (int nt = 0; nt < NT; ++nt)
                    acc[mt][nt] = __builtin_amdgcn_mfma_f32_16x16x32_bf16(afr, bfr[nt], acc[mt][nt], 0, 0, 0);
            }
        }
    }

    // epilogue: D row = pixel x = q*4+reg, D col = co = m
#pragma unroll
    for (int nt = 0; nt < NT; ++nt) {
        const int co = nt * 16 + m;
        const float bv = (co < NSTORE) ? bias[co] : 0.f;
#pragma unroll
        for (int mt = 0; mt < 4; ++mt) {
            const int oy = ty0 + wv * 4 + mt;
#pragma unroll
            for (int j = 0; j < 4; ++j) {
                const int ox = tx0 + q * 4 + j;
                if (oy < Hout && ox < Wout && co < NSTORE) {
                    float v = acc[mt][nt][j] + bv;
                    if (RELU) v = fmaxf(v, 0.f);
                    size_t o = (((size_t)n * Hout + oy) * Wout + ox) * NSTORE + co;
                    if (OUTF32) ((float*)outv)[o] = v;
                    else ((unsigned short*)outv)[o] = f2bf(v);
                }
            }
        }
    }
}

// ---------------- decoder conv1: LDS tile synthesized on the fly ----------------
__global__ __launch_bounds__(256) void conv_dec1_mfma(
    const float* __restrict__ slots, const float* __restrict__ dpw,
    const float* __restrict__ dpb, const unsigned short* __restrict__ wpack,
    const float* __restrict__ bias, unsigned short* __restrict__ out)
{
    constexpr int KS = 5, PAD = 1, TH = 20, CIN = 64, NT = 2, CPT = 2;
    constexpr int Hin = 70, Win = 70, Hout = 68, Wout = 68;
    __shared__ __align__(16) unsigned short tile[TH][TH][CIN];
    const int n = blockIdx.x / 25;
    const int t = blockIdx.x % 25;
    const int ty0 = (t / 5) * 16, tx0 = (t % 5) * 16;
    const int tid = threadIdx.x;

    for (int idx = tid; idx < TH * TH * 8; idx += 256) {
        int g = idx % 8;
        int c = (idx / 8) % TH;
        int r = idx / (8 * TH);
        int iy = ty0 - PAD + r, ix = tx0 - PAD + c;
        unsigned short vv[8];
        if (iy >= 0 && iy < Hin && ix >= 0 && ix < Win) {
            float fy = iy * (1.f / 69.f), fx = ix * (1.f / 69.f);
#pragma unroll
            for (int j = 0; j < 8; ++j) {
                int ci = g * 8 + j;
                float v = slots[n * 64 + ci] + (1.f - fy) * dpw[ci] + fy * dpw[64 + ci]
                          + fx * dpw[128 + ci] + (1.f - fx) * dpw[192 + ci] + dpb[ci];
                vv[j] = f2bf(v);
            }
        } else {
#pragma unroll
            for (int j = 0; j < 8; ++j) vv[j] = 0;
        }
        int slot = (g * 8 + c * 8) % CIN;
        *(uint4*)&tile[r][c][slot] = *(uint4*)vv;
    }
    __syncthreads();

    const int wv = tid >> 6, lane = tid & 63;
    const int q = lane >> 4, m = lane & 15;
    f32x4 acc[4][NT];
#pragma unroll
    for (int mt = 0; mt < 4; ++mt)
#pragma unroll
        for (int nt = 0; nt < NT; ++nt) acc[mt][nt] = (f32x4){0.f, 0.f, 0.f, 0.f};

    for (int tap = 0; tap < KS * KS; ++tap) {
        const int ky = tap / KS, kx = tap % KS;
        const int cbase = m + kx;
#pragma unroll
        for (int cic = 0; cic < CPT; ++cic) {
            const int ch = tap * CPT + cic;
            bf16x8 bfr[NT];
#pragma unroll
            for (int nt = 0; nt < NT; ++nt)
                bfr[nt] = *(const bf16x8*)(wpack + ((size_t)(ch * NT + nt) * 64 + lane) * 8);
            const int slot = (cic * 32 + q * 8 + cbase * 8) % CIN;
#pragma unroll
            for (int mt = 0; mt < 4; ++mt) {
                const int orow = wv * 4 + mt;
                bf16x8 afr = *(const bf16x8*)&tile[orow + ky][cbase][slot];
#pragma unroll
                for (int nt = 0; nt < NT; ++nt)
                    acc[mt][nt] = __builtin_amdgcn_mfma_f32_16x16x32_bf16(afr, bfr[nt], acc[mt][nt], 0, 0, 0);
            }
        }
    }
#pragma unroll
    for (int nt = 0; nt < NT; ++nt) {
        const int co = nt * 16 + m;
        const float bv = bias[co];
#pragma unroll
        for (int mt = 0; mt < 4; ++mt) {
            const int oy = ty0 + wv * 4 + mt;
#pragma unroll
            for (int j = 0; j < 4; ++j) {
                const int ox = tx0 + q * 4 + j;
                if (oy < Hout && ox < Wout) {
                    float v = fmaxf(acc[mt][nt][j] + bv, 0.f);
                    out[(((size_t)n * Hout + oy) * Wout + ox) * 32 + co] = f2bf(v);
                }
            }
        }
    }
}

// ---------------- encoder conv1 (CIN=3, fp32 direct, NHWC bf16 out) ----------------
__global__ __launch_bounds__(256) void conv_ec1(
    const float* __restrict__ in, const float* __restrict__ wts,
    const float* __restrict__ bias, unsigned short* __restrict__ out)
{
    __shared__ float tile[3][20][21];
    const int n = blockIdx.x >> 4;
    const int t = blockIdx.x & 15;
    const int ty0 = (t >> 2) * 16, tx0 = (t & 3) * 16;
    const int tid = threadIdx.x;
    for (int idx = tid; idx < 1200; idx += 256) {
        int ci = idx / 400, rc = idx % 400;
        int r = rc / 20, c = rc % 20;
        int gy = ty0 + r - 2, gx = tx0 + c - 2;
        float v = 0.f;
        if (gy >= 0 && gy < 64 && gx >= 0 && gx < 64)
            v = in[((size_t)n * 3 + ci) * 4096 + gy * 64 + gx];
        tile[ci][r][c] = v;
    }
    __syncthreads();
    const int lx = tid & 15, ly = tid >> 4;
    float acc[64];
#pragma unroll
    for (int co = 0; co < 64; ++co) acc[co] = bias[co];
    for (int ci = 0; ci < 3; ++ci) {
        float val[25];
#pragma unroll
        for (int ky = 0; ky < 5; ++ky)
#pragma unroll
            for (int kx = 0; kx < 5; ++kx) val[ky * 5 + kx] = tile[ci][ly + ky][lx + kx];
#pragma unroll
        for (int co = 0; co < 64; ++co) {
            const float* wc = wts + (size_t)(co * 3 + ci) * 25;
            float a = acc[co];
#pragma unroll
            for (int tt = 0; tt < 25; ++tt) a = fmaf(val[tt], wc[tt], a);
            acc[co] = a;
        }
    }
    unsigned short tmp[64];
#pragma unroll
    for (int co = 0; co < 64; ++co) tmp[co] = f2bf(fmaxf(acc[co], 0.f));
    uint4* ob = (uint4*)(out + (((size_t)n * 64 + ty0 + ly) * 64 + tx0 + lx) * 64);
#pragma unroll
    for (int i = 0; i < 8; ++i) ob[i] = ((uint4*)tmp)[i];
}

// ---------------- encoder tail: +pe, LN, fc1-relu-fc2, k/v (NHWC bf16 in) ----------------
__global__ __launch_bounds__(256) void encoder_feat(
    const unsigned short* __restrict__ h4,
    const float* __restrict__ epw, const float* __restrict__ epb,
    const float* __restrict__ ln1g, const float* __restrict__ ln1b,
    const float* __restrict__ fc1w, const float* __restrict__ fc1b,
    const float* __restrict__ fc2w, const float* __restrict__ fc2b,
    const float* __restrict__ kw, const float* __restrict__ vw,
    float* __restrict__ kout, float* __restrict__ vout)
{
    const int b = blockIdx.x >> 6;
    const int y = blockIdx.x & 63;
    const int tid = threadIdx.x;
    const int lane = tid & 63, wv = tid >> 6;
    const float fy = y * (1.f / 63.f);
    const float pe_a = (1.f - fy) * epw[lane] + fy * epw[64 + lane] + epb[lane];
    const float pe_c = epw[128 + lane];
    const float pe_d = epw[192 + lane];
    for (int px = wv; px < 64; px += 4) {
        const float fx = px * (1.f / 63.f);
        float f = bf2f(h4[(((size_t)b * 64 + y) * 64 + px) * 64 + lane])
                  + pe_a + fx * pe_c + (1.f - fx) * pe_d;
        float mm = wave_sum(f) * (1.f / 64.f);
        float d = f - mm;
        float var = wave_sum(d * d) * (1.f / 64.f);
        float fl = d * rsqrtf(var + 1e-5f) * ln1g[lane] + ln1b[lane];
        float a1 = fc1b[lane];
        for (int c = 0; c < 64; ++c) a1 = fmaf(__shfl(fl, c, 64), fc1w[c * 64 + lane], a1);
        a1 = fmaxf(a1, 0.f);
        float a2 = fc2b[lane];
        for (int c = 0; c < 64; ++c) a2 = fmaf(__shfl(a1, c, 64), fc2w[c * 64 + lane], a2);
        float kk = 0.f, vv = 0.f;
        for (int c = 0; c < 64; ++c) {
            float s = __shfl(a2, c, 64);
            kk = fmaf(s, kw[c * 64 + lane], kk);
            vv = fmaf(s, vw[c * 64 + lane], vv);
        }
        size_t o = (((size_t)b * 4096) + y * 64 + px) * 64 + lane;
        kout[o] = kk;
        vout[o] = vv;
    }
}

// ---------------- slot init ----------------
__global__ __launch_bounds__(256) void slot_init(
    const float* __restrict__ noise, const float* __restrict__ init_slots,
    float* __restrict__ slots)
{
    int i = blockIdx.x * 256 + threadIdx.x;
    if (i < 224 * 64) {
        int z = i & 63;
        float spl = log1pf(expf(init_slots[64 + z]));
        slots[i] = init_slots[z] + spl * noise[i];
    }
}

// ---------------- q = LN(slots)@q_w * scale; zero rowsum ----------------
__global__ __launch_bounds__(256) void compute_q(
    const float* __restrict__ slots, const float* __restrict__ lnsg,
    const float* __restrict__ lnsb, const float* __restrict__ qw,
    float* __restrict__ qout, float* __restrict__ rowsum)
{
    const int tid = threadIdx.x;
    if (blockIdx.x == 0 && tid < 224) rowsum[tid] = 0.f;
    const int lane = tid & 63, wv = tid >> 6;
    const int n = blockIdx.x * 4 + wv;
    if (n < 224) {
        float s = slots[n * 64 + lane];
        float m = wave_sum(s) * (1.f / 64.f);
        float d = s - m;
        float var = wave_sum(d * d) * (1.f / 64.f);
        float x = d * rsqrtf(var + 1e-5f) * lnsg[lane] + lnsb[lane];
        float q = 0.f;
        for (int c = 0; c < 64; ++c) q = fmaf(__shfl(x, c, 64), qw[c * 64 + lane], q);
        qout[n * 64 + lane] = q * SCALE_;
    }
}

// ---------------- attention pass 1 ----------------
__global__ __launch_bounds__(256) void attn_pass1(
    const float* __restrict__ kbuf, const float* __restrict__ qbuf,
    float* __restrict__ attn, float* __restrict__ rowsum)
{
    __shared__ float qs[7][64];
    __shared__ float red[7][4];
    const int b = blockIdx.x >> 4;
    const int jb = (blockIdx.x & 15) * 256;
    const int tid = threadIdx.x;
    if (tid < 7 * 64) qs[tid / 64][tid % 64] = qbuf[b * 7 * 64 + tid];
    __syncthreads();
    const int j = jb + tid;
    float kr[64];
    const float* kp = kbuf + (((size_t)b * 4096) + j) * 64;
#pragma unroll
    for (int d4 = 0; d4 < 16; ++d4) {
        float4 kv = ((const float4*)kp)[d4];
        kr[d4 * 4 + 0] = kv.x; kr[d4 * 4 + 1] = kv.y;
        kr[d4 * 4 + 2] = kv.z; kr[d4 * 4 + 3] = kv.w;
    }
    float dots[7];
#pragma unroll
    for (int i = 0; i < 7; ++i) {
        float a = 0.f;
#pragma unroll
        for (int d = 0; d < 64; ++d) a = fmaf(kr[d], qs[i][d], a);
        dots[i] = a;
    }
    float mx = dots[0];
#pragma unroll
    for (int i = 1; i < 7; ++i) mx = fmaxf(mx, dots[i]);
    float sum = 0.f;
#pragma unroll
    for (int i = 0; i < 7; ++i) { dots[i] = expf(dots[i] - mx); sum += dots[i]; }
    const float inv = 1.f / sum;
#pragma unroll
    for (int i = 0; i < 7; ++i) {
        float a = dots[i] * inv + 1e-8f;
        dots[i] = a;
        attn[(((size_t)b * 7) + i) * 4096 + j] = a;
    }
    const int lane = tid & 63, wv = tid >> 6;
#pragma unroll
    for (int i = 0; i < 7; ++i) {
        float s = wave_sum(dots[i]);
        if (lane == 0) red[i][wv] = s;
    }
    __syncthreads();
    if (tid < 7) {
        float s = red[tid][0] + red[tid][1] + red[tid][2] + red[tid][3];
        atomicAdd(&rowsum[b * 7 + tid], s);
    }
}

// ---------------- attention pass 2 ----------------
__global__ __launch_bounds__(256) void attn_pass2(
    const float* __restrict__ vbuf, const float* __restrict__ attn,
    float* __restrict__ part)
{
    const int b = blockIdx.x >> 4;
    const int js = blockIdx.x & 15;
    const int tid = threadIdx.x;
    const int d = tid & 63, jc = tid >> 6;
    float acc[7];
#pragma unroll
    for (int i = 0; i < 7; ++i) acc[i] = 0.f;
    const int j0 = js * 256;
    for (int j = j0 + jc; j < j0 + 256; j += 4) {
        float av = vbuf[(((size_t)b * 4096) + j) * 64 + d];
#pragma unroll
        for (int i = 0; i < 7; ++i)
            acc[i] = fmaf(attn[(((size_t)b * 7) + i) * 4096 + j], av, acc[i]);
    }
    __shared__ float red[4][7][64];
#pragma unroll
    for (int i = 0; i < 7; ++i) red[jc][i][d] = acc[i];
    __syncthreads();
    if (tid < 7 * 64) {
        int i = tid / 64, dd = tid % 64;
        float s = red[0][i][dd] + red[1][i][dd] + red[2][i][dd] + red[3][i][dd];
        part[((((size_t)b * 16) + js) * 7 + i) * 64 + dd] = s;
    }
}

// ---------------- GRU + residual MLP ----------------
__global__ __launch_bounds__(64) void gru_mlp(
    float* __restrict__ slots, const float* __restrict__ part,
    const float* __restrict__ rowsum,
    const float* __restrict__ wih, const float* __restrict__ whh,
    const float* __restrict__ bih, const float* __restrict__ bhh,
    const float* __restrict__ lnfg, const float* __restrict__ lnfb,
    const float* __restrict__ m1w, const float* __restrict__ m1b,
    const float* __restrict__ m2w, const float* __restrict__ m2b)
{
    const int n = blockIdx.x;
    const int b = n / 7, i = n % 7;
    const int l = threadIdx.x;
    float upd = 0.f;
    for (int js = 0; js < 16; ++js)
        upd += part[((((size_t)b * 16) + js) * 7 + i) * 64 + l];
    upd /= rowsum[n];
    const float prev = slots[n * 64 + l];
    float gi0 = bih[l], gi1 = bih[64 + l], gi2 = bih[128 + l];
    float gh0 = bhh[l], gh1 = bhh[64 + l], gh2 = bhh[128 + l];
    for (int c = 0; c < 64; ++c) {
        float u = __shfl(upd, c, 64), p = __shfl(prev, c, 64);
        gi0 = fmaf(u, wih[l * 64 + c], gi0);
        gi1 = fmaf(u, wih[(64 + l) * 64 + c], gi1);
        gi2 = fmaf(u, wih[(128 + l) * 64 + c], gi2);
        gh0 = fmaf(p, whh[l * 64 + c], gh0);
        gh1 = fmaf(p, whh[(64 + l) * 64 + c], gh1);
        gh2 = fmaf(p, whh[(128 + l) * 64 + c], gh2);
    }
    float r  = 1.f / (1.f + expf(-(gi0 + gh0)));
    float zg = 1.f / (1.f + expf(-(gi1 + gh1)));
    float nn = tanhf(gi2 + r * gh2);
    float s = (1.f - zg) * nn + zg * prev;
    float m = wave_sum(s) * (1.f / 64.f);
    float d = s - m;
    float var = wave_sum(d * d) * (1.f / 64.f);
    float x = d * rsqrtf(var + 1e-5f) * lnfg[l] + lnfb[l];
    float h0 = m1b[l], h1 = m1b[64 + l];
    for (int c = 0; c < 64; ++c) {
        float xv = __shfl(x, c, 64);
        h0 = fmaf(xv, m1w[c * 128 + l], h0);
        h1 = fmaf(xv, m1w[c * 128 + 64 + l], h1);
    }
    h0 = fmaxf(h0, 0.f); h1 = fmaxf(h1, 0.f);
    float o = m2b[l];
    for (int c = 0; c < 64; ++c) {
        o = fmaf(__shfl(h0, c, 64), m2w[c * 64 + l], o);
        o = fmaf(__shfl(h1, c, 64), m2w[(64 + c) * 64 + l], o);
    }
    slots[n * 64 + l] = s + o;
}

// ---------------- finalize (dc4out NHWC fp32 [img][p][4]) ----------------
__global__ __launch_bounds__(256) void finalize_k(
    const float* __restrict__ dc4out, const float* __restrict__ inputs,
    float* __restrict__ out)
{
    const int tid = threadIdx.x;
    const int gp = blockIdx.x * 256 + tid;
    const int b = gp >> 12, p = gp & 4095;
    float4 o4[7];
#pragma unroll
    for (int k = 0; k < 7; ++k)
        o4[k] = ((const float4*)dc4out)[(size_t)(b * 7 + k) * 4096 + p];
    float mx = o4[0].w;
#pragma unroll
    for (int k = 1; k < 7; ++k) mx = fmaxf(mx, o4[k].w);
    float s = 0.f;
#pragma unroll
    for (int k = 0; k < 7; ++k) s += expf(o4[k].w - mx);
    const float lse = mx + logf(s);
    float recon0 = 0.f, recon1 = 0.f, recon2 = 0.f;
    float* xl = out + 1;
    float* ml = out + 2752513;
#pragma unroll
    for (int k = 0; k < 7; ++k) {
        float lp = o4[k].w - lse;
        ml[((size_t)(b * 7 + k)) * 4096 + p] = lp;
        float w = expf(lp);
        float x0 = 1.f / (1.f + expf(-o4[k].x));
        float x1 = 1.f / (1.f + expf(-o4[k].y));
        float x2 = 1.f / (1.f + expf(-o4[k].z));
        xl[(((size_t)(b * 7 + k)) * 3 + 0) * 4096 + p] = x0;
        xl[(((size_t)(b * 7 + k)) * 3 + 1) * 4096 + p] = x1;
        xl[(((size_t)(b * 7 + k)) * 3 + 2) * 4096 + p] = x2;
        recon0 = fmaf(x0, w, recon0);
        recon1 = fmaf(x1, w, recon1);
        recon2 = fmaf(x2, w, recon2);
    }
    float err = 0.f;
    {
        float xo = (inputs[((size_t)b * 3 + 0) * 4096 + p] + 1.f) * 0.5f;
        float dd = xo - recon0; err += dd * dd;
        xo = (inputs[((size_t)b * 3 + 1) * 4096 + p] + 1.f) * 0.5f;
        dd = xo - recon1; err += dd * dd;
        xo = (inputs[((size_t)b * 3 + 2) * 4096 + p] + 1.f) * 0.5f;
        dd = xo - recon2; err += dd * dd;
    }
    float wsum = wave_sum(err);
    __shared__ float red[4];
    const int lane = tid & 63, wv = tid >> 6;
    if (lane == 0) red[wv] = wsum;
    __syncthreads();
    if (tid == 0) atomicAdd(out, (red[0] + red[1] + red[2] + red[3]) * (1.f / 32.f));
}

__global__ void zero_mse(float* out) { if (threadIdx.x == 0) out[0] = 0.f; }

__global__ __launch_bounds__(256) void copy_slots(const float* __restrict__ slots,
                                                  float* __restrict__ out)
{
    int i = blockIdx.x * 256 + threadIdx.x;
    if (i < 14336) out[3670017 + i] = slots[i];
}

// ---------------- launch ----------------
extern "C" void kernel_launch(void* const* d_in, const int* in_sizes, int n_in,
                              void* d_out, int out_size, void* d_ws, size_t ws_size,
                              hipStream_t stream) {
    (void)in_sizes; (void)n_in; (void)out_size; (void)ws_size;
    const float* inputs = (const float*)d_in[0];
    const float* noise  = (const float*)d_in[1];
    const float* epw  = (const float*)d_in[2];
    const float* epb  = (const float*)d_in[3];
    const float* ec1w = (const float*)d_in[4];
    const float* ec1b = (const float*)d_in[5];
    const float* ec2w = (const float*)d_in[6];
    const float* ec2b = (const float*)d_in[7];
    const float* ec3w = (const float*)d_in[8];
    const float* ec3b = (const float*)d_in[9];
    const float* ec4w = (const float*)d_in[10];
    const float* ec4b = (const float*)d_in[11];
    const float* ln1g = (const float*)d_in[12];
    const float* ln1b = (const float*)d_in[13];
    const float* fc1w = (const float*)d_in[14];
    const float* fc1b = (const float*)d_in[15];
    const float* fc2w = (const float*)d_in[16];
    const float* fc2b = (const float*)d_in[17];
    const float* lnsg = (const float*)d_in[18];
    const float* lnsb = (const float*)d_in[19];
    const float* lnfg = (const float*)d_in[20];
    const float* lnfb = (const float*)d_in[21];
    const float* qw   = (const float*)d_in[22];
    const float* kw   = (const float*)d_in[23];
    const float* vw   = (const float*)d_in[24];
    const float* m1w  = (const float*)d_in[25];
    const float* m1b  = (const float*)d_in[26];
    const float* m2w  = (const float*)d_in[27];
    const float* m2b  = (const float*)d_in[28];
    const float* wih  = (const float*)d_in[29];
    const float* whh  = (const float*)d_in[30];
    const float* bih  = (const float*)d_in[31];
    const float* bhh  = (const float*)d_in[32];
    const float* init_slots = (const float*)d_in[33];
    const float* dpw  = (const float*)d_in[34];
    const float* dpb  = (const float*)d_in[35];
    const float* dc1w = (const float*)d_in[36];
    const float* dc1b = (const float*)d_in[37];
    const float* dc2w = (const float*)d_in[38];
    const float* dc2b = (const float*)d_in[39];
    const float* dc3w = (const float*)d_in[40];
    const float* dc3b = (const float*)d_in[41];
    const float* dc4w = (const float*)d_in[42];
    const float* dc4b = (const float*)d_in[43];

    float* ws = (float*)d_ws;
    unsigned short* B0 = (unsigned short*)(ws + WS_B0);
    unsigned short* B1 = (unsigned short*)(ws + WS_B1);
    float* K = ws + WS_K;
    float* V = ws + WS_V;
    float* dc4out = V;                                    // overlay (decode phase)
    unsigned short* PK = (unsigned short*)(ws + WS_V + 4194304u);  // pack area (16MB into V)
    unsigned short* p_ec2 = PK, *p_ec3 = PK + 102400, *p_ec4 = PK + 204800;
    unsigned short* p_dc1 = PK, *p_dc2 = PK + 51200, *p_dc3 = PK + 76800, *p_dc4 = PK + 102400;
    float* attn  = ws + WS_ATTN;
    float* part  = ws + WS_PART;
    float* qbuf  = ws + WS_Q;
    float* slots = ws + WS_SLOT;
    float* rowsum = ws + WS_ROW;
    float* out = (float*)d_out;

    // ---- pack encoder weights (clobbered later by encoder_feat's V write) ----
    pack_weights<<<50, 256, 0, stream>>>(ec2w, p_ec2, 64, 64, 5, 4, 12800);
    pack_weights<<<50, 256, 0, stream>>>(ec3w, p_ec3, 64, 64, 5, 4, 12800);
    pack_weights<<<50, 256, 0, stream>>>(ec4w, p_ec4, 64, 64, 5, 4, 12800);

    // ---- encoder ----
    conv_ec1<<<512, 256, 0, stream>>>(inputs, ec1w, ec1b, B0);
    conv_mfma<64, 64, 5, 2, 64, 1, 0><<<512, 256, 0, stream>>>(B0, p_ec2, ec2b, B1, 64, 64, 64, 64, 4, 4);
    conv_mfma<64, 64, 5, 2, 64, 1, 0><<<512, 256, 0, stream>>>(B1, p_ec3, ec3b, B0, 64, 64, 64, 64, 4, 4);
    conv_mfma<64, 64, 5, 2, 64, 1, 0><<<512, 256, 0, stream>>>(B0, p_ec4, ec4b, B1, 64, 64, 64, 64, 4, 4);
    encoder_feat<<<2048, 256, 0, stream>>>(B1, epw, epb, ln1g, ln1b, fc1w, fc1b,
                                           fc2w, fc2b, kw, vw, K, V);
    slot_init<<<56, 256, 0, stream>>>(noise, init_slots, slots);

    // ---- 3 slot-attention iterations ----
    for (int it = 0; it < 3; ++it) {
        compute_q<<<56, 256, 0, stream>>>(slots, lnsg, lnsb, qw, qbuf, rowsum);
        attn_pass1<<<512, 256, 0, stream>>>(K, qbuf, attn, rowsum);
        attn_pass2<<<512, 256, 0, stream>>>(V, attn, part);
        gru_mlp<<<224, 64, 0, stream>>>(slots, part, rowsum, wih, whh, bih, bhh,
                                        lnfg, lnfb, m1w, m1b, m2w, m2b);
    }

    // ---- pack decoder weights (V's attn role is done) ----
    pack_weights<<<25, 256, 0, stream>>>(dc1w, p_dc1, 64, 32, 5, 2, 6400);
    pack_weights<<<13, 256, 0, stream>>>(dc2w, p_dc2, 32, 32, 5, 2, 3200);
    pack_weights<<<13, 256, 0, stream>>>(dc3w, p_dc3, 32, 32, 5, 2, 3200);
    pack_weights<<<3, 256, 0, stream>>>(dc4w, p_dc4, 32, 4, 3, 1, 576);

    // ---- decoder, 4 chunks of 56 images ----
    for (int ch = 0; ch < 4; ++ch) {
        const float* sl = slots + (size_t)ch * 56 * 64;
        float* d4o = dc4out + (size_t)ch * 56 * 4 * 4096;
        conv_dec1_mfma<<<1400, 256, 0, stream>>>(sl, dpw, dpb, p_dc1, dc1b, B0);
        conv_mfma<32, 32, 5, 1, 32, 1, 0><<<1400, 256, 0, stream>>>(B0, p_dc2, dc2b, B1, 68, 68, 66, 66, 5, 5);
        conv_mfma<32, 32, 5, 1, 32, 1, 0><<<896, 256, 0, stream>>>(B1, p_dc3, dc3b, B0, 66, 66, 64, 64, 4, 4);
        conv_mfma<32, 16, 3, 1, 4, 0, 1><<<896, 256, 0, stream>>>(B0, p_dc4, dc4b, d4o, 64, 64, 64, 64, 4, 4);
    }

    // ---- outputs ----
    zero_mse<<<1, 64, 0, stream>>>(out);
    finalize_k<<<512, 256, 0, stream>>>(dc4out, inputs, out);
    copy_slots<<<56, 256, 0, stream>>>(slots, out);
}

// Round 3
// 1095.739 us; speedup vs baseline: 8.8736x; 1.2458x over previous
//
#include <hip/hip_runtime.h>
#include <math.h>

typedef short bf16x8 __attribute__((ext_vector_type(8)));
typedef float f32x4 __attribute__((ext_vector_type(4)));

// workspace layout (float offsets)
#define WS_B0   0u           // 4194304 floats = 8388608 bf16 : enc ping / dec ping
#define WS_B1   4194304u     // 4194304 floats : enc pong / dec pong
#define WS_K    8388608u     // 8388608 floats : k  (fp32)
#define WS_V    16777216u    // 8388608 floats : v (fp32); decode: dc4out fp32 at +0, packed wts at +4194304
#define WS_ATTN 25165824u    // 917504 (first 8192 floats double as packed fc weights pre-iteration)
#define WS_PART 26083328u    // 229376
#define WS_Q    26312704u    // 14336
#define WS_SLOT 26327040u    // 14336
#define WS_ROW  26341376u    // 224
#define SCALE_ 0.125f

__device__ __forceinline__ float wave_sum(float v) {
#pragma unroll
    for (int m = 32; m >= 1; m >>= 1) v += __shfl_xor(v, m, 64);
    return v;
}
__device__ __forceinline__ unsigned short f2bf(float f) {
    unsigned u = __float_as_uint(f);
    u = u + 0x7fffu + ((u >> 16) & 1u);
    return (unsigned short)(u >> 16);
}
__device__ __forceinline__ float bf2f(unsigned short h) {
    return __uint_as_float(((unsigned)h) << 16);
}

// ---------------- weight packing into B-fragment order (conv, [COUT][CIN][KS][KS]) ----------------
__global__ __launch_bounds__(256) void pack_weights(
    const float* __restrict__ w, unsigned short* __restrict__ wp,
    int CIN, int COUT_STORE, int KS, int NT, int total)
{
    int t = blockIdx.x * 256 + threadIdx.x;
    if (t >= total) return;
    int lane = t & 63;
    int nt = (t >> 6) % NT;
    int ch = t / (64 * NT);
    int CPT = CIN / 32;
    int cic = ch % CPT;
    int tap = ch / CPT;
    int ky = tap / KS, kx = tap % KS;
    int co = nt * 16 + (lane & 15);
    int k0 = cic * 32 + (lane >> 4) * 8;
    unsigned short v[8];
#pragma unroll
    for (int j = 0; j < 8; ++j) {
        int ci = k0 + j;
        float f = (co < COUT_STORE) ? w[((size_t)(co * CIN + ci) * KS + ky) * KS + kx] : 0.f;
        v[j] = f2bf(f);
    }
    *(uint4*)(wp + (size_t)t * 8) = *(uint4*)v;
}

// ---------------- fc weight packing ([K=64][N=64] row-major) into B-frag order ----------------
// wp[((ck*4+nt)*64+lane)*8 + j] = B[k = ck*32 + (lane>>4)*8 + j][n = nt*16 + (lane&15)]
__global__ __launch_bounds__(256) void pack_fc(
    const float* __restrict__ w, unsigned short* __restrict__ wp)
{
    int t = blockIdx.x * 256 + threadIdx.x;
    if (t >= 512) return;
    int lane = t & 63;
    int nt = (t >> 6) & 3;
    int ck = t >> 8;
    int n = nt * 16 + (lane & 15);
    int k0 = ck * 32 + (lane >> 4) * 8;
    unsigned short v[8];
#pragma unroll
    for (int j = 0; j < 8; ++j) v[j] = f2bf(w[(size_t)(k0 + j) * 64 + n]);
    *(uint4*)(wp + (size_t)t * 8) = *(uint4*)v;
}

// ---------------- MFMA implicit-GEMM conv ----------------
template<int CIN, int COUT, int KS, int PAD, int NSTORE, int RELU, int OUTF32>
__global__ __launch_bounds__(256) void conv_mfma(
    const unsigned short* __restrict__ in, const unsigned short* __restrict__ wpack,
    const float* __restrict__ bias, void* __restrict__ outv,
    int Hin, int Win, int Hout, int Wout, int tilesX, int tilesY)
{
    constexpr int TS = 16, TH = TS + KS - 1;
    constexpr int NT = COUT / 16;
    constexpr int CPT = CIN / 32;
    constexpr int G8 = CIN / 8;
    __shared__ __align__(16) unsigned short tile[TH][TH][CIN];
    const int tpb = tilesX * tilesY;
    const int n = blockIdx.x / tpb;
    const int t = blockIdx.x % tpb;
    const int ty0 = (t / tilesX) * TS, tx0 = (t % tilesX) * TS;
    const int tid = threadIdx.x;

    const unsigned short* inb = in + (size_t)n * Hin * Win * CIN;
    for (int idx = tid; idx < TH * TH * G8; idx += 256) {
        int g = idx % G8;
        int c = (idx / G8) % TH;
        int r = idx / (G8 * TH);
        int iy = ty0 - PAD + r, ix = tx0 - PAD + c;
        uint4 vv = make_uint4(0, 0, 0, 0);
        if (iy >= 0 && iy < Hin && ix >= 0 && ix < Win)
            vv = *(const uint4*)(inb + ((size_t)iy * Win + ix) * CIN + g * 8);
        int slot = (g * 8 + c * 8) % CIN;
        *(uint4*)&tile[r][c][slot] = vv;
    }
    __syncthreads();

    const int wv = tid >> 6, lane = tid & 63;
    const int q = lane >> 4, m = lane & 15;
    f32x4 acc[4][NT];
#pragma unroll
    for (int mt = 0; mt < 4; ++mt)
#pragma unroll
        for (int nt = 0; nt < NT; ++nt) acc[mt][nt] = (f32x4){0.f, 0.f, 0.f, 0.f};

    for (int tap = 0; tap < KS * KS; ++tap) {
        const int ky = tap / KS, kx = tap % KS;
        const int cbase = m + kx;
#pragma unroll
        for (int cic = 0; cic < CPT; ++cic) {
            const int ch = tap * CPT + cic;
            bf16x8 bfr[NT];
#pragma unroll
            for (int nt = 0; nt < NT; ++nt)
                bfr[nt] = *(const bf16x8*)(wpack + ((size_t)(ch * NT + nt) * 64 + lane) * 8);
            const int slot = (cic * 32 + q * 8 + cbase * 8) % CIN;
#pragma unroll
            for (int mt = 0; mt < 4; ++mt) {
                const int orow = wv * 4 + mt;
                bf16x8 afr = *(const bf16x8*)&tile[orow + ky][cbase][slot];
#pragma unroll
                for (int nt = 0; nt < NT; ++nt)
                    acc[mt][nt] = __builtin_amdgcn_mfma_f32_16x16x32_bf16(afr, bfr[nt], acc[mt][nt], 0, 0, 0);
            }
        }
    }

#pragma unroll
    for (int nt = 0; nt < NT; ++nt) {
        const int co = nt * 16 + m;
        const float bv = (co < NSTORE) ? bias[co] : 0.f;
#pragma unroll
        for (int mt = 0; mt < 4; ++mt) {
            const int oy = ty0 + wv * 4 + mt;
#pragma unroll
            for (int j = 0; j < 4; ++j) {
                const int ox = tx0 + q * 4 + j;
                if (oy < Hout && ox < Wout && co < NSTORE) {
                    float v = acc[mt][nt][j] + bv;
                    if (RELU) v = fmaxf(v, 0.f);
                    size_t o = (((size_t)n * Hout + oy) * Wout + ox) * NSTORE + co;
                    if (OUTF32) ((float*)outv)[o] = v;
                    else ((unsigned short*)outv)[o] = f2bf(v);
                }
            }
        }
    }
}

// ---------------- decoder conv1: LDS tile synthesized on the fly ----------------
__global__ __launch_bounds__(256) void conv_dec1_mfma(
    const float* __restrict__ slots, const float* __restrict__ dpw,
    const float* __restrict__ dpb, const unsigned short* __restrict__ wpack,
    const float* __restrict__ bias, unsigned short* __restrict__ out)
{
    constexpr int KS = 5, PAD = 1, TH = 20, CIN = 64, NT = 2, CPT = 2;
    constexpr int Hin = 70, Win = 70, Hout = 68, Wout = 68;
    __shared__ __align__(16) unsigned short tile[TH][TH][CIN];
    const int n = blockIdx.x / 25;
    const int t = blockIdx.x % 25;
    const int ty0 = (t / 5) * 16, tx0 = (t % 5) * 16;
    const int tid = threadIdx.x;

    for (int idx = tid; idx < TH * TH * 8; idx += 256) {
        int g = idx % 8;
        int c = (idx / 8) % TH;
        int r = idx / (8 * TH);
        int iy = ty0 - PAD + r, ix = tx0 - PAD + c;
        unsigned short vv[8];
        if (iy >= 0 && iy < Hin && ix >= 0 && ix < Win) {
            float fy = iy * (1.f / 69.f), fx = ix * (1.f / 69.f);
#pragma unroll
            for (int j = 0; j < 8; ++j) {
                int ci = g * 8 + j;
                float v = slots[n * 64 + ci] + (1.f - fy) * dpw[ci] + fy * dpw[64 + ci]
                          + fx * dpw[128 + ci] + (1.f - fx) * dpw[192 + ci] + dpb[ci];
                vv[j] = f2bf(v);
            }
        } else {
#pragma unroll
            for (int j = 0; j < 8; ++j) vv[j] = 0;
        }
        int slot = (g * 8 + c * 8) % CIN;
        *(uint4*)&tile[r][c][slot] = *(uint4*)vv;
    }
    __syncthreads();

    const int wv = tid >> 6, lane = tid & 63;
    const int q = lane >> 4, m = lane & 15;
    f32x4 acc[4][NT];
#pragma unroll
    for (int mt = 0; mt < 4; ++mt)
#pragma unroll
        for (int nt = 0; nt < NT; ++nt) acc[mt][nt] = (f32x4){0.f, 0.f, 0.f, 0.f};

    for (int tap = 0; tap < KS * KS; ++tap) {
        const int ky = tap / KS, kx = tap % KS;
        const int cbase = m + kx;
#pragma unroll
        for (int cic = 0; cic < CPT; ++cic) {
            const int ch = tap * CPT + cic;
            bf16x8 bfr[NT];
#pragma unroll
            for (int nt = 0; nt < NT; ++nt)
                bfr[nt] = *(const bf16x8*)(wpack + ((size_t)(ch * NT + nt) * 64 + lane) * 8);
            const int slot = (cic * 32 + q * 8 + cbase * 8) % CIN;
#pragma unroll
            for (int mt = 0; mt < 4; ++mt) {
                const int orow = wv * 4 + mt;
                bf16x8 afr = *(const bf16x8*)&tile[orow + ky][cbase][slot];
#pragma unroll
                for (int nt = 0; nt < NT; ++nt)
                    acc[mt][nt] = __builtin_amdgcn_mfma_f32_16x16x32_bf16(afr, bfr[nt], acc[mt][nt], 0, 0, 0);
            }
        }
    }
#pragma unroll
    for (int nt = 0; nt < NT; ++nt) {
        const int co = nt * 16 + m;
        const float bv = bias[co];
#pragma unroll
        for (int mt = 0; mt < 4; ++mt) {
            const int oy = ty0 + wv * 4 + mt;
#pragma unroll
            for (int j = 0; j < 4; ++j) {
                const int ox = tx0 + q * 4 + j;
                if (oy < Hout && ox < Wout) {
                    float v = fmaxf(acc[mt][nt][j] + bv, 0.f);
                    out[(((size_t)n * Hout + oy) * Wout + ox) * 32 + co] = f2bf(v);
                }
            }
        }
    }
}

// ---------------- encoder conv1 (CIN=3, fp32 direct, NHWC bf16 out) ----------------
__global__ __launch_bounds__(256) void conv_ec1(
    const float* __restrict__ in, const float* __restrict__ wts,
    const float* __restrict__ bias, unsigned short* __restrict__ out)
{
    __shared__ float tile[3][20][21];
    const int n = blockIdx.x >> 4;
    const int t = blockIdx.x & 15;
    const int ty0 = (t >> 2) * 16, tx0 = (t & 3) * 16;
    const int tid = threadIdx.x;
    for (int idx = tid; idx < 1200; idx += 256) {
        int ci = idx / 400, rc = idx % 400;
        int r = rc / 20, c = rc % 20;
        int gy = ty0 + r - 2, gx = tx0 + c - 2;
        float v = 0.f;
        if (gy >= 0 && gy < 64 && gx >= 0 && gx < 64)
            v = in[((size_t)n * 3 + ci) * 4096 + gy * 64 + gx];
        tile[ci][r][c] = v;
    }
    __syncthreads();
    const int lx = tid & 15, ly = tid >> 4;
    float acc[64];
#pragma unroll
    for (int co = 0; co < 64; ++co) acc[co] = bias[co];
    for (int ci = 0; ci < 3; ++ci) {
        float val[25];
#pragma unroll
        for (int ky = 0; ky < 5; ++ky)
#pragma unroll
            for (int kx = 0; kx < 5; ++kx) val[ky * 5 + kx] = tile[ci][ly + ky][lx + kx];
#pragma unroll
        for (int co = 0; co < 64; ++co) {
            const float* wc = wts + (size_t)(co * 3 + ci) * 25;
            float a = acc[co];
#pragma unroll
            for (int tt = 0; tt < 25; ++tt) a = fmaf(val[tt], wc[tt], a);
            acc[co] = a;
        }
    }
    unsigned short tmp[64];
#pragma unroll
    for (int co = 0; co < 64; ++co) tmp[co] = f2bf(fmaxf(acc[co], 0.f));
    uint4* ob = (uint4*)(out + (((size_t)n * 64 + ty0 + ly) * 64 + tx0 + lx) * 64);
#pragma unroll
    for (int i = 0; i < 8; ++i) ob[i] = ((uint4*)tmp)[i];
}

// ---------------- encoder tail, MFMA: +pe, LN, fc1-relu-fc2, k/v ----------------
// one block = one image row (64 pixels). LDS X[64 pixels][72] bf16 (144B rows, 16B aligned).
__global__ __launch_bounds__(256) void encoder_tail_mfma(
    const unsigned short* __restrict__ h4,
    const float* __restrict__ epw, const float* __restrict__ epb,
    const float* __restrict__ ln1g, const float* __restrict__ ln1b,
    const unsigned short* __restrict__ pfc1, const float* __restrict__ fc1b,
    const unsigned short* __restrict__ pfc2, const float* __restrict__ fc2b,
    const unsigned short* __restrict__ pkw, const unsigned short* __restrict__ pvw,
    float* __restrict__ kout, float* __restrict__ vout)
{
    __shared__ __align__(16) unsigned short X[64][72];
    const int b = blockIdx.x >> 6;
    const int y = blockIdx.x & 63;
    const int tid = threadIdx.x;

    // ---- stage: load 16 ch of pixel p, add pe, LN over 64 ch (4 threads/pixel) ----
    {
        const int p = tid >> 2, sub = tid & 3;
        const unsigned short* hp = h4 + ((((size_t)b * 64 + y) * 64 + p) * 64) + sub * 16;
        unsigned short raw[16];
        *(uint4*)(raw)     = *(const uint4*)hp;
        *(uint4*)(raw + 8) = *(const uint4*)(hp + 8);
        const float fy = y * (1.f / 63.f), fx = p * (1.f / 63.f);
        float f[16];
        float s1 = 0.f, s2 = 0.f;
#pragma unroll
        for (int j = 0; j < 16; ++j) {
            int ch = sub * 16 + j;
            float pe = (1.f - fy) * epw[ch] + fy * epw[64 + ch]
                     + fx * epw[128 + ch] + (1.f - fx) * epw[192 + ch] + epb[ch];
            float v = bf2f(raw[j]) + pe;
            f[j] = v;
            s1 += v;
            s2 += v * v;
        }
        s1 += __shfl_xor(s1, 1, 64); s1 += __shfl_xor(s1, 2, 64);
        s2 += __shfl_xor(s2, 1, 64); s2 += __shfl_xor(s2, 2, 64);
        const float m = s1 * (1.f / 64.f);
        const float var = s2 * (1.f / 64.f) - m * m;
        const float inv = rsqrtf(var + 1e-5f);
        unsigned short xb[16];
#pragma unroll
        for (int j = 0; j < 16; ++j) {
            int ch = sub * 16 + j;
            xb[j] = f2bf((f[j] - m) * inv * ln1g[ch] + ln1b[ch]);
        }
        *(uint4*)&X[p][sub * 16]     = ((uint4*)xb)[0];
        *(uint4*)&X[p][sub * 16 + 8] = ((uint4*)xb)[1];
    }
    __syncthreads();

    const int w = tid >> 6, lane = tid & 63;
    const int q = lane >> 4, m_ = lane & 15;
    const int row0 = w * 16;

    // ---- fc1 + relu ----
    {
        f32x4 a1[4];
#pragma unroll
        for (int nt = 0; nt < 4; ++nt) a1[nt] = (f32x4){0.f, 0.f, 0.f, 0.f};
#pragma unroll
        for (int ck = 0; ck < 2; ++ck) {
            bf16x8 afr = *(const bf16x8*)&X[row0 + m_][ck * 32 + q * 8];
#pragma unroll
            for (int nt = 0; nt < 4; ++nt) {
                bf16x8 bfr = *(const bf16x8*)(pfc1 + ((size_t)((ck * 4 + nt) * 64 + lane)) * 8);
                a1[nt] = __builtin_amdgcn_mfma_f32_16x16x32_bf16(afr, bfr, a1[nt], 0, 0, 0);
            }
        }
        __syncthreads();
#pragma unroll
        for (int nt = 0; nt < 4; ++nt) {
            const float bb = fc1b[nt * 16 + m_];
#pragma unroll
            for (int reg = 0; reg < 4; ++reg)
                X[row0 + q * 4 + reg][nt * 16 + m_] = f2bf(fmaxf(a1[nt][reg] + bb, 0.f));
        }
    }
    __syncthreads();

    // ---- fc2 (+bias, no relu) ----
    {
        f32x4 a2[4];
#pragma unroll
        for (int nt = 0; nt < 4; ++nt) a2[nt] = (f32x4){0.f, 0.f, 0.f, 0.f};
#pragma unroll
        for (int ck = 0; ck < 2; ++ck) {
            bf16x8 afr = *(const bf16x8*)&X[row0 + m_][ck * 32 + q * 8];
#pragma unroll
            for (int nt = 0; nt < 4; ++nt) {
                bf16x8 bfr = *(const bf16x8*)(pfc2 + ((size_t)((ck * 4 + nt) * 64 + lane)) * 8);
                a2[nt] = __builtin_amdgcn_mfma_f32_16x16x32_bf16(afr, bfr, a2[nt], 0, 0, 0);
            }
        }
        __syncthreads();
#pragma unroll
        for (int nt = 0; nt < 4; ++nt) {
            const float bb = fc2b[nt * 16 + m_];
#pragma unroll
            for (int reg = 0; reg < 4; ++reg)
                X[row0 + q * 4 + reg][nt * 16 + m_] = f2bf(a2[nt][reg] + bb);
        }
    }
    __syncthreads();

    // ---- k and v ----
    {
        f32x4 ak[4], av[4];
#pragma unroll
        for (int nt = 0; nt < 4; ++nt) {
            ak[nt] = (f32x4){0.f, 0.f, 0.f, 0.f};
            av[nt] = (f32x4){0.f, 0.f, 0.f, 0.f};
        }
#pragma unroll
        for (int ck = 0; ck < 2; ++ck) {
            bf16x8 afr = *(const bf16x8*)&X[row0 + m_][ck * 32 + q * 8];
#pragma unroll
            for (int nt = 0; nt < 4; ++nt) {
                bf16x8 bk = *(const bf16x8*)(pkw + ((size_t)((ck * 4 + nt) * 64 + lane)) * 8);
                bf16x8 bv = *(const bf16x8*)(pvw + ((size_t)((ck * 4 + nt) * 64 + lane)) * 8);
                ak[nt] = __builtin_amdgcn_mfma_f32_16x16x32_bf16(afr, bk, ak[nt], 0, 0, 0);
                av[nt] = __builtin_amdgcn_mfma_f32_16x16x32_bf16(afr, bv, av[nt], 0, 0, 0);
            }
        }
        const size_t base = ((size_t)b * 4096) + y * 64 + row0;
#pragma unroll
        for (int nt = 0; nt < 4; ++nt) {
            const int ch = nt * 16 + m_;
#pragma unroll
            for (int reg = 0; reg < 4; ++reg) {
                const size_t o = (base + q * 4 + reg) * 64 + ch;
                kout[o] = ak[nt][reg];
                vout[o] = av[nt][reg];
            }
        }
    }
}

// ---------------- slot init ----------------
__global__ __launch_bounds__(256) void slot_init(
    const float* __restrict__ noise, const float* __restrict__ init_slots,
    float* __restrict__ slots)
{
    int i = blockIdx.x * 256 + threadIdx.x;
    if (i < 224 * 64) {
        int z = i & 63;
        float spl = log1pf(expf(init_slots[64 + z]));
        slots[i] = init_slots[z] + spl * noise[i];
    }
}

// ---------------- q = LN(slots)@q_w * scale; zero rowsum ----------------
__global__ __launch_bounds__(256) void compute_q(
    const float* __restrict__ slots, const float* __restrict__ lnsg,
    const float* __restrict__ lnsb, const float* __restrict__ qw,
    float* __restrict__ qout, float* __restrict__ rowsum)
{
    const int tid = threadIdx.x;
    if (blockIdx.x == 0 && tid < 224) rowsum[tid] = 0.f;
    const int lane = tid & 63, wv = tid >> 6;
    const int n = blockIdx.x * 4 + wv;
    if (n < 224) {
        float s = slots[n * 64 + lane];
        float m = wave_sum(s) * (1.f / 64.f);
        float d = s - m;
        float var = wave_sum(d * d) * (1.f / 64.f);
        float x = d * rsqrtf(var + 1e-5f) * lnsg[lane] + lnsb[lane];
        float q = 0.f;
        for (int c = 0; c < 64; ++c) q = fmaf(__shfl(x, c, 64), qw[c * 64 + lane], q);
        qout[n * 64 + lane] = q * SCALE_;
    }
}

// ---------------- attention pass 1 ----------------
__global__ __launch_bounds__(256) void attn_pass1(
    const float* __restrict__ kbuf, const float* __restrict__ qbuf,
    float* __restrict__ attn, float* __restrict__ rowsum)
{
    __shared__ float qs[7][64];
    __shared__ float red[7][4];
    const int b = blockIdx.x >> 4;
    const int jb = (blockIdx.x & 15) * 256;
    const int tid = threadIdx.x;
    if (tid < 7 * 64) qs[tid / 64][tid % 64] = qbuf[b * 7 * 64 + tid];
    __syncthreads();
    const int j = jb + tid;
    float kr[64];
    const float* kp = kbuf + (((size_t)b * 4096) + j) * 64;
#pragma unroll
    for (int d4 = 0; d4 < 16; ++d4) {
        float4 kv = ((const float4*)kp)[d4];
        kr[d4 * 4 + 0] = kv.x; kr[d4 * 4 + 1] = kv.y;
        kr[d4 * 4 + 2] = kv.z; kr[d4 * 4 + 3] = kv.w;
    }
    float dots[7];
#pragma unroll
    for (int i = 0; i < 7; ++i) {
        float a = 0.f;
#pragma unroll
        for (int d = 0; d < 64; ++d) a = fmaf(kr[d], qs[i][d], a);
        dots[i] = a;
    }
    float mx = dots[0];
#pragma unroll
    for (int i = 1; i < 7; ++i) mx = fmaxf(mx, dots[i]);
    float sum = 0.f;
#pragma unroll
    for (int i = 0; i < 7; ++i) { dots[i] = expf(dots[i] - mx); sum += dots[i]; }
    const float inv = 1.f / sum;
#pragma unroll
    for (int i = 0; i < 7; ++i) {
        float a = dots[i] * inv + 1e-8f;
        dots[i] = a;
        attn[(((size_t)b * 7) + i) * 4096 + j] = a;
    }
    const int lane = tid & 63, wv = tid >> 6;
#pragma unroll
    for (int i = 0; i < 7; ++i) {
        float s = wave_sum(dots[i]);
        if (lane == 0) red[i][wv] = s;
    }
    __syncthreads();
    if (tid < 7) {
        float s = red[tid][0] + red[tid][1] + red[tid][2] + red[tid][3];
        atomicAdd(&rowsum[b * 7 + tid], s);
    }
}

// ---------------- attention pass 2 ----------------
__global__ __launch_bounds__(256) void attn_pass2(
    const float* __restrict__ vbuf, const float* __restrict__ attn,
    float* __restrict__ part)
{
    const int b = blockIdx.x >> 4;
    const int js = blockIdx.x & 15;
    const int tid = threadIdx.x;
    const int d = tid & 63, jc = tid >> 6;
    float acc[7];
#pragma unroll
    for (int i = 0; i < 7; ++i) acc[i] = 0.f;
    const int j0 = js * 256;
    for (int j = j0 + jc; j < j0 + 256; j += 4) {
        float av = vbuf[(((size_t)b * 4096) + j) * 64 + d];
#pragma unroll
        for (int i = 0; i < 7; ++i)
            acc[i] = fmaf(attn[(((size_t)b * 7) + i) * 4096 + j], av, acc[i]);
    }
    __shared__ float red[4][7][64];
#pragma unroll
    for (int i = 0; i < 7; ++i) red[jc][i][d] = acc[i];
    __syncthreads();
    if (tid < 7 * 64) {
        int i = tid / 64, dd = tid % 64;
        float s = red[0][i][dd] + red[1][i][dd] + red[2][i][dd] + red[3][i][dd];
        part[((((size_t)b * 16) + js) * 7 + i) * 64 + dd] = s;
    }
}

// ---------------- GRU + residual MLP ----------------
__global__ __launch_bounds__(64) void gru_mlp(
    float* __restrict__ slots, const float* __restrict__ part,
    const float* __restrict__ rowsum,
    const float* __restrict__ wih, const float* __restrict__ whh,
    const float* __restrict__ bih, const float* __restrict__ bhh,
    const float* __restrict__ lnfg, const float* __restrict__ lnfb,
    const float* __restrict__ m1w, const float* __restrict__ m1b,
    const float* __restrict__ m2w, const float* __restrict__ m2b)
{
    const int n = blockIdx.x;
    const int b = n / 7, i = n % 7;
    const int l = threadIdx.x;
    float upd = 0.f;
    for (int js = 0; js < 16; ++js)
        upd += part[((((size_t)b * 16) + js) * 7 + i) * 64 + l];
    upd /= rowsum[n];
    const float prev = slots[n * 64 + l];
    float gi0 = bih[l], gi1 = bih[64 + l], gi2 = bih[128 + l];
    float gh0 = bhh[l], gh1 = bhh[64 + l], gh2 = bhh[128 + l];
    for (int c = 0; c < 64; ++c) {
        float u = __shfl(upd, c, 64), p = __shfl(prev, c, 64);
        gi0 = fmaf(u, wih[l * 64 + c], gi0);
        gi1 = fmaf(u, wih[(64 + l) * 64 + c], gi1);
        gi2 = fmaf(u, wih[(128 + l) * 64 + c], gi2);
        gh0 = fmaf(p, whh[l * 64 + c], gh0);
        gh1 = fmaf(p, whh[(64 + l) * 64 + c], gh1);
        gh2 = fmaf(p, whh[(128 + l) * 64 + c], gh2);
    }
    float r  = 1.f / (1.f + expf(-(gi0 + gh0)));
    float zg = 1.f / (1.f + expf(-(gi1 + gh1)));
    float nn = tanhf(gi2 + r * gh2);
    float s = (1.f - zg) * nn + zg * prev;
    float m = wave_sum(s) * (1.f / 64.f);
    float d = s - m;
    float var = wave_sum(d * d) * (1.f / 64.f);
    float x = d * rsqrtf(var + 1e-5f) * lnfg[l] + lnfb[l];
    float h0 = m1b[l], h1 = m1b[64 + l];
    for (int c = 0; c < 64; ++c) {
        float xv = __shfl(x, c, 64);
        h0 = fmaf(xv, m1w[c * 128 + l], h0);
        h1 = fmaf(xv, m1w[c * 128 + 64 + l], h1);
    }
    h0 = fmaxf(h0, 0.f); h1 = fmaxf(h1, 0.f);
    float o = m2b[l];
    for (int c = 0; c < 64; ++c) {
        o = fmaf(__shfl(h0, c, 64), m2w[c * 64 + l], o);
        o = fmaf(__shfl(h1, c, 64), m2w[(64 + c) * 64 + l], o);
    }
    slots[n * 64 + l] = s + o;
}

// ---------------- finalize (dc4out NHWC fp32 [img][p][4]) ----------------
__global__ __launch_bounds__(256) void finalize_k(
    const float* __restrict__ dc4out, const float* __restrict__ inputs,
    float* __restrict__ out)
{
    const int tid = threadIdx.x;
    const int gp = blockIdx.x * 256 + tid;
    const int b = gp >> 12, p = gp & 4095;
    float4 o4[7];
#pragma unroll
    for (int k = 0; k < 7; ++k)
        o4[k] = ((const float4*)dc4out)[(size_t)(b * 7 + k) * 4096 + p];
    float mx = o4[0].w;
#pragma unroll
    for (int k = 1; k < 7; ++k) mx = fmaxf(mx, o4[k].w);
    float s = 0.f;
#pragma unroll
    for (int k = 0; k < 7; ++k) s += expf(o4[k].w - mx);
    const float lse = mx + logf(s);
    float recon0 = 0.f, recon1 = 0.f, recon2 = 0.f;
    float* xl = out + 1;
    float* ml = out + 2752513;
#pragma unroll
    for (int k = 0; k < 7; ++k) {
        float lp = o4[k].w - lse;
        ml[((size_t)(b * 7 + k)) * 4096 + p] = lp;
        float w = expf(lp);
        float x0 = 1.f / (1.f + expf(-o4[k].x));
        float x1 = 1.f / (1.f + expf(-o4[k].y));
        float x2 = 1.f / (1.f + expf(-o4[k].z));
        xl[(((size_t)(b * 7 + k)) * 3 + 0) * 4096 + p] = x0;
        xl[(((size_t)(b * 7 + k)) * 3 + 1) * 4096 + p] = x1;
        xl[(((size_t)(b * 7 + k)) * 3 + 2) * 4096 + p] = x2;
        recon0 = fmaf(x0, w, recon0);
        recon1 = fmaf(x1, w, recon1);
        recon2 = fmaf(x2, w, recon2);
    }
    float err = 0.f;
    {
        float xo = (inputs[((size_t)b * 3 + 0) * 4096 + p] + 1.f) * 0.5f;
        float dd = xo - recon0; err += dd * dd;
        xo = (inputs[((size_t)b * 3 + 1) * 4096 + p] + 1.f) * 0.5f;
        dd = xo - recon1; err += dd * dd;
        xo = (inputs[((size_t)b * 3 + 2) * 4096 + p] + 1.f) * 0.5f;
        dd = xo - recon2; err += dd * dd;
    }
    float wsum = wave_sum(err);
    __shared__ float red[4];
    const int lane = tid & 63, wv = tid >> 6;
    if (lane == 0) red[wv] = wsum;
    __syncthreads();
    if (tid == 0) atomicAdd(out, (red[0] + red[1] + red[2] + red[3]) * (1.f / 32.f));
}

__global__ void zero_mse(float* out) { if (threadIdx.x == 0) out[0] = 0.f; }

__global__ __launch_bounds__(256) void copy_slots(const float* __restrict__ slots,
                                                  float* __restrict__ out)
{
    int i = blockIdx.x * 256 + threadIdx.x;
    if (i < 14336) out[3670017 + i] = slots[i];
}

// ---------------- launch ----------------
extern "C" void kernel_launch(void* const* d_in, const int* in_sizes, int n_in,
                              void* d_out, int out_size, void* d_ws, size_t ws_size,
                              hipStream_t stream) {
    (void)in_sizes; (void)n_in; (void)out_size; (void)ws_size;
    const float* inputs = (const float*)d_in[0];
    const float* noise  = (const float*)d_in[1];
    const float* epw  = (const float*)d_in[2];
    const float* epb  = (const float*)d_in[3];
    const float* ec1w = (const float*)d_in[4];
    const float* ec1b = (const float*)d_in[5];
    const float* ec2w = (const float*)d_in[6];
    const float* ec2b = (const float*)d_in[7];
    const float* ec3w = (const float*)d_in[8];
    const float* ec3b = (const float*)d_in[9];
    const float* ec4w = (const float*)d_in[10];
    const float* ec4b = (const float*)d_in[11];
    const float* ln1g = (const float*)d_in[12];
    const float* ln1b = (const float*)d_in[13];
    const float* fc1w = (const float*)d_in[14];
    const float* fc1b = (const float*)d_in[15];
    const float* fc2w = (const float*)d_in[16];
    const float* fc2b = (const float*)d_in[17];
    const float* lnsg = (const float*)d_in[18];
    const float* lnsb = (const float*)d_in[19];
    const float* lnfg = (const float*)d_in[20];
    const float* lnfb = (const float*)d_in[21];
    const float* qw   = (const float*)d_in[22];
    const float* kw   = (const float*)d_in[23];
    const float* vw   = (const float*)d_in[24];
    const float* m1w  = (const float*)d_in[25];
    const float* m1b  = (const float*)d_in[26];
    const float* m2w  = (const float*)d_in[27];
    const float* m2b  = (const float*)d_in[28];
    const float* wih  = (const float*)d_in[29];
    const float* whh  = (const float*)d_in[30];
    const float* bih  = (const float*)d_in[31];
    const float* bhh  = (const float*)d_in[32];
    const float* init_slots = (const float*)d_in[33];
    const float* dpw  = (const float*)d_in[34];
    const float* dpb  = (const float*)d_in[35];
    const float* dc1w = (const float*)d_in[36];
    const float* dc1b = (const float*)d_in[37];
    const float* dc2w = (const float*)d_in[38];
    const float* dc2b = (const float*)d_in[39];
    const float* dc3w = (const float*)d_in[40];
    const float* dc3b = (const float*)d_in[41];
    const float* dc4w = (const float*)d_in[42];
    const float* dc4b = (const float*)d_in[43];

    float* ws = (float*)d_ws;
    unsigned short* B0 = (unsigned short*)(ws + WS_B0);
    unsigned short* B1 = (unsigned short*)(ws + WS_B1);
    float* K = ws + WS_K;
    float* V = ws + WS_V;
    float* dc4out = V;                                    // overlay (decode phase)
    unsigned short* PK = (unsigned short*)(ws + WS_V + 4194304u);  // pack area (16MB into V)
    unsigned short* p_ec2 = PK, *p_ec3 = PK + 102400, *p_ec4 = PK + 204800;
    unsigned short* p_dc1 = PK, *p_dc2 = PK + 51200, *p_dc3 = PK + 76800, *p_dc4 = PK + 102400;
    float* attn  = ws + WS_ATTN;
    // fc-pack area: first 8192 floats of attn region (live only until encoder_tail done)
    unsigned short* PFC = (unsigned short*)attn;
    unsigned short* p_fc1 = PFC, *p_fc2 = PFC + 4096, *p_kw = PFC + 8192, *p_vw = PFC + 12288;
    float* part  = ws + WS_PART;
    float* qbuf  = ws + WS_Q;
    float* slots = ws + WS_SLOT;
    float* rowsum = ws + WS_ROW;
    float* out = (float*)d_out;

    // ---- pack encoder weights ----
    pack_weights<<<50, 256, 0, stream>>>(ec2w, p_ec2, 64, 64, 5, 4, 12800);
    pack_weights<<<50, 256, 0, stream>>>(ec3w, p_ec3, 64, 64, 5, 4, 12800);
    pack_weights<<<50, 256, 0, stream>>>(ec4w, p_ec4, 64, 64, 5, 4, 12800);
    pack_fc<<<2, 256, 0, stream>>>(fc1w, p_fc1);
    pack_fc<<<2, 256, 0, stream>>>(fc2w, p_fc2);
    pack_fc<<<2, 256, 0, stream>>>(kw, p_kw);
    pack_fc<<<2, 256, 0, stream>>>(vw, p_vw);

    // ---- encoder ----
    conv_ec1<<<512, 256, 0, stream>>>(inputs, ec1w, ec1b, B0);
    conv_mfma<64, 64, 5, 2, 64, 1, 0><<<512, 256, 0, stream>>>(B0, p_ec2, ec2b, B1, 64, 64, 64, 64, 4, 4);
    conv_mfma<64, 64, 5, 2, 64, 1, 0><<<512, 256, 0, stream>>>(B1, p_ec3, ec3b, B0, 64, 64, 64, 64, 4, 4);
    conv_mfma<64, 64, 5, 2, 64, 1, 0><<<512, 256, 0, stream>>>(B0, p_ec4, ec4b, B1, 64, 64, 64, 64, 4, 4);
    encoder_tail_mfma<<<2048, 256, 0, stream>>>(B1, epw, epb, ln1g, ln1b,
                                                p_fc1, fc1b, p_fc2, fc2b, p_kw, p_vw, K, V);
    slot_init<<<56, 256, 0, stream>>>(noise, init_slots, slots);

    // ---- 3 slot-attention iterations ----
    for (int it = 0; it < 3; ++it) {
        compute_q<<<56, 256, 0, stream>>>(slots, lnsg, lnsb, qw, qbuf, rowsum);
        attn_pass1<<<512, 256, 0, stream>>>(K, qbuf, attn, rowsum);
        attn_pass2<<<512, 256, 0, stream>>>(V, attn, part);
        gru_mlp<<<224, 64, 0, stream>>>(slots, part, rowsum, wih, whh, bih, bhh,
                                        lnfg, lnfb, m1w, m1b, m2w, m2b);
    }

    // ---- pack decoder weights (V's attn role is done) ----
    pack_weights<<<25, 256, 0, stream>>>(dc1w, p_dc1, 64, 32, 5, 2, 6400);
    pack_weights<<<13, 256, 0, stream>>>(dc2w, p_dc2, 32, 32, 5, 2, 3200);
    pack_weights<<<13, 256, 0, stream>>>(dc3w, p_dc3, 32, 32, 5, 2, 3200);
    pack_weights<<<3, 256, 0, stream>>>(dc4w, p_dc4, 32, 4, 3, 1, 576);

    // ---- decoder, 4 chunks of 56 images ----
    for (int ch = 0; ch < 4; ++ch) {
        const float* sl = slots + (size_t)ch * 56 * 64;
        float* d4o = dc4out + (size_t)ch * 56 * 4 * 4096;
        conv_dec1_mfma<<<1400, 256, 0, stream>>>(sl, dpw, dpb, p_dc1, dc1b, B0);
        conv_mfma<32, 32, 5, 1, 32, 1, 0><<<1400, 256, 0, stream>>>(B0, p_dc2, dc2b, B1, 68, 68, 66, 66, 5, 5);
        conv_mfma<32, 32, 5, 1, 32, 1, 0><<<896, 256, 0, stream>>>(B1, p_dc3, dc3b, B0, 66, 66, 64, 64, 4, 4);
        conv_mfma<32, 16, 3, 1, 4, 0, 1><<<896, 256, 0, stream>>>(B0, p_dc4, dc4b, d4o, 64, 64, 64, 64, 4, 4);
    }

    // ---- outputs ----
    zero_mse<<<1, 64, 0, stream>>>(out);
    finalize_k<<<512, 256, 0, stream>>>(dc4out, inputs, out);
    copy_slots<<<56, 256, 0, stream>>>(slots, out);
}

// Round 4
// 964.077 us; speedup vs baseline: 10.0854x; 1.1366x over previous
//
#include <hip/hip_runtime.h>
#include <math.h>

typedef short bf16x8 __attribute__((ext_vector_type(8)));
typedef float f32x4 __attribute__((ext_vector_type(4)));

// workspace layout (float offsets)
#define WS_B0   0u           // encode: B0 (bf16 ping). decode: dec ping (33.5MB spans B0+B1)
#define WS_B1   4194304u     // encode: B1 (bf16 pong)
#define WS_K    8388608u     // encode/attn: k fp32. decode: dec pong (bf16)
#define WS_V    16777216u    // encode/attn: v fp32. decode: dc4out fp32 @+0, packed wts @+4194304
#define WS_ATTN 25165824u    // 917504 (first 16384 bf16 double as packed fc weights pre-attention)
#define WS_PART 26083328u    // 229376
#define WS_Q    26312704u    // 14336 (unused now)
#define WS_SLOT 26327040u    // 14336
#define WS_ROW  26341376u    // 224
#define SCALE_ 0.125f

__device__ __forceinline__ float wave_sum(float v) {
#pragma unroll
    for (int m = 32; m >= 1; m >>= 1) v += __shfl_xor(v, m, 64);
    return v;
}
__device__ __forceinline__ unsigned short f2bf(float f) {
    unsigned u = __float_as_uint(f);
    u = u + 0x7fffu + ((u >> 16) & 1u);
    return (unsigned short)(u >> 16);
}
__device__ __forceinline__ float bf2f(unsigned short h) {
    return __uint_as_float(((unsigned)h) << 16);
}

// ---------------- weight packing into B-fragment order (conv, [COUT][CIN][KS][KS]) ----------------
__global__ __launch_bounds__(256) void pack_weights(
    const float* __restrict__ w, unsigned short* __restrict__ wp,
    int CIN, int COUT_STORE, int KS, int NT, int total)
{
    int t = blockIdx.x * 256 + threadIdx.x;
    if (t >= total) return;
    int lane = t & 63;
    int nt = (t >> 6) % NT;
    int ch = t / (64 * NT);
    int CPT = CIN / 32;
    int cic = ch % CPT;
    int tap = ch / CPT;
    int ky = tap / KS, kx = tap % KS;
    int co = nt * 16 + (lane & 15);
    int k0 = cic * 32 + (lane >> 4) * 8;
    unsigned short v[8];
#pragma unroll
    for (int j = 0; j < 8; ++j) {
        int ci = k0 + j;
        float f = (co < COUT_STORE) ? w[((size_t)(co * CIN + ci) * KS + ky) * KS + kx] : 0.f;
        v[j] = f2bf(f);
    }
    *(uint4*)(wp + (size_t)t * 8) = *(uint4*)v;
}

// ---------------- fc weight packing ([K=64][N=64] row-major) into B-frag order ----------------
__global__ __launch_bounds__(256) void pack_fc(
    const float* __restrict__ w, unsigned short* __restrict__ wp)
{
    int t = blockIdx.x * 256 + threadIdx.x;
    if (t >= 512) return;
    int lane = t & 63;
    int nt = (t >> 6) & 3;
    int ck = t >> 8;
    int n = nt * 16 + (lane & 15);
    int k0 = ck * 32 + (lane >> 4) * 8;
    unsigned short v[8];
#pragma unroll
    for (int j = 0; j < 8; ++j) v[j] = f2bf(w[(size_t)(k0 + j) * 64 + n]);
    *(uint4*)(wp + (size_t)t * 8) = *(uint4*)v;
}

// ---------------- MFMA implicit-GEMM conv ----------------
template<int CIN, int COUT, int KS, int PAD, int NSTORE, int RELU, int OUTF32>
__global__ __launch_bounds__(256) void conv_mfma(
    const unsigned short* __restrict__ in, const unsigned short* __restrict__ wpack,
    const float* __restrict__ bias, void* __restrict__ outv,
    int Hin, int Win, int Hout, int Wout, int tilesX, int tilesY)
{
    constexpr int TS = 16, TH = TS + KS - 1;
    constexpr int NT = COUT / 16;
    constexpr int CPT = CIN / 32;
    constexpr int G8 = CIN / 8;
    __shared__ __align__(16) unsigned short tile[TH][TH][CIN];
    const int tpb = tilesX * tilesY;
    const int n = blockIdx.x / tpb;
    const int t = blockIdx.x % tpb;
    const int ty0 = (t / tilesX) * TS, tx0 = (t % tilesX) * TS;
    const int tid = threadIdx.x;

    const unsigned short* inb = in + (size_t)n * Hin * Win * CIN;
    for (int idx = tid; idx < TH * TH * G8; idx += 256) {
        int g = idx % G8;
        int c = (idx / G8) % TH;
        int r = idx / (G8 * TH);
        int iy = ty0 - PAD + r, ix = tx0 - PAD + c;
        uint4 vv = make_uint4(0, 0, 0, 0);
        if (iy >= 0 && iy < Hin && ix >= 0 && ix < Win)
            vv = *(const uint4*)(inb + ((size_t)iy * Win + ix) * CIN + g * 8);
        int slot = (g * 8 + c * 8) % CIN;
        *(uint4*)&tile[r][c][slot] = vv;
    }
    __syncthreads();

    const int wv = tid >> 6, lane = tid & 63;
    const int q = lane >> 4, m = lane & 15;
    f32x4 acc[4][NT];
#pragma unroll
    for (int mt = 0; mt < 4; ++mt)
#pragma unroll
        for (int nt = 0; nt < NT; ++nt) acc[mt][nt] = (f32x4){0.f, 0.f, 0.f, 0.f};

    for (int tap = 0; tap < KS * KS; ++tap) {
        const int ky = tap / KS, kx = tap % KS;
        const int cbase = m + kx;
#pragma unroll
        for (int cic = 0; cic < CPT; ++cic) {
            const int ch = tap * CPT + cic;
            bf16x8 bfr[NT];
#pragma unroll
            for (int nt = 0; nt < NT; ++nt)
                bfr[nt] = *(const bf16x8*)(wpack + ((size_t)(ch * NT + nt) * 64 + lane) * 8);
            const int slot = (cic * 32 + q * 8 + cbase * 8) % CIN;
#pragma unroll
            for (int mt = 0; mt < 4; ++mt) {
                const int orow = wv * 4 + mt;
                bf16x8 afr = *(const bf16x8*)&tile[orow + ky][cbase][slot];
#pragma unroll
                for (int nt = 0; nt < NT; ++nt)
                    acc[mt][nt] = __builtin_amdgcn_mfma_f32_16x16x32_bf16(afr, bfr[nt], acc[mt][nt], 0, 0, 0);
            }
        }
    }

#pragma unroll
    for (int nt = 0; nt < NT; ++nt) {
        const int co = nt * 16 + m;
        const float bv = (co < NSTORE) ? bias[co] : 0.f;
#pragma unroll
        for (int mt = 0; mt < 4; ++mt) {
            const int oy = ty0 + wv * 4 + mt;
#pragma unroll
            for (int j = 0; j < 4; ++j) {
                const int ox = tx0 + q * 4 + j;
                if (oy < Hout && ox < Wout && co < NSTORE) {
                    float v = acc[mt][nt][j] + bv;
                    if (RELU) v = fmaxf(v, 0.f);
                    size_t o = (((size_t)n * Hout + oy) * Wout + ox) * NSTORE + co;
                    if (OUTF32) ((float*)outv)[o] = v;
                    else ((unsigned short*)outv)[o] = f2bf(v);
                }
            }
        }
    }
}

// ---------------- decoder conv1: LDS tile synthesized on the fly ----------------
__global__ __launch_bounds__(256) void conv_dec1_mfma(
    const float* __restrict__ slots, const float* __restrict__ dpw,
    const float* __restrict__ dpb, const unsigned short* __restrict__ wpack,
    const float* __restrict__ bias, unsigned short* __restrict__ out)
{
    constexpr int KS = 5, PAD = 1, TH = 20, CIN = 64, NT = 2, CPT = 2;
    constexpr int Hin = 70, Win = 70, Hout = 68, Wout = 68;
    __shared__ __align__(16) unsigned short tile[TH][TH][CIN];
    const int n = blockIdx.x / 25;
    const int t = blockIdx.x % 25;
    const int ty0 = (t / 5) * 16, tx0 = (t % 5) * 16;
    const int tid = threadIdx.x;

    for (int idx = tid; idx < TH * TH * 8; idx += 256) {
        int g = idx % 8;
        int c = (idx / 8) % TH;
        int r = idx / (8 * TH);
        int iy = ty0 - PAD + r, ix = tx0 - PAD + c;
        unsigned short vv[8];
        if (iy >= 0 && iy < Hin && ix >= 0 && ix < Win) {
            float fy = iy * (1.f / 69.f), fx = ix * (1.f / 69.f);
#pragma unroll
            for (int j = 0; j < 8; ++j) {
                int ci = g * 8 + j;
                float v = slots[n * 64 + ci] + (1.f - fy) * dpw[ci] + fy * dpw[64 + ci]
                          + fx * dpw[128 + ci] + (1.f - fx) * dpw[192 + ci] + dpb[ci];
                vv[j] = f2bf(v);
            }
        } else {
#pragma unroll
            for (int j = 0; j < 8; ++j) vv[j] = 0;
        }
        int slot = (g * 8 + c * 8) % CIN;
        *(uint4*)&tile[r][c][slot] = *(uint4*)vv;
    }
    __syncthreads();

    const int wv = tid >> 6, lane = tid & 63;
    const int q = lane >> 4, m = lane & 15;
    f32x4 acc[4][NT];
#pragma unroll
    for (int mt = 0; mt < 4; ++mt)
#pragma unroll
        for (int nt = 0; nt < NT; ++nt) acc[mt][nt] = (f32x4){0.f, 0.f, 0.f, 0.f};

    for (int tap = 0; tap < KS * KS; ++tap) {
        const int ky = tap / KS, kx = tap % KS;
        const int cbase = m + kx;
#pragma unroll
        for (int cic = 0; cic < CPT; ++cic) {
            const int ch = tap * CPT + cic;
            bf16x8 bfr[NT];
#pragma unroll
            for (int nt = 0; nt < NT; ++nt)
                bfr[nt] = *(const bf16x8*)(wpack + ((size_t)(ch * NT + nt) * 64 + lane) * 8);
            const int slot = (cic * 32 + q * 8 + cbase * 8) % CIN;
#pragma unroll
            for (int mt = 0; mt < 4; ++mt) {
                const int orow = wv * 4 + mt;
                bf16x8 afr = *(const bf16x8*)&tile[orow + ky][cbase][slot];
#pragma unroll
                for (int nt = 0; nt < NT; ++nt)
                    acc[mt][nt] = __builtin_amdgcn_mfma_f32_16x16x32_bf16(afr, bfr[nt], acc[mt][nt], 0, 0, 0);
            }
        }
    }
#pragma unroll
    for (int nt = 0; nt < NT; ++nt) {
        const int co = nt * 16 + m;
        const float bv = bias[co];
#pragma unroll
        for (int mt = 0; mt < 4; ++mt) {
            const int oy = ty0 + wv * 4 + mt;
#pragma unroll
            for (int j = 0; j < 4; ++j) {
                const int ox = tx0 + q * 4 + j;
                if (oy < Hout && ox < Wout) {
                    float v = fmaxf(acc[mt][nt][j] + bv, 0.f);
                    out[(((size_t)n * Hout + oy) * Wout + ox) * 32 + co] = f2bf(v);
                }
            }
        }
    }
}

// ---------------- encoder conv1 (CIN=3, fp32 direct, co-split x4, NHWC bf16 out) ----------------
__global__ __launch_bounds__(256) void conv_ec1(
    const float* __restrict__ in, const float* __restrict__ wts,
    const float* __restrict__ bias, unsigned short* __restrict__ out)
{
    __shared__ float tile[3][20][21];
    const int blk = blockIdx.x;
    const int n = blk >> 6;            // 64 blocks/image: 16 tiles x 4 channel groups
    const int sub = blk & 63;
    const int t = sub >> 2;
    const int cog = sub & 3;
    const int ty0 = (t >> 2) * 16, tx0 = (t & 3) * 16;
    const int tid = threadIdx.x;
    for (int idx = tid; idx < 1200; idx += 256) {
        int ci = idx / 400, rc = idx % 400;
        int r = rc / 20, c = rc % 20;
        int gy = ty0 + r - 2, gx = tx0 + c - 2;
        float v = 0.f;
        if (gy >= 0 && gy < 64 && gx >= 0 && gx < 64)
            v = in[((size_t)n * 3 + ci) * 4096 + gy * 64 + gx];
        tile[ci][r][c] = v;
    }
    __syncthreads();
    const int lx = tid & 15, ly = tid >> 4;
    float acc[16];
#pragma unroll
    for (int co = 0; co < 16; ++co) acc[co] = bias[cog * 16 + co];
    for (int ci = 0; ci < 3; ++ci) {
        float val[25];
#pragma unroll
        for (int ky = 0; ky < 5; ++ky)
#pragma unroll
            for (int kx = 0; kx < 5; ++kx) val[ky * 5 + kx] = tile[ci][ly + ky][lx + kx];
#pragma unroll
        for (int co = 0; co < 16; ++co) {
            const float* wc = wts + (size_t)((cog * 16 + co) * 3 + ci) * 25;
            float a = acc[co];
#pragma unroll
            for (int tt = 0; tt < 25; ++tt) a = fmaf(val[tt], wc[tt], a);
            acc[co] = a;
        }
    }
    unsigned short tmp[16];
#pragma unroll
    for (int co = 0; co < 16; ++co) tmp[co] = f2bf(fmaxf(acc[co], 0.f));
    uint4* ob = (uint4*)(out + (((size_t)n * 64 + ty0 + ly) * 64 + tx0 + lx) * 64 + cog * 16);
    ob[0] = ((uint4*)tmp)[0];
    ob[1] = ((uint4*)tmp)[1];
}

// ---------------- encoder tail, MFMA: +pe, LN, fc1-relu-fc2, k/v ----------------
__global__ __launch_bounds__(256) void encoder_tail_mfma(
    const unsigned short* __restrict__ h4,
    const float* __restrict__ epw, const float* __restrict__ epb,
    const float* __restrict__ ln1g, const float* __restrict__ ln1b,
    const unsigned short* __restrict__ pfc1, const float* __restrict__ fc1b,
    const unsigned short* __restrict__ pfc2, const float* __restrict__ fc2b,
    const unsigned short* __restrict__ pkw, const unsigned short* __restrict__ pvw,
    float* __restrict__ kout, float* __restrict__ vout)
{
    __shared__ __align__(16) unsigned short X[64][72];
    const int b = blockIdx.x >> 6;
    const int y = blockIdx.x & 63;
    const int tid = threadIdx.x;

    {
        const int p = tid >> 2, sub = tid & 3;
        const unsigned short* hp = h4 + ((((size_t)b * 64 + y) * 64 + p) * 64) + sub * 16;
        unsigned short raw[16];
        *(uint4*)(raw)     = *(const uint4*)hp;
        *(uint4*)(raw + 8) = *(const uint4*)(hp + 8);
        const float fy = y * (1.f / 63.f), fx = p * (1.f / 63.f);
        float f[16];
        float s1 = 0.f, s2 = 0.f;
#pragma unroll
        for (int j = 0; j < 16; ++j) {
            int ch = sub * 16 + j;
            float pe = (1.f - fy) * epw[ch] + fy * epw[64 + ch]
                     + fx * epw[128 + ch] + (1.f - fx) * epw[192 + ch] + epb[ch];
            float v = bf2f(raw[j]) + pe;
            f[j] = v;
            s1 += v;
            s2 += v * v;
        }
        s1 += __shfl_xor(s1, 1, 64); s1 += __shfl_xor(s1, 2, 64);
        s2 += __shfl_xor(s2, 1, 64); s2 += __shfl_xor(s2, 2, 64);
        const float m = s1 * (1.f / 64.f);
        const float var = s2 * (1.f / 64.f) - m * m;
        const float inv = rsqrtf(var + 1e-5f);
        unsigned short xb[16];
#pragma unroll
        for (int j = 0; j < 16; ++j) {
            int ch = sub * 16 + j;
            xb[j] = f2bf((f[j] - m) * inv * ln1g[ch] + ln1b[ch]);
        }
        *(uint4*)&X[p][sub * 16]     = ((uint4*)xb)[0];
        *(uint4*)&X[p][sub * 16 + 8] = ((uint4*)xb)[1];
    }
    __syncthreads();

    const int w = tid >> 6, lane = tid & 63;
    const int q = lane >> 4, m_ = lane & 15;
    const int row0 = w * 16;

    {
        f32x4 a1[4];
#pragma unroll
        for (int nt = 0; nt < 4; ++nt) a1[nt] = (f32x4){0.f, 0.f, 0.f, 0.f};
#pragma unroll
        for (int ck = 0; ck < 2; ++ck) {
            bf16x8 afr = *(const bf16x8*)&X[row0 + m_][ck * 32 + q * 8];
#pragma unroll
            for (int nt = 0; nt < 4; ++nt) {
                bf16x8 bfr = *(const bf16x8*)(pfc1 + ((size_t)((ck * 4 + nt) * 64 + lane)) * 8);
                a1[nt] = __builtin_amdgcn_mfma_f32_16x16x32_bf16(afr, bfr, a1[nt], 0, 0, 0);
            }
        }
        __syncthreads();
#pragma unroll
        for (int nt = 0; nt < 4; ++nt) {
            const float bb = fc1b[nt * 16 + m_];
#pragma unroll
            for (int reg = 0; reg < 4; ++reg)
                X[row0 + q * 4 + reg][nt * 16 + m_] = f2bf(fmaxf(a1[nt][reg] + bb, 0.f));
        }
    }
    __syncthreads();

    {
        f32x4 a2[4];
#pragma unroll
        for (int nt = 0; nt < 4; ++nt) a2[nt] = (f32x4){0.f, 0.f, 0.f, 0.f};
#pragma unroll
        for (int ck = 0; ck < 2; ++ck) {
            bf16x8 afr = *(const bf16x8*)&X[row0 + m_][ck * 32 + q * 8];
#pragma unroll
            for (int nt = 0; nt < 4; ++nt) {
                bf16x8 bfr = *(const bf16x8*)(pfc2 + ((size_t)((ck * 4 + nt) * 64 + lane)) * 8);
                a2[nt] = __builtin_amdgcn_mfma_f32_16x16x32_bf16(afr, bfr, a2[nt], 0, 0, 0);
            }
        }
        __syncthreads();
#pragma unroll
        for (int nt = 0; nt < 4; ++nt) {
            const float bb = fc2b[nt * 16 + m_];
#pragma unroll
            for (int reg = 0; reg < 4; ++reg)
                X[row0 + q * 4 + reg][nt * 16 + m_] = f2bf(a2[nt][reg] + bb);
        }
    }
    __syncthreads();

    {
        f32x4 ak[4], av[4];
#pragma unroll
        for (int nt = 0; nt < 4; ++nt) {
            ak[nt] = (f32x4){0.f, 0.f, 0.f, 0.f};
            av[nt] = (f32x4){0.f, 0.f, 0.f, 0.f};
        }
#pragma unroll
        for (int ck = 0; ck < 2; ++ck) {
            bf16x8 afr = *(const bf16x8*)&X[row0 + m_][ck * 32 + q * 8];
#pragma unroll
            for (int nt = 0; nt < 4; ++nt) {
                bf16x8 bk = *(const bf16x8*)(pkw + ((size_t)((ck * 4 + nt) * 64 + lane)) * 8);
                bf16x8 bv = *(const bf16x8*)(pvw + ((size_t)((ck * 4 + nt) * 64 + lane)) * 8);
                ak[nt] = __builtin_amdgcn_mfma_f32_16x16x32_bf16(afr, bk, ak[nt], 0, 0, 0);
                av[nt] = __builtin_amdgcn_mfma_f32_16x16x32_bf16(afr, bv, av[nt], 0, 0, 0);
            }
        }
        const size_t base = ((size_t)b * 4096) + y * 64 + row0;
#pragma unroll
        for (int nt = 0; nt < 4; ++nt) {
            const int ch = nt * 16 + m_;
#pragma unroll
            for (int reg = 0; reg < 4; ++reg) {
                const size_t o = (base + q * 4 + reg) * 64 + ch;
                kout[o] = ak[nt][reg];
                vout[o] = av[nt][reg];
            }
        }
    }
}

// ---------------- slot init (+ rowsum zero) ----------------
__global__ __launch_bounds__(256) void slot_init(
    const float* __restrict__ noise, const float* __restrict__ init_slots,
    float* __restrict__ slots, float* __restrict__ rowsum)
{
    int i = blockIdx.x * 256 + threadIdx.x;
    if (i < 224) rowsum[i] = 0.f;
    if (i < 224 * 64) {
        int z = i & 63;
        float spl = log1pf(expf(init_slots[64 + z]));
        slots[i] = init_slots[z] + spl * noise[i];
    }
}

// ---------------- attention pass 1 (q computed in-block) ----------------
__global__ __launch_bounds__(256) void attn_pass1(
    const float* __restrict__ kbuf, const float* __restrict__ slots,
    const float* __restrict__ lnsg, const float* __restrict__ lnsb,
    const float* __restrict__ qw,
    float* __restrict__ attn, float* __restrict__ rowsum)
{
    __shared__ float qs[7][64];
    __shared__ float red[7][4];
    const int b = blockIdx.x >> 4;
    const int jb = (blockIdx.x & 15) * 256;
    const int tid = threadIdx.x;
    const int lane = tid & 63, wv = tid >> 6;
    // q = LN(slots)@qw * scale, waves split the 7 slots
    for (int i = wv; i < 7; i += 4) {
        float s = slots[(b * 7 + i) * 64 + lane];
        float m = wave_sum(s) * (1.f / 64.f);
        float d = s - m;
        float var = wave_sum(d * d) * (1.f / 64.f);
        float x = d * rsqrtf(var + 1e-5f) * lnsg[lane] + lnsb[lane];
        float qv = 0.f;
        for (int c = 0; c < 64; ++c) qv = fmaf(__shfl(x, c, 64), qw[c * 64 + lane], qv);
        qs[i][lane] = qv * SCALE_;
    }
    __syncthreads();
    const int j = jb + tid;
    float kr[64];
    const float* kp = kbuf + (((size_t)b * 4096) + j) * 64;
#pragma unroll
    for (int d4 = 0; d4 < 16; ++d4) {
        float4 kv = ((const float4*)kp)[d4];
        kr[d4 * 4 + 0] = kv.x; kr[d4 * 4 + 1] = kv.y;
        kr[d4 * 4 + 2] = kv.z; kr[d4 * 4 + 3] = kv.w;
    }
    float dots[7];
#pragma unroll
    for (int i = 0; i < 7; ++i) {
        float a = 0.f;
#pragma unroll
        for (int d = 0; d < 64; ++d) a = fmaf(kr[d], qs[i][d], a);
        dots[i] = a;
    }
    float mx = dots[0];
#pragma unroll
    for (int i = 1; i < 7; ++i) mx = fmaxf(mx, dots[i]);
    float sum = 0.f;
#pragma unroll
    for (int i = 0; i < 7; ++i) { dots[i] = expf(dots[i] - mx); sum += dots[i]; }
    const float inv = 1.f / sum;
#pragma unroll
    for (int i = 0; i < 7; ++i) {
        float a = dots[i] * inv + 1e-8f;
        dots[i] = a;
        attn[(((size_t)b * 7) + i) * 4096 + j] = a;
    }
#pragma unroll
    for (int i = 0; i < 7; ++i) {
        float s = wave_sum(dots[i]);
        if (lane == 0) red[i][wv] = s;
    }
    __syncthreads();
    if (tid < 7) {
        float s = red[tid][0] + red[tid][1] + red[tid][2] + red[tid][3];
        atomicAdd(&rowsum[b * 7 + tid], s);
    }
}

// ---------------- attention pass 2 ----------------
__global__ __launch_bounds__(256) void attn_pass2(
    const float* __restrict__ vbuf, const float* __restrict__ attn,
    float* __restrict__ part)
{
    const int b = blockIdx.x >> 4;
    const int js = blockIdx.x & 15;
    const int tid = threadIdx.x;
    const int d = tid & 63, jc = tid >> 6;
    float acc[7];
#pragma unroll
    for (int i = 0; i < 7; ++i) acc[i] = 0.f;
    const int j0 = js * 256;
    for (int j = j0 + jc; j < j0 + 256; j += 4) {
        float av = vbuf[(((size_t)b * 4096) + j) * 64 + d];
#pragma unroll
        for (int i = 0; i < 7; ++i)
            acc[i] = fmaf(attn[(((size_t)b * 7) + i) * 4096 + j], av, acc[i]);
    }
    __shared__ float red[4][7][64];
#pragma unroll
    for (int i = 0; i < 7; ++i) red[jc][i][d] = acc[i];
    __syncthreads();
    if (tid < 7 * 64) {
        int i = tid / 64, dd = tid % 64;
        float s = red[0][i][dd] + red[1][i][dd] + red[2][i][dd] + red[3][i][dd];
        part[((((size_t)b * 16) + js) * 7 + i) * 64 + dd] = s;
    }
}

// ---------------- GRU + residual MLP (+ rowsum re-zero for next iter) ----------------
__global__ __launch_bounds__(64) void gru_mlp(
    float* __restrict__ slots, const float* __restrict__ part,
    float* __restrict__ rowsum,
    const float* __restrict__ wih, const float* __restrict__ whh,
    const float* __restrict__ bih, const float* __restrict__ bhh,
    const float* __restrict__ lnfg, const float* __restrict__ lnfb,
    const float* __restrict__ m1w, const float* __restrict__ m1b,
    const float* __restrict__ m2w, const float* __restrict__ m2b)
{
    const int n = blockIdx.x;
    const int b = n / 7, i = n % 7;
    const int l = threadIdx.x;
    float upd = 0.f;
    for (int js = 0; js < 16; ++js)
        upd += part[((((size_t)b * 16) + js) * 7 + i) * 64 + l];
    upd /= rowsum[n];
    if (l == 0) rowsum[n] = 0.f;   // prep next iteration's atomics
    const float prev = slots[n * 64 + l];
    float gi0 = bih[l], gi1 = bih[64 + l], gi2 = bih[128 + l];
    float gh0 = bhh[l], gh1 = bhh[64 + l], gh2 = bhh[128 + l];
    for (int c = 0; c < 64; ++c) {
        float u = __shfl(upd, c, 64), p = __shfl(prev, c, 64);
        gi0 = fmaf(u, wih[l * 64 + c], gi0);
        gi1 = fmaf(u, wih[(64 + l) * 64 + c], gi1);
        gi2 = fmaf(u, wih[(128 + l) * 64 + c], gi2);
        gh0 = fmaf(p, whh[l * 64 + c], gh0);
        gh1 = fmaf(p, whh[(64 + l) * 64 + c], gh1);
        gh2 = fmaf(p, whh[(128 + l) * 64 + c], gh2);
    }
    float r  = 1.f / (1.f + expf(-(gi0 + gh0)));
    float zg = 1.f / (1.f + expf(-(gi1 + gh1)));
    float nn = tanhf(gi2 + r * gh2);
    float s = (1.f - zg) * nn + zg * prev;
    float m = wave_sum(s) * (1.f / 64.f);
    float d = s - m;
    float var = wave_sum(d * d) * (1.f / 64.f);
    float x = d * rsqrtf(var + 1e-5f) * lnfg[l] + lnfb[l];
    float h0 = m1b[l], h1 = m1b[64 + l];
    for (int c = 0; c < 64; ++c) {
        float xv = __shfl(x, c, 64);
        h0 = fmaf(xv, m1w[c * 128 + l], h0);
        h1 = fmaf(xv, m1w[c * 128 + 64 + l], h1);
    }
    h0 = fmaxf(h0, 0.f); h1 = fmaxf(h1, 0.f);
    float o = m2b[l];
    for (int c = 0; c < 64; ++c) {
        o = fmaf(__shfl(h0, c, 64), m2w[c * 64 + l], o);
        o = fmaf(__shfl(h1, c, 64), m2w[(64 + c) * 64 + l], o);
    }
    slots[n * 64 + l] = s + o;
}

// ---------------- finalize (dc4out NHWC fp32 [img][p][4]) ----------------
__global__ __launch_bounds__(256) void finalize_k(
    const float* __restrict__ dc4out, const float* __restrict__ inputs,
    float* __restrict__ out)
{
    const int tid = threadIdx.x;
    const int gp = blockIdx.x * 256 + tid;
    const int b = gp >> 12, p = gp & 4095;
    float4 o4[7];
#pragma unroll
    for (int k = 0; k < 7; ++k)
        o4[k] = ((const float4*)dc4out)[(size_t)(b * 7 + k) * 4096 + p];
    float mx = o4[0].w;
#pragma unroll
    for (int k = 1; k < 7; ++k) mx = fmaxf(mx, o4[k].w);
    float s = 0.f;
#pragma unroll
    for (int k = 0; k < 7; ++k) s += expf(o4[k].w - mx);
    const float lse = mx + logf(s);
    float recon0 = 0.f, recon1 = 0.f, recon2 = 0.f;
    float* xl = out + 1;
    float* ml = out + 2752513;
#pragma unroll
    for (int k = 0; k < 7; ++k) {
        float lp = o4[k].w - lse;
        ml[((size_t)(b * 7 + k)) * 4096 + p] = lp;
        float w = expf(lp);
        float x0 = 1.f / (1.f + expf(-o4[k].x));
        float x1 = 1.f / (1.f + expf(-o4[k].y));
        float x2 = 1.f / (1.f + expf(-o4[k].z));
        xl[(((size_t)(b * 7 + k)) * 3 + 0) * 4096 + p] = x0;
        xl[(((size_t)(b * 7 + k)) * 3 + 1) * 4096 + p] = x1;
        xl[(((size_t)(b * 7 + k)) * 3 + 2) * 4096 + p] = x2;
        recon0 = fmaf(x0, w, recon0);
        recon1 = fmaf(x1, w, recon1);
        recon2 = fmaf(x2, w, recon2);
    }
    float err = 0.f;
    {
        float xo = (inputs[((size_t)b * 3 + 0) * 4096 + p] + 1.f) * 0.5f;
        float dd = xo - recon0; err += dd * dd;
        xo = (inputs[((size_t)b * 3 + 1) * 4096 + p] + 1.f) * 0.5f;
        dd = xo - recon1; err += dd * dd;
        xo = (inputs[((size_t)b * 3 + 2) * 4096 + p] + 1.f) * 0.5f;
        dd = xo - recon2; err += dd * dd;
    }
    float wsum = wave_sum(err);
    __shared__ float red[4];
    const int lane = tid & 63, wv = tid >> 6;
    if (lane == 0) red[wv] = wsum;
    __syncthreads();
    if (tid == 0) atomicAdd(out, (red[0] + red[1] + red[2] + red[3]) * (1.f / 32.f));
}

// ---------------- copy slots to out (+ zero mse slot; runs BEFORE finalize) ----------------
__global__ __launch_bounds__(256) void copy_slots(const float* __restrict__ slots,
                                                  float* __restrict__ out)
{
    int i = blockIdx.x * 256 + threadIdx.x;
    if (i == 0) out[0] = 0.f;
    if (i < 14336) out[3670017 + i] = slots[i];
}

// ---------------- launch ----------------
extern "C" void kernel_launch(void* const* d_in, const int* in_sizes, int n_in,
                              void* d_out, int out_size, void* d_ws, size_t ws_size,
                              hipStream_t stream) {
    (void)in_sizes; (void)n_in; (void)out_size; (void)ws_size;
    const float* inputs = (const float*)d_in[0];
    const float* noise  = (const float*)d_in[1];
    const float* epw  = (const float*)d_in[2];
    const float* epb  = (const float*)d_in[3];
    const float* ec1w = (const float*)d_in[4];
    const float* ec1b = (const float*)d_in[5];
    const float* ec2w = (const float*)d_in[6];
    const float* ec2b = (const float*)d_in[7];
    const float* ec3w = (const float*)d_in[8];
    const float* ec3b = (const float*)d_in[9];
    const float* ec4w = (const float*)d_in[10];
    const float* ec4b = (const float*)d_in[11];
    const float* ln1g = (const float*)d_in[12];
    const float* ln1b = (const float*)d_in[13];
    const float* fc1w = (const float*)d_in[14];
    const float* fc1b = (const float*)d_in[15];
    const float* fc2w = (const float*)d_in[16];
    const float* fc2b = (const float*)d_in[17];
    const float* lnsg = (const float*)d_in[18];
    const float* lnsb = (const float*)d_in[19];
    const float* lnfg = (const float*)d_in[20];
    const float* lnfb = (const float*)d_in[21];
    const float* qw   = (const float*)d_in[22];
    const float* kw   = (const float*)d_in[23];
    const float* vw   = (const float*)d_in[24];
    const float* m1w  = (const float*)d_in[25];
    const float* m1b  = (const float*)d_in[26];
    const float* m2w  = (const float*)d_in[27];
    const float* m2b  = (const float*)d_in[28];
    const float* wih  = (const float*)d_in[29];
    const float* whh  = (const float*)d_in[30];
    const float* bih  = (const float*)d_in[31];
    const float* bhh  = (const float*)d_in[32];
    const float* init_slots = (const float*)d_in[33];
    const float* dpw  = (const float*)d_in[34];
    const float* dpb  = (const float*)d_in[35];
    const float* dc1w = (const float*)d_in[36];
    const float* dc1b = (const float*)d_in[37];
    const float* dc2w = (const float*)d_in[38];
    const float* dc2b = (const float*)d_in[39];
    const float* dc3w = (const float*)d_in[40];
    const float* dc3b = (const float*)d_in[41];
    const float* dc4w = (const float*)d_in[42];
    const float* dc4b = (const float*)d_in[43];

    float* ws = (float*)d_ws;
    unsigned short* B0 = (unsigned short*)(ws + WS_B0);
    unsigned short* B1 = (unsigned short*)(ws + WS_B1);
    float* K = ws + WS_K;
    float* V = ws + WS_V;
    // decode-phase overlays
    unsigned short* dping = (unsigned short*)(ws + WS_B0);   // 33.5 MB (spans B0+B1)
    unsigned short* dpong = (unsigned short*)(ws + WS_K);    // 33.5 MB (over dead K)
    float* dc4out = V;                                       // 14.7 MB (over dead V)
    unsigned short* PK = (unsigned short*)(ws + WS_V + 4194304u);
    unsigned short* p_ec2 = PK, *p_ec3 = PK + 102400, *p_ec4 = PK + 204800;
    unsigned short* p_dc1 = PK, *p_dc2 = PK + 51200, *p_dc3 = PK + 76800, *p_dc4 = PK + 102400;
    float* attn  = ws + WS_ATTN;
    unsigned short* PFC = (unsigned short*)attn;             // live only until encoder_tail done
    unsigned short* p_fc1 = PFC, *p_fc2 = PFC + 4096, *p_kw = PFC + 8192, *p_vw = PFC + 12288;
    float* part  = ws + WS_PART;
    float* slots = ws + WS_SLOT;
    float* rowsum = ws + WS_ROW;
    float* out = (float*)d_out;

    // ---- pack encoder weights ----
    pack_weights<<<50, 256, 0, stream>>>(ec2w, p_ec2, 64, 64, 5, 4, 12800);
    pack_weights<<<50, 256, 0, stream>>>(ec3w, p_ec3, 64, 64, 5, 4, 12800);
    pack_weights<<<50, 256, 0, stream>>>(ec4w, p_ec4, 64, 64, 5, 4, 12800);
    pack_fc<<<2, 256, 0, stream>>>(fc1w, p_fc1);
    pack_fc<<<2, 256, 0, stream>>>(fc2w, p_fc2);
    pack_fc<<<2, 256, 0, stream>>>(kw, p_kw);
    pack_fc<<<2, 256, 0, stream>>>(vw, p_vw);

    // ---- encoder ----
    conv_ec1<<<2048, 256, 0, stream>>>(inputs, ec1w, ec1b, B0);
    conv_mfma<64, 64, 5, 2, 64, 1, 0><<<512, 256, 0, stream>>>(B0, p_ec2, ec2b, B1, 64, 64, 64, 64, 4, 4);
    conv_mfma<64, 64, 5, 2, 64, 1, 0><<<512, 256, 0, stream>>>(B1, p_ec3, ec3b, B0, 64, 64, 64, 64, 4, 4);
    conv_mfma<64, 64, 5, 2, 64, 1, 0><<<512, 256, 0, stream>>>(B0, p_ec4, ec4b, B1, 64, 64, 64, 64, 4, 4);
    encoder_tail_mfma<<<2048, 256, 0, stream>>>(B1, epw, epb, ln1g, ln1b,
                                                p_fc1, fc1b, p_fc2, fc2b, p_kw, p_vw, K, V);
    slot_init<<<56, 256, 0, stream>>>(noise, init_slots, slots, rowsum);

    // ---- 3 slot-attention iterations ----
    for (int it = 0; it < 3; ++it) {
        attn_pass1<<<512, 256, 0, stream>>>(K, slots, lnsg, lnsb, qw, attn, rowsum);
        attn_pass2<<<512, 256, 0, stream>>>(V, attn, part);
        gru_mlp<<<224, 64, 0, stream>>>(slots, part, rowsum, wih, whh, bih, bhh,
                                        lnfg, lnfb, m1w, m1b, m2w, m2b);
    }

    // ---- pack decoder weights (K/V attn roles done) ----
    pack_weights<<<25, 256, 0, stream>>>(dc1w, p_dc1, 64, 32, 5, 2, 6400);
    pack_weights<<<13, 256, 0, stream>>>(dc2w, p_dc2, 32, 32, 5, 2, 3200);
    pack_weights<<<13, 256, 0, stream>>>(dc3w, p_dc3, 32, 32, 5, 2, 3200);
    pack_weights<<<3, 256, 0, stream>>>(dc4w, p_dc4, 32, 4, 3, 1, 576);

    // ---- decoder, 2 chunks of 112 images ----
    for (int ch = 0; ch < 2; ++ch) {
        const float* sl = slots + (size_t)ch * 112 * 64;
        float* d4o = dc4out + (size_t)ch * 112 * 4 * 4096;
        conv_dec1_mfma<<<2800, 256, 0, stream>>>(sl, dpw, dpb, p_dc1, dc1b, dping);
        conv_mfma<32, 32, 5, 1, 32, 1, 0><<<2800, 256, 0, stream>>>(dping, p_dc2, dc2b, dpong, 68, 68, 66, 66, 5, 5);
        conv_mfma<32, 32, 5, 1, 32, 1, 0><<<1792, 256, 0, stream>>>(dpong, p_dc3, dc3b, dping, 66, 66, 64, 64, 4, 4);
        conv_mfma<32, 16, 3, 1, 4, 0, 1><<<1792, 256, 0, stream>>>(dping, p_dc4, dc4b, d4o, 64, 64, 64, 64, 4, 4);
    }

    // ---- outputs ----
    copy_slots<<<56, 256, 0, stream>>>(slots, out);
    finalize_k<<<512, 256, 0, stream>>>(dc4out, inputs, out);
}

// Round 5
// 840.974 us; speedup vs baseline: 11.5618x; 1.1464x over previous
//
#include <hip/hip_runtime.h>
#include <math.h>

typedef short bf16x8 __attribute__((ext_vector_type(8)));
typedef float f32x4 __attribute__((ext_vector_type(4)));

// workspace layout (float offsets)
#define WS_B0   0u           // encode: B0 (bf16 ping). decode: dec ping (33.5MB spans B0+B1)
#define WS_B1   4194304u     // encode: B1 (bf16 pong)
#define WS_K    8388608u     // encode/attn: k fp32. decode: dec pong (bf16)
#define WS_V    16777216u    // encode/attn: v fp32. decode: dc4out fp32 @+0, packed wts @+4194304
#define WS_ATTN 25165824u    // attn (917504). decode: peb/Wcls/S/zbias overlays
#define WS_PART 26083328u    // attn partials (229376). decode: P = conv(pe) fp32 [68][68][32]
#define WS_SLOT 26327040u    // 14336
#define WS_ROW  26341376u    // 224
#define SCALE_ 0.125f

// decode-phase overlays inside attn region (float offsets from attn base)
#define OFF_PEB   0u         // 156800 floats = 313600 bf16 : pe input field [70][70][64]
#define OFF_WCLS  160000u    // 18432 floats : Wcls[9][32][64]
#define OFF_S     180000u    // 64512 floats : S[224][9][32]
#define OFF_ZB    250000u    // 32 floats : zero bias

__device__ __forceinline__ float wave_sum(float v) {
#pragma unroll
    for (int m = 32; m >= 1; m >>= 1) v += __shfl_xor(v, m, 64);
    return v;
}
__device__ __forceinline__ unsigned short f2bf(float f) {
    unsigned u = __float_as_uint(f);
    u = u + 0x7fffu + ((u >> 16) & 1u);
    return (unsigned short)(u >> 16);
}
__device__ __forceinline__ float bf2f(unsigned short h) {
    return __uint_as_float(((unsigned)h) << 16);
}

// ---------------- weight packing into B-fragment order (conv, [COUT][CIN][KS][KS]) ----------------
__global__ __launch_bounds__(256) void pack_weights(
    const float* __restrict__ w, unsigned short* __restrict__ wp,
    int CIN, int COUT_STORE, int KS, int NT, int total)
{
    int t = blockIdx.x * 256 + threadIdx.x;
    if (t >= total) return;
    int lane = t & 63;
    int nt = (t >> 6) % NT;
    int ch = t / (64 * NT);
    int CPT = CIN / 32;
    int cic = ch % CPT;
    int tap = ch / CPT;
    int ky = tap / KS, kx = tap % KS;
    int co = nt * 16 + (lane & 15);
    int k0 = cic * 32 + (lane >> 4) * 8;
    unsigned short v[8];
#pragma unroll
    for (int j = 0; j < 8; ++j) {
        int ci = k0 + j;
        float f = (co < COUT_STORE) ? w[((size_t)(co * CIN + ci) * KS + ky) * KS + kx] : 0.f;
        v[j] = f2bf(f);
    }
    *(uint4*)(wp + (size_t)t * 8) = *(uint4*)v;
}

// ---------------- fc weight packing ([K=64][N=64] row-major) into B-frag order ----------------
__global__ __launch_bounds__(256) void pack_fc(
    const float* __restrict__ w, unsigned short* __restrict__ wp)
{
    int t = blockIdx.x * 256 + threadIdx.x;
    if (t >= 512) return;
    int lane = t & 63;
    int nt = (t >> 6) & 3;
    int ck = t >> 8;
    int n = nt * 16 + (lane & 15);
    int k0 = ck * 32 + (lane >> 4) * 8;
    unsigned short v[8];
#pragma unroll
    for (int j = 0; j < 8; ++j) v[j] = f2bf(w[(size_t)(k0 + j) * 64 + n]);
    *(uint4*)(wp + (size_t)t * 8) = *(uint4*)v;
}

// ---------------- MFMA implicit-GEMM conv ----------------
template<int CIN, int COUT, int KS, int PAD, int NSTORE, int RELU, int OUTF32>
__global__ __launch_bounds__(256) void conv_mfma(
    const unsigned short* __restrict__ in, const unsigned short* __restrict__ wpack,
    const float* __restrict__ bias, void* __restrict__ outv,
    int Hin, int Win, int Hout, int Wout, int tilesX, int tilesY)
{
    constexpr int TS = 16, TH = TS + KS - 1;
    constexpr int NT = COUT / 16;
    constexpr int CPT = CIN / 32;
    constexpr int G8 = CIN / 8;
    __shared__ __align__(16) unsigned short tile[TH][TH][CIN];
    const int tpb = tilesX * tilesY;
    const int n = blockIdx.x / tpb;
    const int t = blockIdx.x % tpb;
    const int ty0 = (t / tilesX) * TS, tx0 = (t % tilesX) * TS;
    const int tid = threadIdx.x;

    const unsigned short* inb = in + (size_t)n * Hin * Win * CIN;
    for (int idx = tid; idx < TH * TH * G8; idx += 256) {
        int g = idx % G8;
        int c = (idx / G8) % TH;
        int r = idx / (G8 * TH);
        int iy = ty0 - PAD + r, ix = tx0 - PAD + c;
        uint4 vv = make_uint4(0, 0, 0, 0);
        if (iy >= 0 && iy < Hin && ix >= 0 && ix < Win)
            vv = *(const uint4*)(inb + ((size_t)iy * Win + ix) * CIN + g * 8);
        int slot = (g * 8 + c * 8) % CIN;
        *(uint4*)&tile[r][c][slot] = vv;
    }
    __syncthreads();

    const int wv = tid >> 6, lane = tid & 63;
    const int q = lane >> 4, m = lane & 15;
    f32x4 acc[4][NT];
#pragma unroll
    for (int mt = 0; mt < 4; ++mt)
#pragma unroll
        for (int nt = 0; nt < NT; ++nt) acc[mt][nt] = (f32x4){0.f, 0.f, 0.f, 0.f};

    for (int tap = 0; tap < KS * KS; ++tap) {
        const int ky = tap / KS, kx = tap % KS;
        const int cbase = m + kx;
#pragma unroll
        for (int cic = 0; cic < CPT; ++cic) {
            const int ch = tap * CPT + cic;
            bf16x8 bfr[NT];
#pragma unroll
            for (int nt = 0; nt < NT; ++nt)
                bfr[nt] = *(const bf16x8*)(wpack + ((size_t)(ch * NT + nt) * 64 + lane) * 8);
            const int slot = (cic * 32 + q * 8 + cbase * 8) % CIN;
#pragma unroll
            for (int mt = 0; mt < 4; ++mt) {
                const int orow = wv * 4 + mt;
                bf16x8 afr = *(const bf16x8*)&tile[orow + ky][cbase][slot];
#pragma unroll
                for (int nt = 0; nt < NT; ++nt)
                    acc[mt][nt] = __builtin_amdgcn_mfma_f32_16x16x32_bf16(afr, bfr[nt], acc[mt][nt], 0, 0, 0);
            }
        }
    }

#pragma unroll
    for (int nt = 0; nt < NT; ++nt) {
        const int co = nt * 16 + m;
        const float bv = (co < NSTORE) ? bias[co] : 0.f;
#pragma unroll
        for (int mt = 0; mt < 4; ++mt) {
            const int oy = ty0 + wv * 4 + mt;
#pragma unroll
            for (int j = 0; j < 4; ++j) {
                const int ox = tx0 + q * 4 + j;
                if (oy < Hout && ox < Wout && co < NSTORE) {
                    float v = acc[mt][nt][j] + bv;
                    if (RELU) v = fmaxf(v, 0.f);
                    size_t o = (((size_t)n * Hout + oy) * Wout + ox) * NSTORE + co;
                    if (OUTF32) ((float*)outv)[o] = v;
                    else ((unsigned short*)outv)[o] = f2bf(v);
                }
            }
        }
    }
}

// ---------------- pe field synth: peb[70][70][64] bf16 (input - slot part); also zero zbias ----------------
__global__ __launch_bounds__(256) void pe_synth(
    const float* __restrict__ dpw, const float* __restrict__ dpb,
    unsigned short* __restrict__ peb, float* __restrict__ zbias)
{
    const int tid = threadIdx.x;
    if (blockIdx.x == 0 && tid < 32) zbias[tid] = 0.f;
    const int pix = blockIdx.x * 256 + tid;
    if (pix >= 4900) return;
    const int iy = pix / 70, ix = pix % 70;
    const float fy = iy * (1.f / 69.f), fx = ix * (1.f / 69.f);
    unsigned short v[64];
#pragma unroll
    for (int ci = 0; ci < 64; ++ci) {
        float p = (1.f - fy) * dpw[ci] + fy * dpw[64 + ci]
                + fx * dpw[128 + ci] + (1.f - fx) * dpw[192 + ci] + dpb[ci];
        v[ci] = f2bf(p);
    }
    uint4* ob = (uint4*)(peb + (size_t)pix * 64);
#pragma unroll
    for (int i = 0; i < 8; ++i) ob[i] = ((uint4*)v)[i];
}

// ---------------- Wcls[9][32][64]: tap-masked weight sums (9 border classes) ----------------
__global__ __launch_bounds__(256) void wcls_build(
    const float* __restrict__ w, float* __restrict__ wcls)
{
    int idx = blockIdx.x * 256 + threadIdx.x;
    if (idx >= 9 * 32 * 64) return;
    int cls = idx / (32 * 64);
    int co = (idx / 64) % 32;
    int ci = idx % 64;
    int rc = cls / 3, cc = cls % 3;
    int ky0 = (rc == 0) ? 1 : 0, ky1 = (rc == 2) ? 3 : 4;
    int kx0 = (cc == 0) ? 1 : 0, kx1 = (cc == 2) ? 3 : 4;
    float s = 0.f;
    const float* wb = w + (size_t)(co * 64 + ci) * 25;
    for (int ky = ky0; ky <= ky1; ++ky)
        for (int kx = kx0; kx <= kx1; ++kx)
            s += wb[ky * 5 + kx];
    wcls[idx] = s;
}

// ---------------- S[224][9][32] = slots @ Wcls^T ----------------
__global__ __launch_bounds__(256) void slot_s(
    const float* __restrict__ slots, const float* __restrict__ wcls,
    float* __restrict__ S)
{
    int idx = blockIdx.x * 256 + threadIdx.x;
    if (idx >= 224 * 9 * 32) return;
    int n = idx / (9 * 32);
    int cls = (idx / 32) % 9;
    int co = idx % 32;
    const float* sl = slots + n * 64;
    const float* wc = wcls + (size_t)(cls * 32 + co) * 64;
    float s = 0.f;
#pragma unroll
    for (int ci = 0; ci < 64; ++ci) s = fmaf(sl[ci], wc[ci], s);
    S[idx] = s;
}

// ---------------- dc1 assemble: out = ReLU(bias + P + S), NHWC bf16 ----------------
__global__ __launch_bounds__(256) void dc1_assemble(
    const float* __restrict__ P,      // [68][68][32] fp32
    const float* __restrict__ S,      // [224][9][32] fp32 (global n)
    const float* __restrict__ bias,   // dc1b[32]
    int n0,                           // global image offset of this chunk
    unsigned short* __restrict__ out) // [112][68][68][32] bf16
{
    const int gid = blockIdx.x * 256 + threadIdx.x;  // 0 .. 112*4624-1
    const int nl = gid / 4624;
    const int pix = gid % 4624;
    const int oy = pix / 68, ox = pix % 68;
    const int rc = (oy == 0) ? 0 : ((oy == 67) ? 2 : 1);
    const int cc = (ox == 0) ? 0 : ((ox == 67) ? 2 : 1);
    const float* Sp = S + ((size_t)(n0 + nl) * 9 + (rc * 3 + cc)) * 32;
    const float* Pp = P + (size_t)pix * 32;
    unsigned short v[32];
#pragma unroll
    for (int co = 0; co < 32; ++co)
        v[co] = f2bf(fmaxf(bias[co] + Pp[co] + Sp[co], 0.f));
    uint4* ob = (uint4*)(out + ((size_t)nl * 4624 + pix) * 32);
#pragma unroll
    for (int i = 0; i < 4; ++i) ob[i] = ((uint4*)v)[i];
}

// ---------------- encoder conv1 (CIN=3, fp32 direct, co-split x4, NHWC bf16 out) ----------------
__global__ __launch_bounds__(256) void conv_ec1(
    const float* __restrict__ in, const float* __restrict__ wts,
    const float* __restrict__ bias, unsigned short* __restrict__ out)
{
    __shared__ float tile[3][20][21];
    const int blk = blockIdx.x;
    const int n = blk >> 6;
    const int sub = blk & 63;
    const int t = sub >> 2;
    const int cog = sub & 3;
    const int ty0 = (t >> 2) * 16, tx0 = (t & 3) * 16;
    const int tid = threadIdx.x;
    for (int idx = tid; idx < 1200; idx += 256) {
        int ci = idx / 400, rc = idx % 400;
        int r = rc / 20, c = rc % 20;
        int gy = ty0 + r - 2, gx = tx0 + c - 2;
        float v = 0.f;
        if (gy >= 0 && gy < 64 && gx >= 0 && gx < 64)
            v = in[((size_t)n * 3 + ci) * 4096 + gy * 64 + gx];
        tile[ci][r][c] = v;
    }
    __syncthreads();
    const int lx = tid & 15, ly = tid >> 4;
    float acc[16];
#pragma unroll
    for (int co = 0; co < 16; ++co) acc[co] = bias[cog * 16 + co];
    for (int ci = 0; ci < 3; ++ci) {
        float val[25];
#pragma unroll
        for (int ky = 0; ky < 5; ++ky)
#pragma unroll
            for (int kx = 0; kx < 5; ++kx) val[ky * 5 + kx] = tile[ci][ly + ky][lx + kx];
#pragma unroll
        for (int co = 0; co < 16; ++co) {
            const float* wc = wts + (size_t)((cog * 16 + co) * 3 + ci) * 25;
            float a = acc[co];
#pragma unroll
            for (int tt = 0; tt < 25; ++tt) a = fmaf(val[tt], wc[tt], a);
            acc[co] = a;
        }
    }
    unsigned short tmp[16];
#pragma unroll
    for (int co = 0; co < 16; ++co) tmp[co] = f2bf(fmaxf(acc[co], 0.f));
    uint4* ob = (uint4*)(out + (((size_t)n * 64 + ty0 + ly) * 64 + tx0 + lx) * 64 + cog * 16);
    ob[0] = ((uint4*)tmp)[0];
    ob[1] = ((uint4*)tmp)[1];
}

// ---------------- encoder tail, MFMA: +pe, LN, fc1-relu-fc2, k/v ----------------
__global__ __launch_bounds__(256) void encoder_tail_mfma(
    const unsigned short* __restrict__ h4,
    const float* __restrict__ epw, const float* __restrict__ epb,
    const float* __restrict__ ln1g, const float* __restrict__ ln1b,
    const unsigned short* __restrict__ pfc1, const float* __restrict__ fc1b,
    const unsigned short* __restrict__ pfc2, const float* __restrict__ fc2b,
    const unsigned short* __restrict__ pkw, const unsigned short* __restrict__ pvw,
    float* __restrict__ kout, float* __restrict__ vout)
{
    __shared__ __align__(16) unsigned short X[64][72];
    const int b = blockIdx.x >> 6;
    const int y = blockIdx.x & 63;
    const int tid = threadIdx.x;

    {
        const int p = tid >> 2, sub = tid & 3;
        const unsigned short* hp = h4 + ((((size_t)b * 64 + y) * 64 + p) * 64) + sub * 16;
        unsigned short raw[16];
        *(uint4*)(raw)     = *(const uint4*)hp;
        *(uint4*)(raw + 8) = *(const uint4*)(hp + 8);
        const float fy = y * (1.f / 63.f), fx = p * (1.f / 63.f);
        float f[16];
        float s1 = 0.f, s2 = 0.f;
#pragma unroll
        for (int j = 0; j < 16; ++j) {
            int ch = sub * 16 + j;
            float pe = (1.f - fy) * epw[ch] + fy * epw[64 + ch]
                     + fx * epw[128 + ch] + (1.f - fx) * epw[192 + ch] + epb[ch];
            float v = bf2f(raw[j]) + pe;
            f[j] = v;
            s1 += v;
            s2 += v * v;
        }
        s1 += __shfl_xor(s1, 1, 64); s1 += __shfl_xor(s1, 2, 64);
        s2 += __shfl_xor(s2, 1, 64); s2 += __shfl_xor(s2, 2, 64);
        const float m = s1 * (1.f / 64.f);
        const float var = s2 * (1.f / 64.f) - m * m;
        const float inv = rsqrtf(var + 1e-5f);
        unsigned short xb[16];
#pragma unroll
        for (int j = 0; j < 16; ++j) {
            int ch = sub * 16 + j;
            xb[j] = f2bf((f[j] - m) * inv * ln1g[ch] + ln1b[ch]);
        }
        *(uint4*)&X[p][sub * 16]     = ((uint4*)xb)[0];
        *(uint4*)&X[p][sub * 16 + 8] = ((uint4*)xb)[1];
    }
    __syncthreads();

    const int w = tid >> 6, lane = tid & 63;
    const int q = lane >> 4, m_ = lane & 15;
    const int row0 = w * 16;

    {
        f32x4 a1[4];
#pragma unroll
        for (int nt = 0; nt < 4; ++nt) a1[nt] = (f32x4){0.f, 0.f, 0.f, 0.f};
#pragma unroll
        for (int ck = 0; ck < 2; ++ck) {
            bf16x8 afr = *(const bf16x8*)&X[row0 + m_][ck * 32 + q * 8];
#pragma unroll
            for (int nt = 0; nt < 4; ++nt) {
                bf16x8 bfr = *(const bf16x8*)(pfc1 + ((size_t)((ck * 4 + nt) * 64 + lane)) * 8);
                a1[nt] = __builtin_amdgcn_mfma_f32_16x16x32_bf16(afr, bfr, a1[nt], 0, 0, 0);
            }
        }
        __syncthreads();
#pragma unroll
        for (int nt = 0; nt < 4; ++nt) {
            const float bb = fc1b[nt * 16 + m_];
#pragma unroll
            for (int reg = 0; reg < 4; ++reg)
                X[row0 + q * 4 + reg][nt * 16 + m_] = f2bf(fmaxf(a1[nt][reg] + bb, 0.f));
        }
    }
    __syncthreads();

    {
        f32x4 a2[4];
#pragma unroll
        for (int nt = 0; nt < 4; ++nt) a2[nt] = (f32x4){0.f, 0.f, 0.f, 0.f};
#pragma unroll
        for (int ck = 0; ck < 2; ++ck) {
            bf16x8 afr = *(const bf16x8*)&X[row0 + m_][ck * 32 + q * 8];
#pragma unroll
            for (int nt = 0; nt < 4; ++nt) {
                bf16x8 bfr = *(const bf16x8*)(pfc2 + ((size_t)((ck * 4 + nt) * 64 + lane)) * 8);
                a2[nt] = __builtin_amdgcn_mfma_f32_16x16x32_bf16(afr, bfr, a2[nt], 0, 0, 0);
            }
        }
        __syncthreads();
#pragma unroll
        for (int nt = 0; nt < 4; ++nt) {
            const float bb = fc2b[nt * 16 + m_];
#pragma unroll
            for (int reg = 0; reg < 4; ++reg)
                X[row0 + q * 4 + reg][nt * 16 + m_] = f2bf(a2[nt][reg] + bb);
        }
    }
    __syncthreads();

    {
        f32x4 ak[4], av[4];
#pragma unroll
        for (int nt = 0; nt < 4; ++nt) {
            ak[nt] = (f32x4){0.f, 0.f, 0.f, 0.f};
            av[nt] = (f32x4){0.f, 0.f, 0.f, 0.f};
        }
#pragma unroll
        for (int ck = 0; ck < 2; ++ck) {
            bf16x8 afr = *(const bf16x8*)&X[row0 + m_][ck * 32 + q * 8];
#pragma unroll
            for (int nt = 0; nt < 4; ++nt) {
                bf16x8 bk = *(const bf16x8*)(pkw + ((size_t)((ck * 4 + nt) * 64 + lane)) * 8);
                bf16x8 bv = *(const bf16x8*)(pvw + ((size_t)((ck * 4 + nt) * 64 + lane)) * 8);
                ak[nt] = __builtin_amdgcn_mfma_f32_16x16x32_bf16(afr, bk, ak[nt], 0, 0, 0);
                av[nt] = __builtin_amdgcn_mfma_f32_16x16x32_bf16(afr, bv, av[nt], 0, 0, 0);
            }
        }
        const size_t base = ((size_t)b * 4096) + y * 64 + row0;
#pragma unroll
        for (int nt = 0; nt < 4; ++nt) {
            const int ch = nt * 16 + m_;
#pragma unroll
            for (int reg = 0; reg < 4; ++reg) {
                const size_t o = (base + q * 4 + reg) * 64 + ch;
                kout[o] = ak[nt][reg];
                vout[o] = av[nt][reg];
            }
        }
    }
}

// ---------------- slot init (+ rowsum zero) ----------------
__global__ __launch_bounds__(256) void slot_init(
    const float* __restrict__ noise, const float* __restrict__ init_slots,
    float* __restrict__ slots, float* __restrict__ rowsum)
{
    int i = blockIdx.x * 256 + threadIdx.x;
    if (i < 224) rowsum[i] = 0.f;
    if (i < 224 * 64) {
        int z = i & 63;
        float spl = log1pf(expf(init_slots[64 + z]));
        slots[i] = init_slots[z] + spl * noise[i];
    }
}

// ---------------- attention pass 1 (q computed in-block) ----------------
__global__ __launch_bounds__(256) void attn_pass1(
    const float* __restrict__ kbuf, const float* __restrict__ slots,
    const float* __restrict__ lnsg, const float* __restrict__ lnsb,
    const float* __restrict__ qw,
    float* __restrict__ attn, float* __restrict__ rowsum)
{
    __shared__ float qs[7][64];
    __shared__ float red[7][4];
    const int b = blockIdx.x >> 4;
    const int jb = (blockIdx.x & 15) * 256;
    const int tid = threadIdx.x;
    const int lane = tid & 63, wv = tid >> 6;
    for (int i = wv; i < 7; i += 4) {
        float s = slots[(b * 7 + i) * 64 + lane];
        float m = wave_sum(s) * (1.f / 64.f);
        float d = s - m;
        float var = wave_sum(d * d) * (1.f / 64.f);
        float x = d * rsqrtf(var + 1e-5f) * lnsg[lane] + lnsb[lane];
        float qv = 0.f;
        for (int c = 0; c < 64; ++c) qv = fmaf(__shfl(x, c, 64), qw[c * 64 + lane], qv);
        qs[i][lane] = qv * SCALE_;
    }
    __syncthreads();
    const int j = jb + tid;
    float kr[64];
    const float* kp = kbuf + (((size_t)b * 4096) + j) * 64;
#pragma unroll
    for (int d4 = 0; d4 < 16; ++d4) {
        float4 kv = ((const float4*)kp)[d4];
        kr[d4 * 4 + 0] = kv.x; kr[d4 * 4 + 1] = kv.y;
        kr[d4 * 4 + 2] = kv.z; kr[d4 * 4 + 3] = kv.w;
    }
    float dots[7];
#pragma unroll
    for (int i = 0; i < 7; ++i) {
        float a = 0.f;
#pragma unroll
        for (int d = 0; d < 64; ++d) a = fmaf(kr[d], qs[i][d], a);
        dots[i] = a;
    }
    float mx = dots[0];
#pragma unroll
    for (int i = 1; i < 7; ++i) mx = fmaxf(mx, dots[i]);
    float sum = 0.f;
#pragma unroll
    for (int i = 0; i < 7; ++i) { dots[i] = expf(dots[i] - mx); sum += dots[i]; }
    const float inv = 1.f / sum;
#pragma unroll
    for (int i = 0; i < 7; ++i) {
        float a = dots[i] * inv + 1e-8f;
        dots[i] = a;
        attn[(((size_t)b * 7) + i) * 4096 + j] = a;
    }
#pragma unroll
    for (int i = 0; i < 7; ++i) {
        float s = wave_sum(dots[i]);
        if (lane == 0) red[i][wv] = s;
    }
    __syncthreads();
    if (tid < 7) {
        float s = red[tid][0] + red[tid][1] + red[tid][2] + red[tid][3];
        atomicAdd(&rowsum[b * 7 + tid], s);
    }
}

// ---------------- attention pass 2 ----------------
__global__ __launch_bounds__(256) void attn_pass2(
    const float* __restrict__ vbuf, const float* __restrict__ attn,
    float* __restrict__ part)
{
    const int b = blockIdx.x >> 4;
    const int js = blockIdx.x & 15;
    const int tid = threadIdx.x;
    const int d = tid & 63, jc = tid >> 6;
    float acc[7];
#pragma unroll
    for (int i = 0; i < 7; ++i) acc[i] = 0.f;
    const int j0 = js * 256;
    for (int j = j0 + jc; j < j0 + 256; j += 4) {
        float av = vbuf[(((size_t)b * 4096) + j) * 64 + d];
#pragma unroll
        for (int i = 0; i < 7; ++i)
            acc[i] = fmaf(attn[(((size_t)b * 7) + i) * 4096 + j], av, acc[i]);
    }
    __shared__ float red[4][7][64];
#pragma unroll
    for (int i = 0; i < 7; ++i) red[jc][i][d] = acc[i];
    __syncthreads();
    if (tid < 7 * 64) {
        int i = tid / 64, dd = tid % 64;
        float s = red[0][i][dd] + red[1][i][dd] + red[2][i][dd] + red[3][i][dd];
        part[((((size_t)b * 16) + js) * 7 + i) * 64 + dd] = s;
    }
}

// ---------------- GRU + residual MLP (+ rowsum re-zero for next iter) ----------------
__global__ __launch_bounds__(64) void gru_mlp(
    float* __restrict__ slots, const float* __restrict__ part,
    float* __restrict__ rowsum,
    const float* __restrict__ wih, const float* __restrict__ whh,
    const float* __restrict__ bih, const float* __restrict__ bhh,
    const float* __restrict__ lnfg, const float* __restrict__ lnfb,
    const float* __restrict__ m1w, const float* __restrict__ m1b,
    const float* __restrict__ m2w, const float* __restrict__ m2b)
{
    const int n = blockIdx.x;
    const int b = n / 7, i = n % 7;
    const int l = threadIdx.x;
    float upd = 0.f;
    for (int js = 0; js < 16; ++js)
        upd += part[((((size_t)b * 16) + js) * 7 + i) * 64 + l];
    upd /= rowsum[n];
    if (l == 0) rowsum[n] = 0.f;
    const float prev = slots[n * 64 + l];
    float gi0 = bih[l], gi1 = bih[64 + l], gi2 = bih[128 + l];
    float gh0 = bhh[l], gh1 = bhh[64 + l], gh2 = bhh[128 + l];
    for (int c = 0; c < 64; ++c) {
        float u = __shfl(upd, c, 64), p = __shfl(prev, c, 64);
        gi0 = fmaf(u, wih[l * 64 + c], gi0);
        gi1 = fmaf(u, wih[(64 + l) * 64 + c], gi1);
        gi2 = fmaf(u, wih[(128 + l) * 64 + c], gi2);
        gh0 = fmaf(p, whh[l * 64 + c], gh0);
        gh1 = fmaf(p, whh[(64 + l) * 64 + c], gh1);
        gh2 = fmaf(p, whh[(128 + l) * 64 + c], gh2);
    }
    float r  = 1.f / (1.f + expf(-(gi0 + gh0)));
    float zg = 1.f / (1.f + expf(-(gi1 + gh1)));
    float nn = tanhf(gi2 + r * gh2);
    float s = (1.f - zg) * nn + zg * prev;
    float m = wave_sum(s) * (1.f / 64.f);
    float d = s - m;
    float var = wave_sum(d * d) * (1.f / 64.f);
    float x = d * rsqrtf(var + 1e-5f) * lnfg[l] + lnfb[l];
    float h0 = m1b[l], h1 = m1b[64 + l];
    for (int c = 0; c < 64; ++c) {
        float xv = __shfl(x, c, 64);
        h0 = fmaf(xv, m1w[c * 128 + l], h0);
        h1 = fmaf(xv, m1w[c * 128 + 64 + l], h1);
    }
    h0 = fmaxf(h0, 0.f); h1 = fmaxf(h1, 0.f);
    float o = m2b[l];
    for (int c = 0; c < 64; ++c) {
        o = fmaf(__shfl(h0, c, 64), m2w[c * 64 + l], o);
        o = fmaf(__shfl(h1, c, 64), m2w[(64 + c) * 64 + l], o);
    }
    slots[n * 64 + l] = s + o;
}

// ---------------- finalize (dc4out NHWC fp32 [img][p][4]) ----------------
__global__ __launch_bounds__(256) void finalize_k(
    const float* __restrict__ dc4out, const float* __restrict__ inputs,
    float* __restrict__ out)
{
    const int tid = threadIdx.x;
    const int gp = blockIdx.x * 256 + tid;
    const int b = gp >> 12, p = gp & 4095;
    float4 o4[7];
#pragma unroll
    for (int k = 0; k < 7; ++k)
        o4[k] = ((const float4*)dc4out)[(size_t)(b * 7 + k) * 4096 + p];
    float mx = o4[0].w;
#pragma unroll
    for (int k = 1; k < 7; ++k) mx = fmaxf(mx, o4[k].w);
    float s = 0.f;
#pragma unroll
    for (int k = 0; k < 7; ++k) s += expf(o4[k].w - mx);
    const float lse = mx + logf(s);
    float recon0 = 0.f, recon1 = 0.f, recon2 = 0.f;
    float* xl = out + 1;
    float* ml = out + 2752513;
#pragma unroll
    for (int k = 0; k < 7; ++k) {
        float lp = o4[k].w - lse;
        ml[((size_t)(b * 7 + k)) * 4096 + p] = lp;
        float w = expf(lp);
        float x0 = 1.f / (1.f + expf(-o4[k].x));
        float x1 = 1.f / (1.f + expf(-o4[k].y));
        float x2 = 1.f / (1.f + expf(-o4[k].z));
        xl[(((size_t)(b * 7 + k)) * 3 + 0) * 4096 + p] = x0;
        xl[(((size_t)(b * 7 + k)) * 3 + 1) * 4096 + p] = x1;
        xl[(((size_t)(b * 7 + k)) * 3 + 2) * 4096 + p] = x2;
        recon0 = fmaf(x0, w, recon0);
        recon1 = fmaf(x1, w, recon1);
        recon2 = fmaf(x2, w, recon2);
    }
    float err = 0.f;
    {
        float xo = (inputs[((size_t)b * 3 + 0) * 4096 + p] + 1.f) * 0.5f;
        float dd = xo - recon0; err += dd * dd;
        xo = (inputs[((size_t)b * 3 + 1) * 4096 + p] + 1.f) * 0.5f;
        dd = xo - recon1; err += dd * dd;
        xo = (inputs[((size_t)b * 3 + 2) * 4096 + p] + 1.f) * 0.5f;
        dd = xo - recon2; err += dd * dd;
    }
    float wsum = wave_sum(err);
    __shared__ float red[4];
    const int lane = tid & 63, wv = tid >> 6;
    if (lane == 0) red[wv] = wsum;
    __syncthreads();
    if (tid == 0) atomicAdd(out, (red[0] + red[1] + red[2] + red[3]) * (1.f / 32.f));
}

// ---------------- copy slots to out (+ zero mse slot; runs BEFORE finalize) ----------------
__global__ __launch_bounds__(256) void copy_slots(const float* __restrict__ slots,
                                                  float* __restrict__ out)
{
    int i = blockIdx.x * 256 + threadIdx.x;
    if (i == 0) out[0] = 0.f;
    if (i < 14336) out[3670017 + i] = slots[i];
}

// ---------------- launch ----------------
extern "C" void kernel_launch(void* const* d_in, const int* in_sizes, int n_in,
                              void* d_out, int out_size, void* d_ws, size_t ws_size,
                              hipStream_t stream) {
    (void)in_sizes; (void)n_in; (void)out_size; (void)ws_size;
    const float* inputs = (const float*)d_in[0];
    const float* noise  = (const float*)d_in[1];
    const float* epw  = (const float*)d_in[2];
    const float* epb  = (const float*)d_in[3];
    const float* ec1w = (const float*)d_in[4];
    const float* ec1b = (const float*)d_in[5];
    const float* ec2w = (const float*)d_in[6];
    const float* ec2b = (const float*)d_in[7];
    const float* ec3w = (const float*)d_in[8];
    const float* ec3b = (const float*)d_in[9];
    const float* ec4w = (const float*)d_in[10];
    const float* ec4b = (const float*)d_in[11];
    const float* ln1g = (const float*)d_in[12];
    const float* ln1b = (const float*)d_in[13];
    const float* fc1w = (const float*)d_in[14];
    const float* fc1b = (const float*)d_in[15];
    const float* fc2w = (const float*)d_in[16];
    const float* fc2b = (const float*)d_in[17];
    const float* lnsg = (const float*)d_in[18];
    const float* lnsb = (const float*)d_in[19];
    const float* lnfg = (const float*)d_in[20];
    const float* lnfb = (const float*)d_in[21];
    const float* qw   = (const float*)d_in[22];
    const float* kw   = (const float*)d_in[23];
    const float* vw   = (const float*)d_in[24];
    const float* m1w  = (const float*)d_in[25];
    const float* m1b  = (const float*)d_in[26];
    const float* m2w  = (const float*)d_in[27];
    const float* m2b  = (const float*)d_in[28];
    const float* wih  = (const float*)d_in[29];
    const float* whh  = (const float*)d_in[30];
    const float* bih  = (const float*)d_in[31];
    const float* bhh  = (const float*)d_in[32];
    const float* init_slots = (const float*)d_in[33];
    const float* dpw  = (const float*)d_in[34];
    const float* dpb  = (const float*)d_in[35];
    const float* dc1w = (const float*)d_in[36];
    const float* dc1b = (const float*)d_in[37];
    const float* dc2w = (const float*)d_in[38];
    const float* dc2b = (const float*)d_in[39];
    const float* dc3w = (const float*)d_in[40];
    const float* dc3b = (const float*)d_in[41];
    const float* dc4w = (const float*)d_in[42];
    const float* dc4b = (const float*)d_in[43];

    float* ws = (float*)d_ws;
    unsigned short* B0 = (unsigned short*)(ws + WS_B0);
    unsigned short* B1 = (unsigned short*)(ws + WS_B1);
    float* K = ws + WS_K;
    float* V = ws + WS_V;
    // decode-phase overlays
    unsigned short* dping = (unsigned short*)(ws + WS_B0);   // 33.5 MB (spans B0+B1)
    unsigned short* dpong = (unsigned short*)(ws + WS_K);    // 33.5 MB (over dead K)
    float* dc4out = V;                                       // 14.7 MB (over dead V)
    unsigned short* PK = (unsigned short*)(ws + WS_V + 4194304u);
    unsigned short* p_ec2 = PK, *p_ec3 = PK + 102400, *p_ec4 = PK + 204800;
    unsigned short* p_dc1 = PK, *p_dc2 = PK + 51200, *p_dc3 = PK + 76800, *p_dc4 = PK + 102400;
    float* attn  = ws + WS_ATTN;
    unsigned short* PFC = (unsigned short*)attn;             // live only until encoder_tail done
    unsigned short* p_fc1 = PFC, *p_fc2 = PFC + 4096, *p_kw = PFC + 8192, *p_vw = PFC + 12288;
    // decode overlays in attn region
    unsigned short* peb = (unsigned short*)(attn + OFF_PEB); // [70][70][64] bf16
    float* wclsb = attn + OFF_WCLS;                          // [9][32][64]
    float* Sbuf  = attn + OFF_S;                             // [224][9][32]
    float* zbias = attn + OFF_ZB;                            // [32]
    float* part  = ws + WS_PART;
    float* P     = ws + WS_PART;                             // decode: conv(pe) fp32 [68][68][32]
    float* slots = ws + WS_SLOT;
    float* rowsum = ws + WS_ROW;
    float* out = (float*)d_out;

    // ---- pack encoder weights ----
    pack_weights<<<50, 256, 0, stream>>>(ec2w, p_ec2, 64, 64, 5, 4, 12800);
    pack_weights<<<50, 256, 0, stream>>>(ec3w, p_ec3, 64, 64, 5, 4, 12800);
    pack_weights<<<50, 256, 0, stream>>>(ec4w, p_ec4, 64, 64, 5, 4, 12800);
    pack_fc<<<2, 256, 0, stream>>>(fc1w, p_fc1);
    pack_fc<<<2, 256, 0, stream>>>(fc2w, p_fc2);
    pack_fc<<<2, 256, 0, stream>>>(kw, p_kw);
    pack_fc<<<2, 256, 0, stream>>>(vw, p_vw);

    // ---- encoder ----
    conv_ec1<<<2048, 256, 0, stream>>>(inputs, ec1w, ec1b, B0);
    conv_mfma<64, 64, 5, 2, 64, 1, 0><<<512, 256, 0, stream>>>(B0, p_ec2, ec2b, B1, 64, 64, 64, 64, 4, 4);
    conv_mfma<64, 64, 5, 2, 64, 1, 0><<<512, 256, 0, stream>>>(B1, p_ec3, ec3b, B0, 64, 64, 64, 64, 4, 4);
    conv_mfma<64, 64, 5, 2, 64, 1, 0><<<512, 256, 0, stream>>>(B0, p_ec4, ec4b, B1, 64, 64, 64, 64, 4, 4);
    encoder_tail_mfma<<<2048, 256, 0, stream>>>(B1, epw, epb, ln1g, ln1b,
                                                p_fc1, fc1b, p_fc2, fc2b, p_kw, p_vw, K, V);
    slot_init<<<56, 256, 0, stream>>>(noise, init_slots, slots, rowsum);

    // ---- 3 slot-attention iterations ----
    for (int it = 0; it < 3; ++it) {
        attn_pass1<<<512, 256, 0, stream>>>(K, slots, lnsg, lnsb, qw, attn, rowsum);
        attn_pass2<<<512, 256, 0, stream>>>(V, attn, part);
        gru_mlp<<<224, 64, 0, stream>>>(slots, part, rowsum, wih, whh, bih, bhh,
                                        lnfg, lnfb, m1w, m1b, m2w, m2b);
    }

    // ---- pack decoder weights + dc1 linearization precomputes ----
    pack_weights<<<25, 256, 0, stream>>>(dc1w, p_dc1, 64, 32, 5, 2, 6400);
    pack_weights<<<13, 256, 0, stream>>>(dc2w, p_dc2, 32, 32, 5, 2, 3200);
    pack_weights<<<13, 256, 0, stream>>>(dc3w, p_dc3, 32, 32, 5, 2, 3200);
    pack_weights<<<3, 256, 0, stream>>>(dc4w, p_dc4, 32, 4, 3, 1, 576);
    pe_synth<<<20, 256, 0, stream>>>(dpw, dpb, peb, zbias);
    conv_mfma<64, 32, 5, 1, 32, 0, 1><<<25, 256, 0, stream>>>(peb, p_dc1, zbias, P, 70, 70, 68, 68, 5, 5);
    wcls_build<<<72, 256, 0, stream>>>(dc1w, wclsb);
    slot_s<<<252, 256, 0, stream>>>(slots, wclsb, Sbuf);

    // ---- decoder, 2 chunks of 112 images ----
    for (int ch = 0; ch < 2; ++ch) {
        float* d4o = dc4out + (size_t)ch * 112 * 4 * 4096;
        dc1_assemble<<<2023, 256, 0, stream>>>(P, Sbuf, dc1b, ch * 112, dping);
        conv_mfma<32, 32, 5, 1, 32, 1, 0><<<2800, 256, 0, stream>>>(dping, p_dc2, dc2b, dpong, 68, 68, 66, 66, 5, 5);
        conv_mfma<32, 32, 5, 1, 32, 1, 0><<<1792, 256, 0, stream>>>(dpong, p_dc3, dc3b, dping, 66, 66, 64, 64, 4, 4);
        conv_mfma<32, 16, 3, 1, 4, 0, 1><<<1792, 256, 0, stream>>>(dping, p_dc4, dc4b, d4o, 64, 64, 64, 64, 4, 4);
    }

    // ---- outputs ----
    copy_slots<<<56, 256, 0, stream>>>(slots, out);
    finalize_k<<<512, 256, 0, stream>>>(dc4out, inputs, out);
}

// Round 6
// 763.274 us; speedup vs baseline: 12.7387x; 1.1018x over previous
//
#include <hip/hip_runtime.h>
#include <math.h>

typedef short bf16x8 __attribute__((ext_vector_type(8)));
typedef float f32x4 __attribute__((ext_vector_type(4)));

// workspace layout (float offsets)
#define WS_B0   0u           // encode: B0 (bf16 ping). decode: dec ping (33.5MB spans B0+B1)
#define WS_B1   4194304u     // encode: B1 (bf16 pong)
#define WS_K    8388608u     // encode/attn: k bf16. decode: dec pong (bf16)
#define WS_V    16777216u    // encode/attn: v bf16. decode: dc4out fp32 @+0, packed wts @+4194304
#define WS_ATTN 25165824u    // attn (917504). decode: peb/Wcls/S/zbias overlays
#define WS_PART 26083328u    // attn partials (229376). decode: P = conv(pe) fp32 [68][68][32]
#define WS_SLOT 26327040u    // 14336
#define WS_ROW  26341376u    // 224
#define SCALE_ 0.125f

// decode-phase overlays inside attn region (float offsets from attn base)
#define OFF_PEB   0u
#define OFF_WCLS  160000u
#define OFF_S     180000u
#define OFF_ZB    250000u

__device__ __forceinline__ float wave_sum(float v) {
#pragma unroll
    for (int m = 32; m >= 1; m >>= 1) v += __shfl_xor(v, m, 64);
    return v;
}
__device__ __forceinline__ unsigned short f2bf(float f) {
    unsigned u = __float_as_uint(f);
    u = u + 0x7fffu + ((u >> 16) & 1u);
    return (unsigned short)(u >> 16);
}
__device__ __forceinline__ float bf2f(unsigned short h) {
    return __uint_as_float(((unsigned)h) << 16);
}

// ---------------- weight packing into B-fragment order (conv) ----------------
__global__ __launch_bounds__(256) void pack_weights(
    const float* __restrict__ w, unsigned short* __restrict__ wp,
    int CIN, int COUT_STORE, int KS, int NT, int total)
{
    int t = blockIdx.x * 256 + threadIdx.x;
    if (t >= total) return;
    int lane = t & 63;
    int nt = (t >> 6) % NT;
    int ch = t / (64 * NT);
    int CPT = CIN / 32;
    int cic = ch % CPT;
    int tap = ch / CPT;
    int ky = tap / KS, kx = tap % KS;
    int co = nt * 16 + (lane & 15);
    int k0 = cic * 32 + (lane >> 4) * 8;
    unsigned short v[8];
#pragma unroll
    for (int j = 0; j < 8; ++j) {
        int ci = k0 + j;
        float f = (co < COUT_STORE) ? w[((size_t)(co * CIN + ci) * KS + ky) * KS + kx] : 0.f;
        v[j] = f2bf(f);
    }
    *(uint4*)(wp + (size_t)t * 8) = *(uint4*)v;
}

// ---------------- fc weight packing ----------------
__global__ __launch_bounds__(256) void pack_fc(
    const float* __restrict__ w, unsigned short* __restrict__ wp)
{
    int t = blockIdx.x * 256 + threadIdx.x;
    if (t >= 512) return;
    int lane = t & 63;
    int nt = (t >> 6) & 3;
    int ck = t >> 8;
    int n = nt * 16 + (lane & 15);
    int k0 = ck * 32 + (lane >> 4) * 8;
    unsigned short v[8];
#pragma unroll
    for (int j = 0; j < 8; ++j) v[j] = f2bf(w[(size_t)(k0 + j) * 64 + n]);
    *(uint4*)(wp + (size_t)t * 8) = *(uint4*)v;
}

// ---------------- MFMA implicit-GEMM conv, input-row-major K loop ----------------
// For each (cic,kx): hoist B[ky][nt] into regs, sweep input rows ir=0..KS+2,
// one A-read per row serves all valid (mt=ir-ky, ky) pairs (2.5x fewer LDS reads).
template<int CIN, int COUT, int KS, int PAD, int NSTORE, int RELU, int OUTF32>
__global__ __launch_bounds__(256) void conv_mfma(
    const unsigned short* __restrict__ in, const unsigned short* __restrict__ wpack,
    const float* __restrict__ bias, void* __restrict__ outv,
    int Hin, int Win, int Hout, int Wout, int tilesX, int tilesY)
{
    constexpr int TS = 16, TH = TS + KS - 1;
    constexpr int NT = COUT / 16;
    constexpr int CPT = CIN / 32;
    constexpr int G8 = CIN / 8;
    __shared__ __align__(16) unsigned short tile[TH][TH][CIN];
    const int tpb = tilesX * tilesY;
    const int n = blockIdx.x / tpb;
    const int t = blockIdx.x % tpb;
    const int ty0 = (t / tilesX) * TS, tx0 = (t % tilesX) * TS;
    const int tid = threadIdx.x;

    const unsigned short* inb = in + (size_t)n * Hin * Win * CIN;
    for (int idx = tid; idx < TH * TH * G8; idx += 256) {
        int g = idx % G8;
        int c = (idx / G8) % TH;
        int r = idx / (G8 * TH);
        int iy = ty0 - PAD + r, ix = tx0 - PAD + c;
        uint4 vv = make_uint4(0, 0, 0, 0);
        if (iy >= 0 && iy < Hin && ix >= 0 && ix < Win)
            vv = *(const uint4*)(inb + ((size_t)iy * Win + ix) * CIN + g * 8);
        int slot = (g * 8 + c * 8) % CIN;
        *(uint4*)&tile[r][c][slot] = vv;
    }
    __syncthreads();

    const int wv = tid >> 6, lane = tid & 63;
    const int q = lane >> 4, m = lane & 15;
    const int row0 = wv * 4;
    f32x4 acc[4][NT];
#pragma unroll
    for (int mt = 0; mt < 4; ++mt)
#pragma unroll
        for (int nt = 0; nt < NT; ++nt) acc[mt][nt] = (f32x4){0.f, 0.f, 0.f, 0.f};

#pragma unroll
    for (int cic = 0; cic < CPT; ++cic) {
#pragma unroll
        for (int kx = 0; kx < KS; ++kx) {
            bf16x8 B[KS][NT];
#pragma unroll
            for (int ky = 0; ky < KS; ++ky)
#pragma unroll
                for (int nt = 0; nt < NT; ++nt)
                    B[ky][nt] = *(const bf16x8*)(wpack +
                        ((size_t)(((ky * KS + kx) * CPT + cic) * NT + nt) * 64 + lane) * 8);
            const int cbase = m + kx;
            const int slot = (cic * 32 + q * 8 + cbase * 8) % CIN;
#pragma unroll
            for (int ir = 0; ir < KS + 3; ++ir) {
                bf16x8 afr = *(const bf16x8*)&tile[row0 + ir][cbase][slot];
#pragma unroll
                for (int ky = 0; ky < KS; ++ky) {
                    const int mt = ir - ky;
                    if (mt < 0 || mt > 3) continue;
#pragma unroll
                    for (int nt = 0; nt < NT; ++nt)
                        acc[mt][nt] = __builtin_amdgcn_mfma_f32_16x16x32_bf16(afr, B[ky][nt], acc[mt][nt], 0, 0, 0);
                }
            }
        }
    }

#pragma unroll
    for (int nt = 0; nt < NT; ++nt) {
        const int co = nt * 16 + m;
        const float bv = (co < NSTORE) ? bias[co] : 0.f;
#pragma unroll
        for (int mt = 0; mt < 4; ++mt) {
            const int oy = ty0 + wv * 4 + mt;
#pragma unroll
            for (int j = 0; j < 4; ++j) {
                const int ox = tx0 + q * 4 + j;
                if (oy < Hout && ox < Wout && co < NSTORE) {
                    float v = acc[mt][nt][j] + bv;
                    if (RELU) v = fmaxf(v, 0.f);
                    size_t o = (((size_t)n * Hout + oy) * Wout + ox) * NSTORE + co;
                    if (OUTF32) ((float*)outv)[o] = v;
                    else ((unsigned short*)outv)[o] = f2bf(v);
                }
            }
        }
    }
}

// ---------------- pe field synth ----------------
__global__ __launch_bounds__(256) void pe_synth(
    const float* __restrict__ dpw, const float* __restrict__ dpb,
    unsigned short* __restrict__ peb, float* __restrict__ zbias)
{
    const int tid = threadIdx.x;
    if (blockIdx.x == 0 && tid < 32) zbias[tid] = 0.f;
    const int pix = blockIdx.x * 256 + tid;
    if (pix >= 4900) return;
    const int iy = pix / 70, ix = pix % 70;
    const float fy = iy * (1.f / 69.f), fx = ix * (1.f / 69.f);
    unsigned short v[64];
#pragma unroll
    for (int ci = 0; ci < 64; ++ci) {
        float p = (1.f - fy) * dpw[ci] + fy * dpw[64 + ci]
                + fx * dpw[128 + ci] + (1.f - fx) * dpw[192 + ci] + dpb[ci];
        v[ci] = f2bf(p);
    }
    uint4* ob = (uint4*)(peb + (size_t)pix * 64);
#pragma unroll
    for (int i = 0; i < 8; ++i) ob[i] = ((uint4*)v)[i];
}

// ---------------- Wcls[9][32][64] ----------------
__global__ __launch_bounds__(256) void wcls_build(
    const float* __restrict__ w, float* __restrict__ wcls)
{
    int idx = blockIdx.x * 256 + threadIdx.x;
    if (idx >= 9 * 32 * 64) return;
    int cls = idx / (32 * 64);
    int co = (idx / 64) % 32;
    int ci = idx % 64;
    int rc = cls / 3, cc = cls % 3;
    int ky0 = (rc == 0) ? 1 : 0, ky1 = (rc == 2) ? 3 : 4;
    int kx0 = (cc == 0) ? 1 : 0, kx1 = (cc == 2) ? 3 : 4;
    float s = 0.f;
    const float* wb = w + (size_t)(co * 64 + ci) * 25;
    for (int ky = ky0; ky <= ky1; ++ky)
        for (int kx = kx0; kx <= kx1; ++kx)
            s += wb[ky * 5 + kx];
    wcls[idx] = s;
}

// ---------------- S[224][9][32] = slots @ Wcls^T ----------------
__global__ __launch_bounds__(256) void slot_s(
    const float* __restrict__ slots, const float* __restrict__ wcls,
    float* __restrict__ S)
{
    int idx = blockIdx.x * 256 + threadIdx.x;
    if (idx >= 224 * 9 * 32) return;
    int n = idx / (9 * 32);
    int cls = (idx / 32) % 9;
    int co = idx % 32;
    const float* sl = slots + n * 64;
    const float* wc = wcls + (size_t)(cls * 32 + co) * 64;
    float s = 0.f;
#pragma unroll
    for (int ci = 0; ci < 64; ++ci) s = fmaf(sl[ci], wc[ci], s);
    S[idx] = s;
}

// ---------------- dc1 assemble ----------------
__global__ __launch_bounds__(256) void dc1_assemble(
    const float* __restrict__ P, const float* __restrict__ S,
    const float* __restrict__ bias, int n0,
    unsigned short* __restrict__ out)
{
    const int gid = blockIdx.x * 256 + threadIdx.x;
    const int nl = gid / 4624;
    const int pix = gid % 4624;
    const int oy = pix / 68, ox = pix % 68;
    const int rc = (oy == 0) ? 0 : ((oy == 67) ? 2 : 1);
    const int cc = (ox == 0) ? 0 : ((ox == 67) ? 2 : 1);
    const float* Sp = S + ((size_t)(n0 + nl) * 9 + (rc * 3 + cc)) * 32;
    const float* Pp = P + (size_t)pix * 32;
    unsigned short v[32];
#pragma unroll
    for (int co = 0; co < 32; ++co)
        v[co] = f2bf(fmaxf(bias[co] + Pp[co] + Sp[co], 0.f));
    uint4* ob = (uint4*)(out + ((size_t)nl * 4624 + pix) * 32);
#pragma unroll
    for (int i = 0; i < 4; ++i) ob[i] = ((uint4*)v)[i];
}

// ---------------- encoder conv1 ----------------
__global__ __launch_bounds__(256) void conv_ec1(
    const float* __restrict__ in, const float* __restrict__ wts,
    const float* __restrict__ bias, unsigned short* __restrict__ out)
{
    __shared__ float tile[3][20][21];
    const int blk = blockIdx.x;
    const int n = blk >> 6;
    const int sub = blk & 63;
    const int t = sub >> 2;
    const int cog = sub & 3;
    const int ty0 = (t >> 2) * 16, tx0 = (t & 3) * 16;
    const int tid = threadIdx.x;
    for (int idx = tid; idx < 1200; idx += 256) {
        int ci = idx / 400, rc = idx % 400;
        int r = rc / 20, c = rc % 20;
        int gy = ty0 + r - 2, gx = tx0 + c - 2;
        float v = 0.f;
        if (gy >= 0 && gy < 64 && gx >= 0 && gx < 64)
            v = in[((size_t)n * 3 + ci) * 4096 + gy * 64 + gx];
        tile[ci][r][c] = v;
    }
    __syncthreads();
    const int lx = tid & 15, ly = tid >> 4;
    float acc[16];
#pragma unroll
    for (int co = 0; co < 16; ++co) acc[co] = bias[cog * 16 + co];
    for (int ci = 0; ci < 3; ++ci) {
        float val[25];
#pragma unroll
        for (int ky = 0; ky < 5; ++ky)
#pragma unroll
            for (int kx = 0; kx < 5; ++kx) val[ky * 5 + kx] = tile[ci][ly + ky][lx + kx];
#pragma unroll
        for (int co = 0; co < 16; ++co) {
            const float* wc = wts + (size_t)((cog * 16 + co) * 3 + ci) * 25;
            float a = acc[co];
#pragma unroll
            for (int tt = 0; tt < 25; ++tt) a = fmaf(val[tt], wc[tt], a);
            acc[co] = a;
        }
    }
    unsigned short tmp[16];
#pragma unroll
    for (int co = 0; co < 16; ++co) tmp[co] = f2bf(fmaxf(acc[co], 0.f));
    uint4* ob = (uint4*)(out + (((size_t)n * 64 + ty0 + ly) * 64 + tx0 + lx) * 64 + cog * 16);
    ob[0] = ((uint4*)tmp)[0];
    ob[1] = ((uint4*)tmp)[1];
}

// ---------------- encoder tail, MFMA (k/v out in bf16) ----------------
__global__ __launch_bounds__(256) void encoder_tail_mfma(
    const unsigned short* __restrict__ h4,
    const float* __restrict__ epw, const float* __restrict__ epb,
    const float* __restrict__ ln1g, const float* __restrict__ ln1b,
    const unsigned short* __restrict__ pfc1, const float* __restrict__ fc1b,
    const unsigned short* __restrict__ pfc2, const float* __restrict__ fc2b,
    const unsigned short* __restrict__ pkw, const unsigned short* __restrict__ pvw,
    unsigned short* __restrict__ kout, unsigned short* __restrict__ vout)
{
    __shared__ __align__(16) unsigned short X[64][72];
    const int b = blockIdx.x >> 6;
    const int y = blockIdx.x & 63;
    const int tid = threadIdx.x;

    {
        const int p = tid >> 2, sub = tid & 3;
        const unsigned short* hp = h4 + ((((size_t)b * 64 + y) * 64 + p) * 64) + sub * 16;
        unsigned short raw[16];
        *(uint4*)(raw)     = *(const uint4*)hp;
        *(uint4*)(raw + 8) = *(const uint4*)(hp + 8);
        const float fy = y * (1.f / 63.f), fx = p * (1.f / 63.f);
        float f[16];
        float s1 = 0.f, s2 = 0.f;
#pragma unroll
        for (int j = 0; j < 16; ++j) {
            int ch = sub * 16 + j;
            float pe = (1.f - fy) * epw[ch] + fy * epw[64 + ch]
                     + fx * epw[128 + ch] + (1.f - fx) * epw[192 + ch] + epb[ch];
            float v = bf2f(raw[j]) + pe;
            f[j] = v;
            s1 += v;
            s2 += v * v;
        }
        s1 += __shfl_xor(s1, 1, 64); s1 += __shfl_xor(s1, 2, 64);
        s2 += __shfl_xor(s2, 1, 64); s2 += __shfl_xor(s2, 2, 64);
        const float m = s1 * (1.f / 64.f);
        const float var = s2 * (1.f / 64.f) - m * m;
        const float inv = rsqrtf(var + 1e-5f);
        unsigned short xb[16];
#pragma unroll
        for (int j = 0; j < 16; ++j) {
            int ch = sub * 16 + j;
            xb[j] = f2bf((f[j] - m) * inv * ln1g[ch] + ln1b[ch]);
        }
        *(uint4*)&X[p][sub * 16]     = ((uint4*)xb)[0];
        *(uint4*)&X[p][sub * 16 + 8] = ((uint4*)xb)[1];
    }
    __syncthreads();

    const int w = tid >> 6, lane = tid & 63;
    const int q = lane >> 4, m_ = lane & 15;
    const int row0 = w * 16;

    {
        f32x4 a1[4];
#pragma unroll
        for (int nt = 0; nt < 4; ++nt) a1[nt] = (f32x4){0.f, 0.f, 0.f, 0.f};
#pragma unroll
        for (int ck = 0; ck < 2; ++ck) {
            bf16x8 afr = *(const bf16x8*)&X[row0 + m_][ck * 32 + q * 8];
#pragma unroll
            for (int nt = 0; nt < 4; ++nt) {
                bf16x8 bfr = *(const bf16x8*)(pfc1 + ((size_t)((ck * 4 + nt) * 64 + lane)) * 8);
                a1[nt] = __builtin_amdgcn_mfma_f32_16x16x32_bf16(afr, bfr, a1[nt], 0, 0, 0);
            }
        }
        __syncthreads();
#pragma unroll
        for (int nt = 0; nt < 4; ++nt) {
            const float bb = fc1b[nt * 16 + m_];
#pragma unroll
            for (int reg = 0; reg < 4; ++reg)
                X[row0 + q * 4 + reg][nt * 16 + m_] = f2bf(fmaxf(a1[nt][reg] + bb, 0.f));
        }
    }
    __syncthreads();

    {
        f32x4 a2[4];
#pragma unroll
        for (int nt = 0; nt < 4; ++nt) a2[nt] = (f32x4){0.f, 0.f, 0.f, 0.f};
#pragma unroll
        for (int ck = 0; ck < 2; ++ck) {
            bf16x8 afr = *(const bf16x8*)&X[row0 + m_][ck * 32 + q * 8];
#pragma unroll
            for (int nt = 0; nt < 4; ++nt) {
                bf16x8 bfr = *(const bf16x8*)(pfc2 + ((size_t)((ck * 4 + nt) * 64 + lane)) * 8);
                a2[nt] = __builtin_amdgcn_mfma_f32_16x16x32_bf16(afr, bfr, a2[nt], 0, 0, 0);
            }
        }
        __syncthreads();
#pragma unroll
        for (int nt = 0; nt < 4; ++nt) {
            const float bb = fc2b[nt * 16 + m_];
#pragma unroll
            for (int reg = 0; reg < 4; ++reg)
                X[row0 + q * 4 + reg][nt * 16 + m_] = f2bf(a2[nt][reg] + bb);
        }
    }
    __syncthreads();

    {
        f32x4 ak[4], av[4];
#pragma unroll
        for (int nt = 0; nt < 4; ++nt) {
            ak[nt] = (f32x4){0.f, 0.f, 0.f, 0.f};
            av[nt] = (f32x4){0.f, 0.f, 0.f, 0.f};
        }
#pragma unroll
        for (int ck = 0; ck < 2; ++ck) {
            bf16x8 afr = *(const bf16x8*)&X[row0 + m_][ck * 32 + q * 8];
#pragma unroll
            for (int nt = 0; nt < 4; ++nt) {
                bf16x8 bk = *(const bf16x8*)(pkw + ((size_t)((ck * 4 + nt) * 64 + lane)) * 8);
                bf16x8 bv = *(const bf16x8*)(pvw + ((size_t)((ck * 4 + nt) * 64 + lane)) * 8);
                ak[nt] = __builtin_amdgcn_mfma_f32_16x16x32_bf16(afr, bk, ak[nt], 0, 0, 0);
                av[nt] = __builtin_amdgcn_mfma_f32_16x16x32_bf16(afr, bv, av[nt], 0, 0, 0);
            }
        }
        const size_t base = ((size_t)b * 4096) + y * 64 + row0;
#pragma unroll
        for (int nt = 0; nt < 4; ++nt) {
            const int ch = nt * 16 + m_;
#pragma unroll
            for (int reg = 0; reg < 4; ++reg) {
                const size_t o = (base + q * 4 + reg) * 64 + ch;
                kout[o] = f2bf(ak[nt][reg]);
                vout[o] = f2bf(av[nt][reg]);
            }
        }
    }
}

// ---------------- slot init (+ rowsum zero) ----------------
__global__ __launch_bounds__(256) void slot_init(
    const float* __restrict__ noise, const float* __restrict__ init_slots,
    float* __restrict__ slots, float* __restrict__ rowsum)
{
    int i = blockIdx.x * 256 + threadIdx.x;
    if (i < 224) rowsum[i] = 0.f;
    if (i < 224 * 64) {
        int z = i & 63;
        float spl = log1pf(expf(init_slots[64 + z]));
        slots[i] = init_slots[z] + spl * noise[i];
    }
}

// ---------------- attention pass 1 (k in bf16) ----------------
__global__ __launch_bounds__(256) void attn_pass1(
    const unsigned short* __restrict__ kbuf, const float* __restrict__ slots,
    const float* __restrict__ lnsg, const float* __restrict__ lnsb,
    const float* __restrict__ qw,
    float* __restrict__ attn, float* __restrict__ rowsum)
{
    __shared__ float qs[7][64];
    __shared__ float red[7][4];
    const int b = blockIdx.x >> 4;
    const int jb = (blockIdx.x & 15) * 256;
    const int tid = threadIdx.x;
    const int lane = tid & 63, wv = tid >> 6;
    for (int i = wv; i < 7; i += 4) {
        float s = slots[(b * 7 + i) * 64 + lane];
        float m = wave_sum(s) * (1.f / 64.f);
        float d = s - m;
        float var = wave_sum(d * d) * (1.f / 64.f);
        float x = d * rsqrtf(var + 1e-5f) * lnsg[lane] + lnsb[lane];
        float qv = 0.f;
        for (int c = 0; c < 64; ++c) qv = fmaf(__shfl(x, c, 64), qw[c * 64 + lane], qv);
        qs[i][lane] = qv * SCALE_;
    }
    __syncthreads();
    const int j = jb + tid;
    float kr[64];
    const unsigned short* kp = kbuf + (((size_t)b * 4096) + j) * 64;
#pragma unroll
    for (int d8 = 0; d8 < 8; ++d8) {
        uint4 kv = ((const uint4*)kp)[d8];
        const unsigned short* h = (const unsigned short*)&kv;
#pragma unroll
        for (int z = 0; z < 8; ++z) kr[d8 * 8 + z] = bf2f(h[z]);
    }
    float dots[7];
#pragma unroll
    for (int i = 0; i < 7; ++i) {
        float a = 0.f;
#pragma unroll
        for (int d = 0; d < 64; ++d) a = fmaf(kr[d], qs[i][d], a);
        dots[i] = a;
    }
    float mx = dots[0];
#pragma unroll
    for (int i = 1; i < 7; ++i) mx = fmaxf(mx, dots[i]);
    float sum = 0.f;
#pragma unroll
    for (int i = 0; i < 7; ++i) { dots[i] = expf(dots[i] - mx); sum += dots[i]; }
    const float inv = 1.f / sum;
#pragma unroll
    for (int i = 0; i < 7; ++i) {
        float a = dots[i] * inv + 1e-8f;
        dots[i] = a;
        attn[(((size_t)b * 7) + i) * 4096 + j] = a;
    }
#pragma unroll
    for (int i = 0; i < 7; ++i) {
        float s = wave_sum(dots[i]);
        if (lane == 0) red[i][wv] = s;
    }
    __syncthreads();
    if (tid < 7) {
        float s = red[tid][0] + red[tid][1] + red[tid][2] + red[tid][3];
        atomicAdd(&rowsum[b * 7 + tid], s);
    }
}

// ---------------- attention pass 2 (v in bf16) ----------------
__global__ __launch_bounds__(256) void attn_pass2(
    const unsigned short* __restrict__ vbuf, const float* __restrict__ attn,
    float* __restrict__ part)
{
    const int b = blockIdx.x >> 4;
    const int js = blockIdx.x & 15;
    const int tid = threadIdx.x;
    const int d = tid & 63, jc = tid >> 6;
    float acc[7];
#pragma unroll
    for (int i = 0; i < 7; ++i) acc[i] = 0.f;
    const int j0 = js * 256;
    for (int j = j0 + jc; j < j0 + 256; j += 4) {
        float av = bf2f(vbuf[(((size_t)b * 4096) + j) * 64 + d]);
#pragma unroll
        for (int i = 0; i < 7; ++i)
            acc[i] = fmaf(attn[(((size_t)b * 7) + i) * 4096 + j], av, acc[i]);
    }
    __shared__ float red[4][7][64];
#pragma unroll
    for (int i = 0; i < 7; ++i) red[jc][i][d] = acc[i];
    __syncthreads();
    if (tid < 7 * 64) {
        int i = tid / 64, dd = tid % 64;
        float s = red[0][i][dd] + red[1][i][dd] + red[2][i][dd] + red[3][i][dd];
        part[((((size_t)b * 16) + js) * 7 + i) * 64 + dd] = s;
    }
}

// ---------------- GRU + residual MLP ----------------
__global__ __launch_bounds__(64) void gru_mlp(
    float* __restrict__ slots, const float* __restrict__ part,
    float* __restrict__ rowsum,
    const float* __restrict__ wih, const float* __restrict__ whh,
    const float* __restrict__ bih, const float* __restrict__ bhh,
    const float* __restrict__ lnfg, const float* __restrict__ lnfb,
    const float* __restrict__ m1w, const float* __restrict__ m1b,
    const float* __restrict__ m2w, const float* __restrict__ m2b)
{
    const int n = blockIdx.x;
    const int b = n / 7, i = n % 7;
    const int l = threadIdx.x;
    float upd = 0.f;
    for (int js = 0; js < 16; ++js)
        upd += part[((((size_t)b * 16) + js) * 7 + i) * 64 + l];
    upd /= rowsum[n];
    if (l == 0) rowsum[n] = 0.f;
    const float prev = slots[n * 64 + l];
    float gi0 = bih[l], gi1 = bih[64 + l], gi2 = bih[128 + l];
    float gh0 = bhh[l], gh1 = bhh[64 + l], gh2 = bhh[128 + l];
    for (int c = 0; c < 64; ++c) {
        float u = __shfl(upd, c, 64), p = __shfl(prev, c, 64);
        gi0 = fmaf(u, wih[l * 64 + c], gi0);
        gi1 = fmaf(u, wih[(64 + l) * 64 + c], gi1);
        gi2 = fmaf(u, wih[(128 + l) * 64 + c], gi2);
        gh0 = fmaf(p, whh[l * 64 + c], gh0);
        gh1 = fmaf(p, whh[(64 + l) * 64 + c], gh1);
        gh2 = fmaf(p, whh[(128 + l) * 64 + c], gh2);
    }
    float r  = 1.f / (1.f + expf(-(gi0 + gh0)));
    float zg = 1.f / (1.f + expf(-(gi1 + gh1)));
    float nn = tanhf(gi2 + r * gh2);
    float s = (1.f - zg) * nn + zg * prev;
    float m = wave_sum(s) * (1.f / 64.f);
    float d = s - m;
    float var = wave_sum(d * d) * (1.f / 64.f);
    float x = d * rsqrtf(var + 1e-5f) * lnfg[l] + lnfb[l];
    float h0 = m1b[l], h1 = m1b[64 + l];
    for (int c = 0; c < 64; ++c) {
        float xv = __shfl(x, c, 64);
        h0 = fmaf(xv, m1w[c * 128 + l], h0);
        h1 = fmaf(xv, m1w[c * 128 + 64 + l], h1);
    }
    h0 = fmaxf(h0, 0.f); h1 = fmaxf(h1, 0.f);
    float o = m2b[l];
    for (int c = 0; c < 64; ++c) {
        o = fmaf(__shfl(h0, c, 64), m2w[c * 64 + l], o);
        o = fmaf(__shfl(h1, c, 64), m2w[(64 + c) * 64 + l], o);
    }
    slots[n * 64 + l] = s + o;
}

// ---------------- finalize ----------------
__global__ __launch_bounds__(256) void finalize_k(
    const float* __restrict__ dc4out, const float* __restrict__ inputs,
    float* __restrict__ out)
{
    const int tid = threadIdx.x;
    const int gp = blockIdx.x * 256 + tid;
    const int b = gp >> 12, p = gp & 4095;
    float4 o4[7];
#pragma unroll
    for (int k = 0; k < 7; ++k)
        o4[k] = ((const float4*)dc4out)[(size_t)(b * 7 + k) * 4096 + p];
    float mx = o4[0].w;
#pragma unroll
    for (int k = 1; k < 7; ++k) mx = fmaxf(mx, o4[k].w);
    float s = 0.f;
#pragma unroll
    for (int k = 0; k < 7; ++k) s += expf(o4[k].w - mx);
    const float lse = mx + logf(s);
    float recon0 = 0.f, recon1 = 0.f, recon2 = 0.f;
    float* xl = out + 1;
    float* ml = out + 2752513;
#pragma unroll
    for (int k = 0; k < 7; ++k) {
        float lp = o4[k].w - lse;
        ml[((size_t)(b * 7 + k)) * 4096 + p] = lp;
        float w = expf(lp);
        float x0 = 1.f / (1.f + expf(-o4[k].x));
        float x1 = 1.f / (1.f + expf(-o4[k].y));
        float x2 = 1.f / (1.f + expf(-o4[k].z));
        xl[(((size_t)(b * 7 + k)) * 3 + 0) * 4096 + p] = x0;
        xl[(((size_t)(b * 7 + k)) * 3 + 1) * 4096 + p] = x1;
        xl[(((size_t)(b * 7 + k)) * 3 + 2) * 4096 + p] = x2;
        recon0 = fmaf(x0, w, recon0);
        recon1 = fmaf(x1, w, recon1);
        recon2 = fmaf(x2, w, recon2);
    }
    float err = 0.f;
    {
        float xo = (inputs[((size_t)b * 3 + 0) * 4096 + p] + 1.f) * 0.5f;
        float dd = xo - recon0; err += dd * dd;
        xo = (inputs[((size_t)b * 3 + 1) * 4096 + p] + 1.f) * 0.5f;
        dd = xo - recon1; err += dd * dd;
        xo = (inputs[((size_t)b * 3 + 2) * 4096 + p] + 1.f) * 0.5f;
        dd = xo - recon2; err += dd * dd;
    }
    float wsum = wave_sum(err);
    __shared__ float red[4];
    const int lane = tid & 63, wv = tid >> 6;
    if (lane == 0) red[wv] = wsum;
    __syncthreads();
    if (tid == 0) atomicAdd(out, (red[0] + red[1] + red[2] + red[3]) * (1.f / 32.f));
}

// ---------------- copy slots to out (+ zero mse) ----------------
__global__ __launch_bounds__(256) void copy_slots(const float* __restrict__ slots,
                                                  float* __restrict__ out)
{
    int i = blockIdx.x * 256 + threadIdx.x;
    if (i == 0) out[0] = 0.f;
    if (i < 14336) out[3670017 + i] = slots[i];
}

// ---------------- launch ----------------
extern "C" void kernel_launch(void* const* d_in, const int* in_sizes, int n_in,
                              void* d_out, int out_size, void* d_ws, size_t ws_size,
                              hipStream_t stream) {
    (void)in_sizes; (void)n_in; (void)out_size; (void)ws_size;
    const float* inputs = (const float*)d_in[0];
    const float* noise  = (const float*)d_in[1];
    const float* epw  = (const float*)d_in[2];
    const float* epb  = (const float*)d_in[3];
    const float* ec1w = (const float*)d_in[4];
    const float* ec1b = (const float*)d_in[5];
    const float* ec2w = (const float*)d_in[6];
    const float* ec2b = (const float*)d_in[7];
    const float* ec3w = (const float*)d_in[8];
    const float* ec3b = (const float*)d_in[9];
    const float* ec4w = (const float*)d_in[10];
    const float* ec4b = (const float*)d_in[11];
    const float* ln1g = (const float*)d_in[12];
    const float* ln1b = (const float*)d_in[13];
    const float* fc1w = (const float*)d_in[14];
    const float* fc1b = (const float*)d_in[15];
    const float* fc2w = (const float*)d_in[16];
    const float* fc2b = (const float*)d_in[17];
    const float* lnsg = (const float*)d_in[18];
    const float* lnsb = (const float*)d_in[19];
    const float* lnfg = (const float*)d_in[20];
    const float* lnfb = (const float*)d_in[21];
    const float* qw   = (const float*)d_in[22];
    const float* kw   = (const float*)d_in[23];
    const float* vw   = (const float*)d_in[24];
    const float* m1w  = (const float*)d_in[25];
    const float* m1b  = (const float*)d_in[26];
    const float* m2w  = (const float*)d_in[27];
    const float* m2b  = (const float*)d_in[28];
    const float* wih  = (const float*)d_in[29];
    const float* whh  = (const float*)d_in[30];
    const float* bih  = (const float*)d_in[31];
    const float* bhh  = (const float*)d_in[32];
    const float* init_slots = (const float*)d_in[33];
    const float* dpw  = (const float*)d_in[34];
    const float* dpb  = (const float*)d_in[35];
    const float* dc1w = (const float*)d_in[36];
    const float* dc1b = (const float*)d_in[37];
    const float* dc2w = (const float*)d_in[38];
    const float* dc2b = (const float*)d_in[39];
    const float* dc3w = (const float*)d_in[40];
    const float* dc3b = (const float*)d_in[41];
    const float* dc4w = (const float*)d_in[42];
    const float* dc4b = (const float*)d_in[43];

    float* ws = (float*)d_ws;
    unsigned short* B0 = (unsigned short*)(ws + WS_B0);
    unsigned short* B1 = (unsigned short*)(ws + WS_B1);
    unsigned short* K = (unsigned short*)(ws + WS_K);
    unsigned short* V = (unsigned short*)(ws + WS_V);
    unsigned short* dping = (unsigned short*)(ws + WS_B0);
    unsigned short* dpong = (unsigned short*)(ws + WS_K);
    float* dc4out = ws + WS_V;
    unsigned short* PK = (unsigned short*)(ws + WS_V + 4194304u);
    unsigned short* p_ec2 = PK, *p_ec3 = PK + 102400, *p_ec4 = PK + 204800;
    unsigned short* p_dc1 = PK, *p_dc2 = PK + 51200, *p_dc3 = PK + 76800, *p_dc4 = PK + 102400;
    float* attn  = ws + WS_ATTN;
    unsigned short* PFC = (unsigned short*)attn;
    unsigned short* p_fc1 = PFC, *p_fc2 = PFC + 4096, *p_kw = PFC + 8192, *p_vw = PFC + 12288;
    unsigned short* peb = (unsigned short*)(attn + OFF_PEB);
    float* wclsb = attn + OFF_WCLS;
    float* Sbuf  = attn + OFF_S;
    float* zbias = attn + OFF_ZB;
    float* part  = ws + WS_PART;
    float* P     = ws + WS_PART;
    float* slots = ws + WS_SLOT;
    float* rowsum = ws + WS_ROW;
    float* out = (float*)d_out;

    // ---- pack encoder weights ----
    pack_weights<<<50, 256, 0, stream>>>(ec2w, p_ec2, 64, 64, 5, 4, 12800);
    pack_weights<<<50, 256, 0, stream>>>(ec3w, p_ec3, 64, 64, 5, 4, 12800);
    pack_weights<<<50, 256, 0, stream>>>(ec4w, p_ec4, 64, 64, 5, 4, 12800);
    pack_fc<<<2, 256, 0, stream>>>(fc1w, p_fc1);
    pack_fc<<<2, 256, 0, stream>>>(fc2w, p_fc2);
    pack_fc<<<2, 256, 0, stream>>>(kw, p_kw);
    pack_fc<<<2, 256, 0, stream>>>(vw, p_vw);

    // ---- encoder ----
    conv_ec1<<<2048, 256, 0, stream>>>(inputs, ec1w, ec1b, B0);
    conv_mfma<64, 64, 5, 2, 64, 1, 0><<<512, 256, 0, stream>>>(B0, p_ec2, ec2b, B1, 64, 64, 64, 64, 4, 4);
    conv_mfma<64, 64, 5, 2, 64, 1, 0><<<512, 256, 0, stream>>>(B1, p_ec3, ec3b, B0, 64, 64, 64, 64, 4, 4);
    conv_mfma<64, 64, 5, 2, 64, 1, 0><<<512, 256, 0, stream>>>(B0, p_ec4, ec4b, B1, 64, 64, 64, 64, 4, 4);
    encoder_tail_mfma<<<2048, 256, 0, stream>>>(B1, epw, epb, ln1g, ln1b,
                                                p_fc1, fc1b, p_fc2, fc2b, p_kw, p_vw, K, V);
    slot_init<<<56, 256, 0, stream>>>(noise, init_slots, slots, rowsum);

    // ---- 3 slot-attention iterations ----
    for (int it = 0; it < 3; ++it) {
        attn_pass1<<<512, 256, 0, stream>>>(K, slots, lnsg, lnsb, qw, attn, rowsum);
        attn_pass2<<<512, 256, 0, stream>>>(V, attn, part);
        gru_mlp<<<224, 64, 0, stream>>>(slots, part, rowsum, wih, whh, bih, bhh,
                                        lnfg, lnfb, m1w, m1b, m2w, m2b);
    }

    // ---- pack decoder weights + dc1 linearization precomputes ----
    pack_weights<<<25, 256, 0, stream>>>(dc1w, p_dc1, 64, 32, 5, 2, 6400);
    pack_weights<<<13, 256, 0, stream>>>(dc2w, p_dc2, 32, 32, 5, 2, 3200);
    pack_weights<<<13, 256, 0, stream>>>(dc3w, p_dc3, 32, 32, 5, 2, 3200);
    pack_weights<<<3, 256, 0, stream>>>(dc4w, p_dc4, 32, 4, 3, 1, 576);
    pe_synth<<<20, 256, 0, stream>>>(dpw, dpb, peb, zbias);
    conv_mfma<64, 32, 5, 1, 32, 0, 1><<<25, 256, 0, stream>>>(peb, p_dc1, zbias, P, 70, 70, 68, 68, 5, 5);
    wcls_build<<<72, 256, 0, stream>>>(dc1w, wclsb);
    slot_s<<<252, 256, 0, stream>>>(slots, wclsb, Sbuf);

    // ---- decoder, 2 chunks of 112 images ----
    for (int ch = 0; ch < 2; ++ch) {
        float* d4o = dc4out + (size_t)ch * 112 * 4 * 4096;
        dc1_assemble<<<2023, 256, 0, stream>>>(P, Sbuf, dc1b, ch * 112, dping);
        conv_mfma<32, 32, 5, 1, 32, 1, 0><<<2800, 256, 0, stream>>>(dping, p_dc2, dc2b, dpong, 68, 68, 66, 66, 5, 5);
        conv_mfma<32, 32, 5, 1, 32, 1, 0><<<1792, 256, 0, stream>>>(dpong, p_dc3, dc3b, dping, 66, 66, 64, 64, 4, 4);
        conv_mfma<32, 16, 3, 1, 4, 0, 1><<<1792, 256, 0, stream>>>(dping, p_dc4, dc4b, d4o, 64, 64, 64, 64, 4, 4);
    }

    // ---- outputs ----
    copy_slots<<<56, 256, 0, stream>>>(slots, out);
    finalize_k<<<512, 256, 0, stream>>>(dc4out, inputs, out);
}